// Round 1
// baseline (1316.159 us; speedup 1.0000x reference)
//
#include <hip/hip_runtime.h>
#include <math.h>

constexpr int N = 50000;
constexpr int E = 800000;
constexpr int H = 64;
constexpr int NWAVE = 12500;          // N/4 nodes-per-wave mapping (gat_prep: 4 nodes per wave)
constexpr int HW2 = N / 2;            // 25000: agg kernels use 2 nodes per wave
constexpr int SCB = 49;               // scan blocks per graph: 49*1024 >= N
constexpr int RNG = 8;                // histogram ranges per graph
constexpr int BPR = 8;                // edge slices per graph
constexpr int BINS = N / RNG;         // 6250 bins per range
constexpr int ES   = E / BPR;         // 100000 edges per slice

typedef unsigned short ushort_t;
typedef unsigned int uint_t;
typedef unsigned char uchar_t;
typedef float fl2 __attribute__((ext_vector_type(2)));
typedef float fl4 __attribute__((ext_vector_type(4)));

// ---- workspace layout (element offsets) ----
constexpr size_t X_OFF    = 0;                          // N*H
constexpr size_t NO_OFF   = X_OFF + (size_t)N*H;        // N   deg_out^-1/2
constexpr size_t NI_OFF   = NO_OFF + N;                 // N   deg_in^-1/2
constexpr size_t EL_OFF   = NI_OFF + N;                 // N+1 GAT el (incl supernode)
constexpr size_t ER_OFF   = EL_OFF + (N+1);             // N   GAT er
constexpr size_t EE_OFF   = ER_OFF + N;                 // E   per-edge exp(e) (CSR order)
constexpr size_t IS_OFF   = EE_OFF + E;                 // N   1/softmax-denominator
constexpr size_t ASLF_OFF = IS_OFF + N;                 // N   self-loop numerator
constexpr size_t ASUP_OFF = ASLF_OFF + N;               // N   supernode numerator
constexpr size_t GF = ((ASUP_OFF + N + 255)/256)*256;

constexpr size_t RP_OFF = 0;                            // N+1 row_ptr (CSR by dst)
constexpr size_t CT_OFF = RP_OFF + (N+1);               // N   in-degree count
constexpr size_t SS_OFF = CT_OFF + N;                   // E   src sorted by dst
constexpr size_t GI = ((SS_OFF + E + 255)/256)*256;

// per-graph fp8 h block: 64 B per row (64 x e4m3 = 16 uints); row N = supernode
constexpr size_t GH = (size_t)(N+1)*64;                 // bytes

// fp8 helpers: HW RNE pack/unpack (OCP e4m3 on gfx950)
__device__ inline uint_t f8pack4(float a, float b, float c, float d){
  int r = __builtin_amdgcn_cvt_pk_fp8_f32(a, b, 0, false);
  r = __builtin_amdgcn_cvt_pk_fp8_f32(c, d, r, true);
  return (uint_t)r;
}
__device__ inline fl4 f8up4(uint_t v){
  fl2 lo = __builtin_amdgcn_cvt_pk_f32_fp8((int)v, false);
  fl2 hi = __builtin_amdgcn_cvt_pk_f32_fp8((int)v, true);
  fl4 r; r.x = lo.x; r.y = lo.y; r.z = hi.x; r.w = hi.y;
  return r;
}

// ---- prep: range-partitioned LDS histograms, zero global atomics ----
__global__ __launch_bounds__(1024) void k_hist(int* parts_ct, int* parts_no,
    const int* s0,const int* d0,const int* s1,const int* d1,const int* s2,const int* d2) {
  int sl = blockIdx.x, r = blockIdx.y, g = blockIdx.z;
  const int* s = g==0?s0:(g==1?s1:s2);
  const int* d = g==0?d0:(g==1?d1:d2);
  __shared__ int hc[BINS];
  __shared__ int hn[BINS];
  for (int i=threadIdx.x;i<BINS;i+=1024){ hc[i]=0; hn[i]=0; }
  __syncthreads();
  int lo = r*BINS, hi = lo+BINS;
  int e0 = sl*ES, e1 = e0+ES;
  for (int e=e0+threadIdx.x; e<e1; e+=1024){
    int ds = d[e], sr = s[e];
    if (ds>=lo && ds<hi) atomicAdd(&hc[ds-lo],1);
    if (sr>=lo && sr<hi) atomicAdd(&hn[sr-lo],1);
  }
  __syncthreads();
  size_t base = ((size_t)g*BPR + sl)*N + lo;
  for (int i=threadIdx.x;i<BINS;i+=1024){
    parts_ct[base+i]=hc[i];
    parts_no[base+i]=hn[i];
  }
}

// ---- hierarchical exclusive scan of cnt -> rp (all parallel) ----
__global__ __launch_bounds__(1024) void k_scan_local(int* ib, int* pt, const int* parts_ct) {
  int g = blockIdx.y;
  int* ig = ib + (size_t)g*GI;
  int i = blockIdx.x*1024 + threadIdx.x;
  int c = 0;
  if (i < N){
    #pragma unroll
    for (int s=0;s<BPR;s++) c += parts_ct[((size_t)g*BPR+s)*N + i];
    ig[CT_OFF + i] = c;
  }
  __shared__ int sh[1024];
  sh[threadIdx.x] = c; __syncthreads();
  #pragma unroll
  for (int off=1; off<1024; off<<=1){
    int t = (threadIdx.x>=off) ? sh[threadIdx.x-off] : 0;
    __syncthreads();
    sh[threadIdx.x] += t;
    __syncthreads();
  }
  if (i < N) ig[RP_OFF + i] = sh[threadIdx.x] - c;       // local exclusive
  if (threadIdx.x == 1023) pt[g*SCB + blockIdx.x] = sh[1023];
}

__global__ void k_scan_part(int* pt) {
  int g = blockIdx.x;
  __shared__ int sh[SCB];
  int t = threadIdx.x;
  if (t < SCB) sh[t] = pt[g*SCB + t];
  __syncthreads();
  if (t == 0){
    int run = 0;
    for (int b=0;b<SCB;b++){ int c = sh[b]; sh[b] = run; run += c; }
  }
  __syncthreads();
  if (t < SCB) pt[g*SCB + t] = sh[t];
}

__global__ __launch_bounds__(1024) void k_scan_apply(float* fb, int* ib, const int* pt,
                                                     const int* parts_no) {
  int g = blockIdx.y;
  float* fg = fb + (size_t)g*GF;
  int* ig = ib + (size_t)g*GI;
  int i = blockIdx.x*1024 + threadIdx.x;
  if (i >= N) return;
  int base = pt[g*SCB + blockIdx.x];
  int r = ig[RP_OFF + i] + base;
  ig[RP_OFF + i] = r;
  int c = ig[CT_OFF + i];
  int o = 0;
  #pragma unroll
  for (int s=0;s<BPR;s++) o += parts_no[((size_t)g*BPR+s)*N + i];
  fg[NI_OFF + i] = rsqrtf((float)(c+1));                 // +1 self loop
  fg[NO_OFF + i] = rsqrtf((float)(o+1));
  if (i == N-1) ig[RP_OFF + N] = r + c;
}

// per-(slice,bin) exclusive prefix over slices -> exact scatter offsets
__global__ __launch_bounds__(256) void k_slice_off(const int* ib, const int* parts_ct, int* off) {
  int g = blockIdx.y;
  int i = blockIdx.x*256 + threadIdx.x;
  if (i >= N) return;
  int base = ib[(size_t)g*GI + RP_OFF + i];
  #pragma unroll
  for (int s=0;s<BPR;s++){
    size_t idx = ((size_t)g*BPR+s)*N + i;
    off[idx] = base;
    base += parts_ct[idx];
  }
}

// scatter: LDS cursors per range, plain scattered store (no global atomics)
__global__ __launch_bounds__(1024) void k_scatter_r(int* ib, const int* off,
    const int* s0,const int* d0,const int* s1,const int* d1,const int* s2,const int* d2) {
  int sl = blockIdx.x, r = blockIdx.y, g = blockIdx.z;
  const int* s = g==0?s0:(g==1?s1:s2);
  const int* d = g==0?d0:(g==1?d1:d2);
  int* ss = ib + (size_t)g*GI + SS_OFF;
  __shared__ int cur[BINS];
  int lo = r*BINS;
  size_t ob = ((size_t)g*BPR + sl)*N + lo;
  for (int i=threadIdx.x;i<BINS;i+=1024) cur[i] = off[ob+i];
  __syncthreads();
  int e0 = sl*ES, e1 = e0+ES;
  for (int e=e0+threadIdx.x; e<e1; e+=1024){
    int ds = d[e];
    if (ds>=lo && ds<lo+BINS){
      int pos = atomicAdd(&cur[ds-lo],1);
      ss[pos] = s[e];
    }
  }
}

__global__ __launch_bounds__(256) void k_copyx(float* fb, const float* x0,const float* x1,const float* x2) {
  int i = blockIdx.x*256 + threadIdx.x;
  int g = blockIdx.y;
  const float* x = g==0?x0:(g==1?x1:x2);
  if (i < N*H/4) {
    ((float4*)(fb + (size_t)g*GF + X_OFF))[i] = ((const float4*)x)[i];
  }
}

// Tiled matmul: 64 rows/block, 4 threads/row (q = 16-col group), acc[16].
// h = fp8( (x @ W) * no[row] ) -> 64 B/row. Block (0,0) zeroes readout accs.
__global__ __launch_bounds__(256) void k_mm_gcn(float* fb, uchar_t* hb,
    const float* W0,const float* W1,const float* W2, float* sm) {
  if (blockIdx.x==0 && blockIdx.y==0){
    for (int i=threadIdx.x;i<384;i+=256) sm[i]=0.f;
  }
  int g = blockIdx.y;
  const float* W = g==0?W0:(g==1?W1:W2);
  __shared__ float Ws[64*64];
  __shared__ float Xs[64*65];
  float* fg = fb + (size_t)g*GF;
  int row0 = blockIdx.x*64;
  for (int i=threadIdx.x; i<4096; i+=256) Ws[i] = W[i];
  int r = threadIdx.x>>2, q = threadIdx.x&3;
  int row = row0 + r;
  int rowc = row < N ? row : N-1;
  {
    const float4* xr = (const float4*)(fg + X_OFF + (size_t)rowc*64) + q*4;
    float* xd = Xs + r*65 + q*16;
    #pragma unroll
    for (int c=0;c<4;c++){ float4 v = xr[c]; xd[4*c]=v.x; xd[4*c+1]=v.y; xd[4*c+2]=v.z; xd[4*c+3]=v.w; }
  }
  __syncthreads();
  float acc[16];
  #pragma unroll
  for (int j=0;j<16;j++) acc[j]=0.f;
  const float* xrow = Xs + r*65;
  #pragma unroll 8
  for (int k=0;k<64;k++){
    float xk = xrow[k];
    const float* wr = Ws + k*64 + q*16;
    #pragma unroll
    for (int j=0;j<16;j++) acc[j] = fmaf(xk, wr[j], acc[j]);
  }
  if (row >= N) return;
  float sc = fg[NO_OFF + row];
  uint_t pk[4];
  #pragma unroll
  for (int j=0;j<4;j++)
    pk[j] = f8pack4(acc[4*j]*sc, acc[4*j+1]*sc, acc[4*j+2]*sc, acc[4*j+3]*sc);
  *(uint4*)(hb + (size_t)g*GH + (size_t)row*64 + q*16) = *(const uint4*)pk;
}

// Same tiling; h = fp8(x @ Wgat[g]); el/er via quad shfl reduce.
__global__ __launch_bounds__(256) void k_mm_gat(float* fb, uchar_t* hb,
    const float* Wgat, const float* al, const float* ar) {
  int g = blockIdx.y;
  const float* W = Wgat + (size_t)g*4096;
  __shared__ float Ws[64*64];
  __shared__ float Xs[64*65];
  __shared__ float als[64], ars[64];
  float* fg = fb + (size_t)g*GF;
  int row0 = blockIdx.x*64;
  for (int i=threadIdx.x; i<4096; i+=256) Ws[i] = W[i];
  if (threadIdx.x < 64){ als[threadIdx.x] = al[g*64+threadIdx.x]; ars[threadIdx.x] = ar[g*64+threadIdx.x]; }
  int r = threadIdx.x>>2, q = threadIdx.x&3;
  int row = row0 + r;
  int rowc = row < N ? row : N-1;
  {
    const float4* xr = (const float4*)(fg + X_OFF + (size_t)rowc*64) + q*4;
    float* xd = Xs + r*65 + q*16;
    #pragma unroll
    for (int c=0;c<4;c++){ float4 v = xr[c]; xd[4*c]=v.x; xd[4*c+1]=v.y; xd[4*c+2]=v.z; xd[4*c+3]=v.w; }
  }
  __syncthreads();
  float acc[16];
  #pragma unroll
  for (int j=0;j<16;j++) acc[j]=0.f;
  const float* xrow = Xs + r*65;
  #pragma unroll 8
  for (int k=0;k<64;k++){
    float xk = xrow[k];
    const float* wr = Ws + k*64 + q*16;
    #pragma unroll
    for (int j=0;j<16;j++) acc[j] = fmaf(xk, wr[j], acc[j]);
  }
  float el = 0.f, er = 0.f;
  #pragma unroll
  for (int j=0;j<16;j++){ el = fmaf(acc[j], als[q*16+j], el); er = fmaf(acc[j], ars[q*16+j], er); }
  el += __shfl_xor(el,1); el += __shfl_xor(el,2);
  er += __shfl_xor(er,1); er += __shfl_xor(er,2);
  if (row >= N) return;
  uint_t pk[4];
  #pragma unroll
  for (int j=0;j<4;j++)
    pk[j] = f8pack4(acc[4*j], acc[4*j+1], acc[4*j+2], acc[4*j+3]);
  *(uint4*)(hb + (size_t)g*GH + (size_t)row*64 + q*16) = *(const uint4*)pk;
  if (q == 0){
    fg[EL_OFF + row] = el;
    fg[ER_OFF + row] = er;
  }
}

// GCN aggregate, merged over graphs. 2 nodes/wave, deep-MLP restructure:
// phase A issues ALL independent loads (rp, self rows, ni, 2x16 clamped edge
// indices per node), phase B issues all 16 row-gathers, phase C accumulates
// with validity weights. One predicated 32-edge round covers ~99.99% of nodes
// (Poisson-16 degrees); rare wave-uniform tail loop handles the rest.
// Dependent-latency chain per wave: ~3 (was ~16 with serial 4-node loop).
__global__ __launch_bounds__(256) void k_gcn_agg(float* fb, const uchar_t* hb, const int* ib,
    const float* b0, const float* b1, const float* b2, int lay, float* sm, int writex) {
  int g = blockIdx.y;
  const float* b = (g==0?b0:(g==1?b1:b2)) + lay*64;
  float* fg = fb + (size_t)g*GF;
  const uint_t* hu = (const uint_t*)(hb + (size_t)g*GH);  // 16 uints per row
  const int* ig = ib + (size_t)g*GI;
  int wave = threadIdx.x >> 6, lane = threadIdx.x & 63;
  int q = lane >> 4, u = lane & 15, l15 = lane & 15;
  int w = blockIdx.x*4 + wave;                            // w in [0, HW2)
  const int* rp = ig + RP_OFF;
  const int* ss = ig + SS_OFF;
  fl4 bl = ((const fl4*)b)[u];
  fl4 vs = {0.f,0.f,0.f,0.f}, vm = {0.f,0.f,0.f,0.f};
  __shared__ float ssum[4][64];
  __shared__ float smx[4][64];

  int nd[2]; nd[0] = w; nd[1] = w + HW2;
  int s0[2], s1[2];
  #pragma unroll
  for (int i=0;i<2;i++){ s0[i] = rp[nd[i]]; s1[i] = rp[nd[i]+1]; }

  // phase A: all independent loads
  uint_t vself[2]; float ni[2]; int ia[2], ibv[2];
  #pragma unroll
  for (int i=0;i<2;i++){
    vself[i] = hu[nd[i]*16 + u];
    ni[i] = fg[NI_OFF + nd[i]];
    int eA = s0[i] + l15, eB = eA + 16;
    ia[i]  = ss[eA < s1[i] ? eA : 0];
    ibv[i] = ss[eB < s1[i] ? eB : 0];
  }

  // phase B: 16 row-gathers in flight
  uint_t v[2][8];
  #pragma unroll
  for (int i=0;i<2;i++){
    #pragma unroll
    for (int j=0;j<8;j++){
      int r = __shfl(j<4 ? ia[i] : ibv[i], q + (j&3)*4);
      v[i][j] = hu[r*16 + u];
    }
  }

  // phase C: accumulate with validity weights + rare tail + finalize
  #pragma unroll
  for (int i=0;i<2;i++){
    fl4 a = {0.f,0.f,0.f,0.f};
    if (q == 0) a = f8up4(vself[i]);                     // self loop (pre-scaled)
    #pragma unroll
    for (int j=0;j<8;j++){
      int e = s0[i] + (j>>2)*16 + q + (j&3)*4;
      float wv = e < s1[i] ? 1.f : 0.f;
      fl4 f = f8up4(v[i][j]);
      a.x = fmaf(wv, f.x, a.x); a.y = fmaf(wv, f.y, a.y);
      a.z = fmaf(wv, f.z, a.z); a.w = fmaf(wv, f.w, a.w);
    }
    for (int k = s0[i]+32; k < s1[i]; k += 16){          // wave-uniform, rare
      int kk = k + l15;
      int iv = ss[kk < s1[i] ? kk : 0];
      #pragma unroll
      for (int j=0;j<4;j++){
        int r = __shfl(iv, q + j*4);
        uint_t vv = hu[r*16 + u];
        int e = k + q + j*4;
        float wv = e < s1[i] ? 1.f : 0.f;
        fl4 f = f8up4(vv);
        a.x = fmaf(wv, f.x, a.x); a.y = fmaf(wv, f.y, a.y);
        a.z = fmaf(wv, f.z, a.z); a.w = fmaf(wv, f.w, a.w);
      }
    }
    a.x += __shfl_xor(a.x,16); a.x += __shfl_xor(a.x,32);
    a.y += __shfl_xor(a.y,16); a.y += __shfl_xor(a.y,32);
    a.z += __shfl_xor(a.z,16); a.z += __shfl_xor(a.z,32);
    a.w += __shfl_xor(a.w,16); a.w += __shfl_xor(a.w,32);
    if (q == 0){
      fl4 vv;
      vv.x = fmaf(a.x, ni[i], bl.x); vv.x = vv.x > 0.f ? vv.x : 0.f;
      vv.y = fmaf(a.y, ni[i], bl.y); vv.y = vv.y > 0.f ? vv.y : 0.f;
      vv.z = fmaf(a.z, ni[i], bl.z); vv.z = vv.z > 0.f ? vv.z : 0.f;
      vv.w = fmaf(a.w, ni[i], bl.w); vv.w = vv.w > 0.f ? vv.w : 0.f;
      if (writex) ((fl4*)(fg + X_OFF + (size_t)nd[i]*64))[u] = vv;
      vs += vv;
      vm.x = fmaxf(vm.x,vv.x); vm.y = fmaxf(vm.y,vv.y);
      vm.z = fmaxf(vm.z,vv.z); vm.w = fmaxf(vm.w,vv.w);
    }
  }
  if (q == 0){
    ((fl4*)ssum[wave])[u] = vs;
    ((fl4*)smx[wave])[u]  = vm;
  }
  __syncthreads();
  if (threadIdx.x < 64){
    int t = threadIdx.x;
    float s = ssum[0][t]+ssum[1][t]+ssum[2][t]+ssum[3][t];
    float mx = fmaxf(fmaxf(smx[0][t],smx[1][t]), fmaxf(smx[2][t],smx[3][t]));
    atomicAdd(&sm[g*64 + t], s);
    atomicMax((int*)sm + 192 + g*64 + t, __float_as_int(mx));  // v>=0: int order == float order
  }
}

// readout finalize + cross-graph feature exchange + supernode h row (fp8), el[N]
__global__ void k_exchange(float* fb, uchar_t* hb, float* sm, const float* Wx, const float* bx,
                           const float* Wgat, const float* al, int it) {
  int gt = blockIdx.x;     // target graph
  int t = threadIdx.x;     // 64 threads
  int src, widx;
  if ((it & 1) == 0){ src = (gt==0)?1:(gt==1)?2:0; widx = (gt==0)?1:(gt==1)?0:2; }
  else              { src = (gt==0)?2:(gt==1)?0:1; widx = (gt==0)?5:(gt==1)?3:4; }
  __shared__ float ro[128];
  __shared__ float f[64];
  __shared__ float red[64];
  __shared__ float hsb[64];
  ro[t]      = sm[src*64 + t] * (1.0f/(float)N);
  ro[64 + t] = __int_as_float(((int*)sm)[192 + src*64 + t]);
  __syncthreads();
  float a = bx[widx*64 + t];
  for (int k=0;k<128;k++) a = fmaf(ro[k], Wx[(size_t)widx*8192 + k*64 + t], a);
  a = a > 0.f ? a : 0.f;
  f[t] = a;
  __syncthreads();
  float* fg = fb + (size_t)gt*GF;
  float hs = 0.f;
  for (int k=0;k<64;k++) hs = fmaf(f[k], Wgat[(size_t)gt*4096 + k*64 + t], hs);
  hsb[t] = hs;
  red[t] = hs * al[gt*64 + t];
  __syncthreads();
  if (t < 16){
    uint_t r = f8pack4(hsb[4*t], hsb[4*t+1], hsb[4*t+2], hsb[4*t+3]);
    ((uint_t*)(hb + (size_t)gt*GH + (size_t)N*64))[t] = r;
  }
  if (t == 0){
    float e = 0.f;
    for (int k=0;k<64;k++) e += red[k];
    fg[EL_OFF + N] = e;                      // el for supernode
  }
}

// GAT softmax prep: wave per 4 nodes, interleaved phases: all ss loads ->
// all el gathers -> compute. One predicated 64-edge chunk per node covers
// essentially all degrees; tail loop for safety.
__global__ __launch_bounds__(256) void k_gat_prep(float* fb, const int* ib) {
  int g = blockIdx.y;
  float* fg = fb + (size_t)g*GF;
  const int* ig = ib + (size_t)g*GI;
  const int* rp = ig + RP_OFF;
  const int* ss = ig + SS_OFF;
  const float* el = fg + EL_OFF;
  float* ee = fg + EE_OFF;
  int wave = threadIdx.x>>6, lane = threadIdx.x&63;
  int w = blockIdx.x*4 + wave;
  float elsup = el[N];
  int node[4], s0[4], s1[4];
  #pragma unroll
  for (int i=0;i<4;i++){ node[i] = w + NWAVE*i; s0[i] = rp[node[i]]; s1[i] = rp[node[i]+1]; }
  float eri[4];
  #pragma unroll
  for (int i=0;i<4;i++) eri[i] = fg[ER_OFF + node[i]];
  int sv[4];
  #pragma unroll
  for (int i=0;i<4;i++){ int e = s0[i] + lane; sv[i] = ss[e < s1[i] ? e : 0]; }
  float ev[4];
  #pragma unroll
  for (int i=0;i<4;i++) ev[i] = el[sv[i]];
  #pragma unroll
  for (int i=0;i<4;i++){
    int e = s0[i] + lane;
    float x = ev[i] + eri[i];
    x = x >= 0.f ? x : 0.2f*x;
    float t = 0.f;
    if (e < s1[i]){ t = __expf(x); ee[e] = t; }
    float s = t;
    for (int k = s0[i]+64; k < s1[i]; k += 64){          // wave-uniform, ~never
      int e2 = k + lane;
      float t2 = 0.f;
      if (e2 < s1[i]){
        float x2 = el[ss[e2]] + eri[i];
        x2 = x2 >= 0.f ? x2 : 0.2f*x2;
        t2 = __expf(x2);
        ee[e2] = t2;
      }
      s += t2;
    }
    #pragma unroll
    for (int m=1;m<64;m<<=1) s += __shfl_xor(s,m);
    if (lane == 0){
      float eself = el[node[i]] + eri[i]; eself = eself >= 0.f ? eself : 0.2f*eself;
      float esup  = elsup + eri[i];       esup  = esup  >= 0.f ? esup  : 0.2f*esup;
      float ts = __expf(eself), tu = __expf(esup);
      s += ts + tu;
      fg[IS_OFF + node[i]]   = 1.0f / s;
      fg[ASLF_OFF + node[i]] = ts;
      fg[ASUP_OFF + node[i]] = tu;
    }
  }
}

// GAT aggregation, merged: same 2-node/wave deep-MLP scheme as k_gcn_agg,
// with per-edge weights (ee) shfl-distributed; slot q==0 adds self-loop,
// q==1 adds supernode.
__global__ __launch_bounds__(256) void k_gat_agg(float* fb, const uchar_t* hb, const int* ib,
    const float* bgat) {
  int g = blockIdx.y;
  float* fg = fb + (size_t)g*GF;
  const uint_t* hu = (const uint_t*)(hb + (size_t)g*GH);
  const int* ig = ib + (size_t)g*GI;
  int wave = threadIdx.x >> 6, lane = threadIdx.x & 63;
  int q = lane >> 4, u = lane & 15, l15 = lane & 15;
  int w = blockIdx.x*4 + wave;                            // w in [0, HW2)
  const int* rp = ig + RP_OFF;
  const int* ss = ig + SS_OFF;
  const float* ee = fg + EE_OFF;
  fl4 bg = ((const fl4*)(bgat + g*64))[u];

  int nd[2]; nd[0] = w; nd[1] = w + HW2;
  int s0[2], s1[2];
  #pragma unroll
  for (int i=0;i<2;i++){ s0[i] = rp[nd[i]]; s1[i] = rp[nd[i]+1]; }

  // phase A: all independent loads
  uint_t vsup = hu[N*16 + u];
  uint_t vself[2]; float aslf[2], asup[2], isv[2];
  int ia[2], ibv[2]; float wa[2], wb[2];
  #pragma unroll
  for (int i=0;i<2;i++){
    vself[i] = hu[nd[i]*16 + u];
    aslf[i] = fg[ASLF_OFF + nd[i]];
    asup[i] = fg[ASUP_OFF + nd[i]];
    isv[i]  = fg[IS_OFF + nd[i]];
    int eA = s0[i] + l15, eB = eA + 16;
    int cA = eA < s1[i] ? eA : 0, cB = eB < s1[i] ? eB : 0;
    ia[i]  = ss[cA]; ibv[i] = ss[cB];
    wa[i]  = ee[cA]; wb[i]  = ee[cB];
  }

  // phase B: 16 row-gathers in flight
  uint_t v[2][8];
  #pragma unroll
  for (int i=0;i<2;i++){
    #pragma unroll
    for (int j=0;j<8;j++){
      int r = __shfl(j<4 ? ia[i] : ibv[i], q + (j&3)*4);
      v[i][j] = hu[r*16 + u];
    }
  }

  fl4 supf = f8up4(vsup);
  #pragma unroll
  for (int i=0;i<2;i++){
    fl4 a = {0.f,0.f,0.f,0.f};
    if (q == 0){
      fl4 f = f8up4(vself[i]);
      a.x = aslf[i]*f.x; a.y = aslf[i]*f.y; a.z = aslf[i]*f.z; a.w = aslf[i]*f.w;
    } else if (q == 1){
      a.x = asup[i]*supf.x; a.y = asup[i]*supf.y; a.z = asup[i]*supf.z; a.w = asup[i]*supf.w;
    }
    #pragma unroll
    for (int j=0;j<8;j++){
      int e = s0[i] + (j>>2)*16 + q + (j&3)*4;
      float wsh = __shfl(j<4 ? wa[i] : wb[i], q + (j&3)*4);
      float wv = e < s1[i] ? wsh : 0.f;
      fl4 f = f8up4(v[i][j]);
      a.x = fmaf(wv, f.x, a.x); a.y = fmaf(wv, f.y, a.y);
      a.z = fmaf(wv, f.z, a.z); a.w = fmaf(wv, f.w, a.w);
    }
    for (int k = s0[i]+32; k < s1[i]; k += 16){          // wave-uniform, rare
      int kk = k + l15;
      int cc = kk < s1[i] ? kk : 0;
      int iv = ss[cc];
      float wt = ee[cc];
      #pragma unroll
      for (int j=0;j<4;j++){
        int r = __shfl(iv, q + j*4);
        float ws = __shfl(wt, q + j*4);
        uint_t vv = hu[r*16 + u];
        int e = k + q + j*4;
        float wv = e < s1[i] ? ws : 0.f;
        fl4 f = f8up4(vv);
        a.x = fmaf(wv, f.x, a.x); a.y = fmaf(wv, f.y, a.y);
        a.z = fmaf(wv, f.z, a.z); a.w = fmaf(wv, f.w, a.w);
      }
    }
    a.x += __shfl_xor(a.x,16); a.x += __shfl_xor(a.x,32);
    a.y += __shfl_xor(a.y,16); a.y += __shfl_xor(a.y,32);
    a.z += __shfl_xor(a.z,16); a.z += __shfl_xor(a.z,32);
    a.w += __shfl_xor(a.w,16); a.w += __shfl_xor(a.w,32);
    if (q == 0){
      fl4 vv;
      vv.x = fmaf(a.x, isv[i], bg.x); vv.y = fmaf(a.y, isv[i], bg.y);
      vv.z = fmaf(a.z, isv[i], bg.z); vv.w = fmaf(a.w, isv[i], bg.w);
      ((fl4*)(fg + X_OFF + (size_t)nd[i]*64))[u] = vv;
    }
  }
}

__global__ __launch_bounds__(384) void k_mlp(const float* sm, const float* W1, const float* b1,
    const float* W2, const float* b2, const float* W3, const float* b3, float* out) {
  __shared__ float nf[384];
  __shared__ float y1[192];
  __shared__ float y2[96];
  __shared__ float z[2];
  int t = threadIdx.x;
  int g = t / 128, j = t % 128;
  nf[t] = (j < 64) ? sm[g*64 + j] * (1.0f/(float)N)
                   : __int_as_float(((const int*)sm)[192 + g*64 + (j-64)]);
  __syncthreads();
  if (t < 192){
    float a = b1[t];
    for (int k=0;k<384;k++) a = fmaf(nf[k], W1[(size_t)k*192 + t], a);
    y1[t] = a > 0.f ? a : 0.f;
  }
  __syncthreads();
  if (t < 96){
    float a = b2[t];
    for (int k=0;k<192;k++) a = fmaf(y1[k], W2[(size_t)k*96 + t], a);
    y2[t] = a > 0.f ? a : 0.f;
  }
  __syncthreads();
  if (t < 2){
    float a = b3[t];
    for (int k=0;k<96;k++) a = fmaf(y2[k], W3[k*2 + t], a);
    z[t] = a;
  }
  __syncthreads();
  if (t == 0){
    float m = fmaxf(z[0], z[1]);
    float l = m + logf(__expf(z[0]-m) + __expf(z[1]-m));
    out[0] = z[0] - l;
    out[1] = z[1] - l;
  }
}

extern "C" void kernel_launch(void* const* d_in, const int* in_sizes, int n_in,
                              void* d_out, int out_size, void* d_ws, size_t ws_size,
                              hipStream_t stream) {
  const float* x_s  = (const float*)d_in[0];
  const float* x_g  = (const float*)d_in[1];
  const float* x_t  = (const float*)d_in[2];
  const float* Wc_s = (const float*)d_in[3];
  const float* bc_s = (const float*)d_in[4];
  const float* Wc_g = (const float*)d_in[5];
  const float* bc_g = (const float*)d_in[6];
  const float* Wc_t = (const float*)d_in[7];
  const float* bc_t = (const float*)d_in[8];
  const float* Wx   = (const float*)d_in[9];
  const float* bx   = (const float*)d_in[10];
  const float* Wgat = (const float*)d_in[11];
  const float* al   = (const float*)d_in[12];
  const float* ar   = (const float*)d_in[13];
  const float* bgat = (const float*)d_in[14];
  const float* W1   = (const float*)d_in[15];
  const float* b1   = (const float*)d_in[16];
  const float* W2   = (const float*)d_in[17];
  const float* b2   = (const float*)d_in[18];
  const float* W3   = (const float*)d_in[19];
  const float* b3   = (const float*)d_in[20];
  const int* src_s  = (const int*)d_in[21];
  const int* dst_s  = (const int*)d_in[22];
  const int* src_g  = (const int*)d_in[23];
  const int* dst_g  = (const int*)d_in[24];
  const int* src_t  = (const int*)d_in[25];
  const int* dst_t  = (const int*)d_in[26];

  float* fb = (float*)d_ws;
  int*   ib = (int*)(fb + 3*GF);
  uchar_t* hb = (uchar_t*)(ib + 3*GI);
  float* sm = (float*)(hb + 3*GH);
  int*   pt = (int*)(sm + 384);              // 3*SCB scan partials
  int*   parts_ct = pt + 3*SCB + 64;         // 3*BPR*N
  int*   parts_no = parts_ct + (size_t)3*BPR*N;
  int*   off      = parts_no + (size_t)3*BPR*N;
  float* out = (float*)d_out;

  dim3 b256(256);
  int mmb = (N+63)/64;

  // graph prep: LDS-histogram counting sort (no global atomics)
  k_hist      <<<dim3(BPR, RNG, 3),  dim3(1024), 0, stream>>>(parts_ct, parts_no, src_s,dst_s, src_g,dst_g, src_t,dst_t);
  k_scan_local<<<dim3(SCB, 3),       dim3(1024), 0, stream>>>(ib, pt, parts_ct);
  k_scan_part <<<dim3(3),              dim3(64), 0, stream>>>(pt);
  k_scan_apply<<<dim3(SCB, 3),       dim3(1024), 0, stream>>>(fb, ib, pt, parts_no);
  k_slice_off <<<dim3((N+255)/256, 3),     b256, 0, stream>>>(ib, parts_ct, off);
  k_scatter_r <<<dim3(BPR, RNG, 3),  dim3(1024), 0, stream>>>(ib, off, src_s,dst_s, src_g,dst_g, src_t,dst_t);
  k_copyx     <<<dim3((N*H/4+255)/256, 3), b256, 0, stream>>>(fb, x_s, x_g, x_t);

  for (int it = 0; it < 2; ++it) {
    k_mm_gcn  <<<dim3(mmb, 3),    b256, 0, stream>>>(fb, hb, Wc_s + it*4096, Wc_g + it*4096, Wc_t + it*4096, sm);
    k_gcn_agg <<<dim3(HW2/4, 3),  b256, 0, stream>>>(fb, hb, ib, bc_s, bc_g, bc_t, it, sm, 1);
    k_exchange<<<dim3(3), dim3(64), 0, stream>>>(fb, hb, sm, Wx, bx, Wgat, al, it);
    k_mm_gat  <<<dim3(mmb, 3),    b256, 0, stream>>>(fb, hb, Wgat, al, ar);
    k_gat_prep<<<dim3(NWAVE/4, 3),b256, 0, stream>>>(fb, ib);
    k_gat_agg <<<dim3(HW2/4, 3),  b256, 0, stream>>>(fb, hb, ib, bgat);
  }

  // final layer readouts + MLP head (x write skipped — only readout consumed)
  k_mm_gcn  <<<dim3(mmb, 3),    b256, 0, stream>>>(fb, hb, Wc_s + 2*4096, Wc_g + 2*4096, Wc_t + 2*4096, sm);
  k_gcn_agg <<<dim3(HW2/4, 3),  b256, 0, stream>>>(fb, hb, ib, bc_s, bc_g, bc_t, 2, sm, 0);
  k_mlp     <<<1, 384, 0, stream>>>(sm, W1, b1, W2, b2, W3, b3, out);
}

// Round 3
// 1000.824 us; speedup vs baseline: 1.3151x; 1.3151x over previous
//
#include <hip/hip_runtime.h>
#include <math.h>

constexpr int N = 50000;
constexpr int E = 800000;
constexpr int H = 64;
constexpr int NWAVE = 12500;          // N/4 nodes-per-wave mapping (4 nodes per wave)
constexpr int AGB = 3125;             // agg blocks (tiles) per graph (NWAVE/4)
constexpr int SCB = 49;               // scan blocks per graph: 49*1024 >= N
constexpr int RNG = 8;                // histogram ranges per graph
constexpr int BPR = 8;                // edge slices per graph
constexpr int BINS = N / RNG;         // 6250 bins per range
constexpr int ES   = E / BPR;         // 100000 edges per slice

// XCD-affinity swizzle constants (stateless, replay-safe).
// Default dispatch round-robins blockIdx across 8 XCDs; rounds of 8 blocks:
// slots 0-2 -> g0, 3-5 -> g1, 6-7 -> g2 until g0/g1 exhaust, then tail.
constexpr int FULLR = AGB / 3;        // 1041 full rounds
constexpr int FULLB = FULLR * 8;      // 8328 bids in full rounds
constexpr int G2F   = FULLR * 2;      // 2082 g2 tiles from full rounds
constexpr int REM0  = AGB - 3*FULLR;  // 2 leftover g0 tiles
static_assert(3*FULLR + REM0 == AGB, "g0 cover");
static_assert(2*FULLR + (3*AGB - FULLB - 2*REM0) == AGB, "g2 cover");

typedef unsigned short ushort_t;
typedef unsigned int uint_t;
typedef unsigned char uchar_t;
typedef float fl2 __attribute__((ext_vector_type(2)));
typedef float fl4 __attribute__((ext_vector_type(4)));

// ---- workspace layout (element offsets) ----
constexpr size_t X_OFF    = 0;                          // N*H
constexpr size_t NO_OFF   = X_OFF + (size_t)N*H;        // N   deg_out^-1/2
constexpr size_t NI_OFF   = NO_OFF + N;                 // N   deg_in^-1/2
constexpr size_t EL_OFF   = NI_OFF + N;                 // N+1 GAT el (incl supernode)
constexpr size_t ER_OFF   = EL_OFF + (N+1);             // N   GAT er
constexpr size_t EE_OFF   = ER_OFF + N;                 // E   per-edge exp(e) (CSR order)
constexpr size_t IS_OFF   = EE_OFF + E;                 // N   1/softmax-denominator
constexpr size_t ASLF_OFF = IS_OFF + N;                 // N   self-loop numerator
constexpr size_t ASUP_OFF = ASLF_OFF + N;               // N   supernode numerator
constexpr size_t GF = ((ASUP_OFF + N + 255)/256)*256;

constexpr size_t RP_OFF = 0;                            // N+1 row_ptr (CSR by dst)
constexpr size_t CT_OFF = RP_OFF + (N+1);               // N   in-degree count
constexpr size_t SS_OFF = CT_OFF + N;                   // E   src sorted by dst
constexpr size_t GI = ((SS_OFF + E + 255)/256)*256;

// per-graph fp8 h block: 64 B per row (64 x e4m3 = 16 uints); row N = supernode
constexpr size_t GH = (size_t)(N+1)*64;                 // bytes

// fp8 helpers: HW RNE pack/unpack (OCP e4m3 on gfx950)
__device__ inline uint_t f8pack4(float a, float b, float c, float d){
  int r = __builtin_amdgcn_cvt_pk_fp8_f32(a, b, 0, false);
  r = __builtin_amdgcn_cvt_pk_fp8_f32(c, d, r, true);
  return (uint_t)r;
}
__device__ inline fl4 f8up4(uint_t v){
  fl2 lo = __builtin_amdgcn_cvt_pk_f32_fp8((int)v, false);
  fl2 hi = __builtin_amdgcn_cvt_pk_f32_fp8((int)v, true);
  fl4 r; r.x = lo.x; r.y = lo.y; r.z = hi.x; r.w = hi.y;
  return r;
}

// Deterministic bid -> (graph, tile) swizzle for XCD L2 affinity.
// bid%8 in {0,1,2} -> g0, {3,4,5} -> g1, {6,7} -> g2 for the first FULLB bids;
// exact closed-form tail covers the remainder. Bijective onto 3 x [0,AGB).
__device__ inline void swz_tile(int bid, int& g, int& b){
  if (bid < FULLB){
    int r = bid >> 3, s = bid & 7;
    if (s < 3){ g = 0; b = r*3 + s; }
    else if (s < 6){ g = 1; b = r*3 + (s-3); }
    else { g = 2; b = r*2 + (s-6); }
  } else {
    int t = bid - FULLB;
    if (t < REM0){ g = 0; b = 3*FULLR + t; }
    else if (t < 2*REM0){ g = 1; b = 3*FULLR + (t-REM0); }
    else { g = 2; b = G2F + (t-2*REM0); }
  }
}

// ---- prep: range-partitioned LDS histograms, zero global atomics ----
__global__ __launch_bounds__(1024) void k_hist(int* parts_ct, int* parts_no,
    const int* s0,const int* d0,const int* s1,const int* d1,const int* s2,const int* d2) {
  int sl = blockIdx.x, r = blockIdx.y, g = blockIdx.z;
  const int* s = g==0?s0:(g==1?s1:s2);
  const int* d = g==0?d0:(g==1?d1:d2);
  __shared__ int hc[BINS];
  __shared__ int hn[BINS];
  for (int i=threadIdx.x;i<BINS;i+=1024){ hc[i]=0; hn[i]=0; }
  __syncthreads();
  int lo = r*BINS, hi = lo+BINS;
  int e0 = sl*ES, e1 = e0+ES;
  for (int e=e0+threadIdx.x; e<e1; e+=1024){
    int ds = d[e], sr = s[e];
    if (ds>=lo && ds<hi) atomicAdd(&hc[ds-lo],1);
    if (sr>=lo && sr<hi) atomicAdd(&hn[sr-lo],1);
  }
  __syncthreads();
  size_t base = ((size_t)g*BPR + sl)*N + lo;
  for (int i=threadIdx.x;i<BINS;i+=1024){
    parts_ct[base+i]=hc[i];
    parts_no[base+i]=hn[i];
  }
}

// ---- hierarchical exclusive scan of cnt -> rp (all parallel) ----
__global__ __launch_bounds__(1024) void k_scan_local(int* ib, int* pt, const int* parts_ct) {
  int g = blockIdx.y;
  int* ig = ib + (size_t)g*GI;
  int i = blockIdx.x*1024 + threadIdx.x;
  int c = 0;
  if (i < N){
    #pragma unroll
    for (int s=0;s<BPR;s++) c += parts_ct[((size_t)g*BPR+s)*N + i];
    ig[CT_OFF + i] = c;
  }
  __shared__ int sh[1024];
  sh[threadIdx.x] = c; __syncthreads();
  #pragma unroll
  for (int off=1; off<1024; off<<=1){
    int t = (threadIdx.x>=off) ? sh[threadIdx.x-off] : 0;
    __syncthreads();
    sh[threadIdx.x] += t;
    __syncthreads();
  }
  if (i < N) ig[RP_OFF + i] = sh[threadIdx.x] - c;       // local exclusive
  if (threadIdx.x == 1023) pt[g*SCB + blockIdx.x] = sh[1023];
}

__global__ void k_scan_part(int* pt) {
  int g = blockIdx.x;
  __shared__ int sh[SCB];
  int t = threadIdx.x;
  if (t < SCB) sh[t] = pt[g*SCB + t];
  __syncthreads();
  if (t == 0){
    int run = 0;
    for (int b=0;b<SCB;b++){ int c = sh[b]; sh[b] = run; run += c; }
  }
  __syncthreads();
  if (t < SCB) pt[g*SCB + t] = sh[t];
}

__global__ __launch_bounds__(1024) void k_scan_apply(float* fb, int* ib, const int* pt,
                                                     const int* parts_no) {
  int g = blockIdx.y;
  float* fg = fb + (size_t)g*GF;
  int* ig = ib + (size_t)g*GI;
  int i = blockIdx.x*1024 + threadIdx.x;
  if (i >= N) return;
  int base = pt[g*SCB + blockIdx.x];
  int r = ig[RP_OFF + i] + base;
  ig[RP_OFF + i] = r;
  int c = ig[CT_OFF + i];
  int o = 0;
  #pragma unroll
  for (int s=0;s<BPR;s++) o += parts_no[((size_t)g*BPR+s)*N + i];
  fg[NI_OFF + i] = rsqrtf((float)(c+1));                 // +1 self loop
  fg[NO_OFF + i] = rsqrtf((float)(o+1));
  if (i == N-1) ig[RP_OFF + N] = r + c;
}

// per-(slice,bin) exclusive prefix over slices -> exact scatter offsets
__global__ __launch_bounds__(256) void k_slice_off(const int* ib, const int* parts_ct, int* off) {
  int g = blockIdx.y;
  int i = blockIdx.x*256 + threadIdx.x;
  if (i >= N) return;
  int base = ib[(size_t)g*GI + RP_OFF + i];
  #pragma unroll
  for (int s=0;s<BPR;s++){
    size_t idx = ((size_t)g*BPR+s)*N + i;
    off[idx] = base;
    base += parts_ct[idx];
  }
}

// scatter: LDS cursors per range, plain scattered store (no global atomics)
__global__ __launch_bounds__(1024) void k_scatter_r(int* ib, const int* off,
    const int* s0,const int* d0,const int* s1,const int* d1,const int* s2,const int* d2) {
  int sl = blockIdx.x, r = blockIdx.y, g = blockIdx.z;
  const int* s = g==0?s0:(g==1?s1:s2);
  const int* d = g==0?d0:(g==1?d1:d2);
  int* ss = ib + (size_t)g*GI + SS_OFF;
  __shared__ int cur[BINS];
  int lo = r*BINS;
  size_t ob = ((size_t)g*BPR + sl)*N + lo;
  for (int i=threadIdx.x;i<BINS;i+=1024) cur[i] = off[ob+i];
  __syncthreads();
  int e0 = sl*ES, e1 = e0+ES;
  for (int e=e0+threadIdx.x; e<e1; e+=1024){
    int ds = d[e];
    if (ds>=lo && ds<lo+BINS){
      int pos = atomicAdd(&cur[ds-lo],1);
      ss[pos] = s[e];
    }
  }
}

__global__ __launch_bounds__(256) void k_copyx(float* fb, const float* x0,const float* x1,const float* x2) {
  int i = blockIdx.x*256 + threadIdx.x;
  int g = blockIdx.y;
  const float* x = g==0?x0:(g==1?x1:x2);
  if (i < N*H/4) {
    ((float4*)(fb + (size_t)g*GF + X_OFF))[i] = ((const float4*)x)[i];
  }
}

// Tiled matmul: 64 rows/block, 4 threads/row (q = 16-col group), acc[16].
// h = fp8( (x @ W) * no[row] ) -> 64 B/row. Block (0,0) zeroes readout accs.
__global__ __launch_bounds__(256) void k_mm_gcn(float* fb, uchar_t* hb,
    const float* W0,const float* W1,const float* W2, float* sm) {
  if (blockIdx.x==0 && blockIdx.y==0){
    for (int i=threadIdx.x;i<384;i+=256) sm[i]=0.f;
  }
  int g = blockIdx.y;
  const float* W = g==0?W0:(g==1?W1:W2);
  __shared__ float Ws[64*64];
  __shared__ float Xs[64*65];
  float* fg = fb + (size_t)g*GF;
  int row0 = blockIdx.x*64;
  for (int i=threadIdx.x; i<4096; i+=256) Ws[i] = W[i];
  int r = threadIdx.x>>2, q = threadIdx.x&3;
  int row = row0 + r;
  int rowc = row < N ? row : N-1;
  {
    const float4* xr = (const float4*)(fg + X_OFF + (size_t)rowc*64) + q*4;
    float* xd = Xs + r*65 + q*16;
    #pragma unroll
    for (int c=0;c<4;c++){ float4 v = xr[c]; xd[4*c]=v.x; xd[4*c+1]=v.y; xd[4*c+2]=v.z; xd[4*c+3]=v.w; }
  }
  __syncthreads();
  float acc[16];
  #pragma unroll
  for (int j=0;j<16;j++) acc[j]=0.f;
  const float* xrow = Xs + r*65;
  #pragma unroll 8
  for (int k=0;k<64;k++){
    float xk = xrow[k];
    const float* wr = Ws + k*64 + q*16;
    #pragma unroll
    for (int j=0;j<16;j++) acc[j] = fmaf(xk, wr[j], acc[j]);
  }
  if (row >= N) return;
  float sc = fg[NO_OFF + row];
  uint_t pk[4];
  #pragma unroll
  for (int j=0;j<4;j++)
    pk[j] = f8pack4(acc[4*j]*sc, acc[4*j+1]*sc, acc[4*j+2]*sc, acc[4*j+3]*sc);
  *(uint4*)(hb + (size_t)g*GH + (size_t)row*64 + q*16) = *(const uint4*)pk;
}

// Same tiling; h = fp8(x @ Wgat[g]); el/er via quad shfl reduce.
__global__ __launch_bounds__(256) void k_mm_gat(float* fb, uchar_t* hb,
    const float* Wgat, const float* al, const float* ar) {
  int g = blockIdx.y;
  const float* W = Wgat + (size_t)g*4096;
  __shared__ float Ws[64*64];
  __shared__ float Xs[64*65];
  __shared__ float als[64], ars[64];
  float* fg = fb + (size_t)g*GF;
  int row0 = blockIdx.x*64;
  for (int i=threadIdx.x; i<4096; i+=256) Ws[i] = W[i];
  if (threadIdx.x < 64){ als[threadIdx.x] = al[g*64+threadIdx.x]; ars[threadIdx.x] = ar[g*64+threadIdx.x]; }
  int r = threadIdx.x>>2, q = threadIdx.x&3;
  int row = row0 + r;
  int rowc = row < N ? row : N-1;
  {
    const float4* xr = (const float4*)(fg + X_OFF + (size_t)rowc*64) + q*4;
    float* xd = Xs + r*65 + q*16;
    #pragma unroll
    for (int c=0;c<4;c++){ float4 v = xr[c]; xd[4*c]=v.x; xd[4*c+1]=v.y; xd[4*c+2]=v.z; xd[4*c+3]=v.w; }
  }
  __syncthreads();
  float acc[16];
  #pragma unroll
  for (int j=0;j<16;j++) acc[j]=0.f;
  const float* xrow = Xs + r*65;
  #pragma unroll 8
  for (int k=0;k<64;k++){
    float xk = xrow[k];
    const float* wr = Ws + k*64 + q*16;
    #pragma unroll
    for (int j=0;j<16;j++) acc[j] = fmaf(xk, wr[j], acc[j]);
  }
  float el = 0.f, er = 0.f;
  #pragma unroll
  for (int j=0;j<16;j++){ el = fmaf(acc[j], als[q*16+j], el); er = fmaf(acc[j], ars[q*16+j], er); }
  el += __shfl_xor(el,1); el += __shfl_xor(el,2);
  er += __shfl_xor(er,1); er += __shfl_xor(er,2);
  if (row >= N) return;
  uint_t pk[4];
  #pragma unroll
  for (int j=0;j<4;j++)
    pk[j] = f8pack4(acc[4*j], acc[4*j+1], acc[4*j+2], acc[4*j+3]);
  *(uint4*)(hb + (size_t)g*GH + (size_t)row*64 + q*16) = *(const uint4*)pk;
  if (q == 0){
    fg[EL_OFF + row] = el;
    fg[ER_OFF + row] = er;
  }
}

// GCN aggregate (R0 structure + stateless XCD graph affinity + nt hints).
// fp8 rows, 16 lanes/row, dword/lane: one gather instr = 4 edges, 4 lines.
__global__ __launch_bounds__(256) void k_gcn_agg(float* fb, const uchar_t* hb, const int* ib,
    const float* b0, const float* b1, const float* b2, int lay, float* sm, int writex) {
  int g, blk;
  swz_tile(blockIdx.x, g, blk);
  const float* b = (g==0?b0:(g==1?b1:b2)) + lay*64;
  float* fg = fb + (size_t)g*GF;
  const uint_t* hu = (const uint_t*)(hb + (size_t)g*GH);  // 16 uints per row
  const int* ig = ib + (size_t)g*GI;
  int wave = threadIdx.x >> 6, lane = threadIdx.x & 63;
  int q = lane >> 4, u = lane & 15;
  int w = blk*4 + wave;
  const int* rp = ig + RP_OFF;
  const int* ss = ig + SS_OFF;
  fl4 bl = ((const fl4*)b)[u];
  fl4 vs = {0.f,0.f,0.f,0.f}, vm = {0.f,0.f,0.f,0.f};
  __shared__ float ssum[4][64];
  __shared__ float smx[4][64];
  #pragma unroll
  for (int i=0;i<4;i++){
    int node = w + NWAVE*i;
    int s0 = rp[node], s1 = rp[node+1];
    fl4 a = {0.f,0.f,0.f,0.f};
    if (q == 0) a = f8up4(hu[(size_t)node*16 + u]);   // self loop (pre-scaled)
    int k = s0;
    for (; k + 16 <= s1; k += 16){
      int idxv = __builtin_nontemporal_load(&ss[k + (lane & 15)]);
      int i0 = __shfl(idxv, q);
      int i1 = __shfl(idxv, q+4);
      int i2 = __shfl(idxv, q+8);
      int i3 = __shfl(idxv, q+12);
      uint_t v0 = hu[(size_t)i0*16 + u];
      uint_t v1 = hu[(size_t)i1*16 + u];
      uint_t v2 = hu[(size_t)i2*16 + u];
      uint_t v3 = hu[(size_t)i3*16 + u];
      a += (f8up4(v0) + f8up4(v1)) + (f8up4(v2) + f8up4(v3));
    }
    for (; k < s1; k += 4){
      int e = k + q;
      int ec = e < s1 ? e : s1-1;
      int idx = ss[ec];
      float wv = e < s1 ? 1.f : 0.f;
      fl4 f = f8up4(hu[(size_t)idx*16 + u]);
      a.x = fmaf(wv, f.x, a.x); a.y = fmaf(wv, f.y, a.y);
      a.z = fmaf(wv, f.z, a.z); a.w = fmaf(wv, f.w, a.w);
    }
    a.x += __shfl_xor(a.x,16); a.x += __shfl_xor(a.x,32);
    a.y += __shfl_xor(a.y,16); a.y += __shfl_xor(a.y,32);
    a.z += __shfl_xor(a.z,16); a.z += __shfl_xor(a.z,32);
    a.w += __shfl_xor(a.w,16); a.w += __shfl_xor(a.w,32);
    if (q == 0){
      float ni = fg[NI_OFF + node];
      fl4 v;
      v.x = fmaf(a.x, ni, bl.x); v.x = v.x > 0.f ? v.x : 0.f;
      v.y = fmaf(a.y, ni, bl.y); v.y = v.y > 0.f ? v.y : 0.f;
      v.z = fmaf(a.z, ni, bl.z); v.z = v.z > 0.f ? v.z : 0.f;
      v.w = fmaf(a.w, ni, bl.w); v.w = v.w > 0.f ? v.w : 0.f;
      if (writex){
        fl4* xp = (fl4*)(fg + X_OFF + (size_t)node*64);
        __builtin_nontemporal_store(v, &xp[u]);
      }
      vs += v;
      vm.x = fmaxf(vm.x,v.x); vm.y = fmaxf(vm.y,v.y);
      vm.z = fmaxf(vm.z,v.z); vm.w = fmaxf(vm.w,v.w);
    }
  }
  if (q == 0){
    ((fl4*)ssum[wave])[u] = vs;
    ((fl4*)smx[wave])[u]  = vm;
  }
  __syncthreads();
  if (threadIdx.x < 64){
    int t = threadIdx.x;
    float s = ssum[0][t]+ssum[1][t]+ssum[2][t]+ssum[3][t];
    float mx = fmaxf(fmaxf(smx[0][t],smx[1][t]), fmaxf(smx[2][t],smx[3][t]));
    atomicAdd(&sm[g*64 + t], s);
    atomicMax((int*)sm + 192 + g*64 + t, __float_as_int(mx));  // v>=0: int order == float order
  }
}

// readout finalize + cross-graph feature exchange + supernode h row (fp8), el[N]
__global__ void k_exchange(float* fb, uchar_t* hb, float* sm, const float* Wx, const float* bx,
                           const float* Wgat, const float* al, int it) {
  int gt = blockIdx.x;     // target graph
  int t = threadIdx.x;     // 64 threads
  int src, widx;
  if ((it & 1) == 0){ src = (gt==0)?1:(gt==1)?2:0; widx = (gt==0)?1:(gt==1)?0:2; }
  else              { src = (gt==0)?2:(gt==1)?0:1; widx = (gt==0)?5:(gt==1)?3:4; }
  __shared__ float ro[128];
  __shared__ float f[64];
  __shared__ float red[64];
  __shared__ float hsb[64];
  ro[t]      = sm[src*64 + t] * (1.0f/(float)N);
  ro[64 + t] = __int_as_float(((int*)sm)[192 + src*64 + t]);
  __syncthreads();
  float a = bx[widx*64 + t];
  for (int k=0;k<128;k++) a = fmaf(ro[k], Wx[(size_t)widx*8192 + k*64 + t], a);
  a = a > 0.f ? a : 0.f;
  f[t] = a;
  __syncthreads();
  float* fg = fb + (size_t)gt*GF;
  float hs = 0.f;
  for (int k=0;k<64;k++) hs = fmaf(f[k], Wgat[(size_t)gt*4096 + k*64 + t], hs);
  hsb[t] = hs;
  red[t] = hs * al[gt*64 + t];
  __syncthreads();
  if (t < 16){
    uint_t r = f8pack4(hsb[4*t], hsb[4*t+1], hsb[4*t+2], hsb[4*t+3]);
    ((uint_t*)(hb + (size_t)gt*GH + (size_t)N*64))[t] = r;
  }
  if (t == 0){
    float e = 0.f;
    for (int k=0;k<64;k++) e += red[k];
    fg[EL_OFF + N] = e;                      // el for supernode
  }
}

// GAT softmax prep: wave per 4 nodes, interleaved phases (all ss loads ->
// all el gathers -> compute); el table is 200KB/graph so it L2-caches fine.
__global__ __launch_bounds__(256) void k_gat_prep(float* fb, const int* ib) {
  int g = blockIdx.y;
  float* fg = fb + (size_t)g*GF;
  const int* ig = ib + (size_t)g*GI;
  const int* rp = ig + RP_OFF;
  const int* ss = ig + SS_OFF;
  const float* el = fg + EL_OFF;
  float* ee = fg + EE_OFF;
  int wave = threadIdx.x>>6, lane = threadIdx.x&63;
  int w = blockIdx.x*4 + wave;
  float elsup = el[N];
  int node[4], s0[4], s1[4];
  #pragma unroll
  for (int i=0;i<4;i++){ node[i] = w + NWAVE*i; s0[i] = rp[node[i]]; s1[i] = rp[node[i]+1]; }
  float eri[4];
  #pragma unroll
  for (int i=0;i<4;i++) eri[i] = fg[ER_OFF + node[i]];
  int sv[4];
  #pragma unroll
  for (int i=0;i<4;i++){ int e = s0[i] + lane; sv[i] = __builtin_nontemporal_load(&ss[e < s1[i] ? e : 0]); }
  float ev[4];
  #pragma unroll
  for (int i=0;i<4;i++) ev[i] = el[sv[i]];
  #pragma unroll
  for (int i=0;i<4;i++){
    int e = s0[i] + lane;
    float x = ev[i] + eri[i];
    x = x >= 0.f ? x : 0.2f*x;
    float t = 0.f;
    if (e < s1[i]){ t = __expf(x); __builtin_nontemporal_store(t, &ee[e]); }
    float s = t;
    for (int k = s0[i]+64; k < s1[i]; k += 64){          // wave-uniform, ~never
      int e2 = k + lane;
      float t2 = 0.f;
      if (e2 < s1[i]){
        float x2 = el[ss[e2]] + eri[i];
        x2 = x2 >= 0.f ? x2 : 0.2f*x2;
        t2 = __expf(x2);
        __builtin_nontemporal_store(t2, &ee[e2]);
      }
      s += t2;
    }
    #pragma unroll
    for (int m=1;m<64;m<<=1) s += __shfl_xor(s,m);
    if (lane == 0){
      float eself = el[node[i]] + eri[i]; eself = eself >= 0.f ? eself : 0.2f*eself;
      float esup  = elsup + eri[i];       esup  = esup  >= 0.f ? esup  : 0.2f*esup;
      float ts = __expf(eself), tu = __expf(esup);
      s += ts + tu;
      fg[IS_OFF + node[i]]   = 1.0f / s;
      fg[ASLF_OFF + node[i]] = ts;
      fg[ASUP_OFF + node[i]] = tu;
    }
  }
}

// GAT aggregation (R0 structure + stateless XCD graph affinity + nt hints).
__global__ __launch_bounds__(256) void k_gat_agg(float* fb, const uchar_t* hb, const int* ib,
    const float* bgat) {
  int g, blk;
  swz_tile(blockIdx.x, g, blk);
  float* fg = fb + (size_t)g*GF;
  const uint_t* hu = (const uint_t*)(hb + (size_t)g*GH);
  const int* ig = ib + (size_t)g*GI;
  int wave = threadIdx.x >> 6, lane = threadIdx.x & 63;
  int q = lane >> 4, u = lane & 15;
  int w = blk*4 + wave;
  const int* rp = ig + RP_OFF;
  const int* ss = ig + SS_OFF;
  const float* ee = fg + EE_OFF;
  fl4 bg = ((const fl4*)(bgat + g*64))[u];
  fl4 supf = f8up4(hu[(size_t)N*16 + u]);
  #pragma unroll
  for (int i=0;i<4;i++){
    int node = w + NWAVE*i;
    int s0 = rp[node], s1 = rp[node+1];
    fl4 a = {0.f,0.f,0.f,0.f};
    if (q == 0){
      float aslf = fg[ASLF_OFF + node];
      fl4 f = f8up4(hu[(size_t)node*16 + u]);
      a.x = aslf*f.x; a.y = aslf*f.y; a.z = aslf*f.z; a.w = aslf*f.w;
    } else if (q == 1){
      float asup = fg[ASUP_OFF + node];
      a.x = asup*supf.x; a.y = asup*supf.y; a.z = asup*supf.z; a.w = asup*supf.w;
    }
    int k = s0;
    for (; k + 16 <= s1; k += 16){
      int idxv = __builtin_nontemporal_load(&ss[k + (lane & 15)]);
      float wtv = __builtin_nontemporal_load(&ee[k + (lane & 15)]);
      int i0 = __shfl(idxv, q);
      int i1 = __shfl(idxv, q+4);
      int i2 = __shfl(idxv, q+8);
      int i3 = __shfl(idxv, q+12);
      float w0 = __shfl(wtv, q);
      float w1 = __shfl(wtv, q+4);
      float w2 = __shfl(wtv, q+8);
      float w3 = __shfl(wtv, q+12);
      uint_t v0 = hu[(size_t)i0*16 + u];
      uint_t v1 = hu[(size_t)i1*16 + u];
      uint_t v2 = hu[(size_t)i2*16 + u];
      uint_t v3 = hu[(size_t)i3*16 + u];
      fl4 f0=f8up4(v0), f1=f8up4(v1), f2=f8up4(v2), f3=f8up4(v3);
      a.x += (fmaf(w0,f0.x, w1*f1.x)) + (fmaf(w2,f2.x, w3*f3.x));
      a.y += (fmaf(w0,f0.y, w1*f1.y)) + (fmaf(w2,f2.y, w3*f3.y));
      a.z += (fmaf(w0,f0.z, w1*f1.z)) + (fmaf(w2,f2.z, w3*f3.z));
      a.w += (fmaf(w0,f0.w, w1*f1.w)) + (fmaf(w2,f2.w, w3*f3.w));
    }
    for (; k < s1; k += 4){
      int e = k + q;
      int ec = e < s1 ? e : s1-1;
      int idx = ss[ec];
      float wv = e < s1 ? ee[ec] : 0.f;
      fl4 f = f8up4(hu[(size_t)idx*16 + u]);
      a.x = fmaf(wv, f.x, a.x); a.y = fmaf(wv, f.y, a.y);
      a.z = fmaf(wv, f.z, a.z); a.w = fmaf(wv, f.w, a.w);
    }
    a.x += __shfl_xor(a.x,16); a.x += __shfl_xor(a.x,32);
    a.y += __shfl_xor(a.y,16); a.y += __shfl_xor(a.y,32);
    a.z += __shfl_xor(a.z,16); a.z += __shfl_xor(a.z,32);
    a.w += __shfl_xor(a.w,16); a.w += __shfl_xor(a.w,32);
    if (q == 0){
      float is = fg[IS_OFF + node];
      fl4 v;
      v.x = fmaf(a.x, is, bg.x); v.y = fmaf(a.y, is, bg.y);
      v.z = fmaf(a.z, is, bg.z); v.w = fmaf(a.w, is, bg.w);
      fl4* xp = (fl4*)(fg + X_OFF + (size_t)node*64);
      __builtin_nontemporal_store(v, &xp[u]);
    }
  }
}

__global__ __launch_bounds__(384) void k_mlp(const float* sm, const float* W1, const float* b1,
    const float* W2, const float* b2, const float* W3, const float* b3, float* out) {
  __shared__ float nf[384];
  __shared__ float y1[192];
  __shared__ float y2[96];
  __shared__ float z[2];
  int t = threadIdx.x;
  int g = t / 128, j = t % 128;
  nf[t] = (j < 64) ? sm[g*64 + j] * (1.0f/(float)N)
                   : __int_as_float(((const int*)sm)[192 + g*64 + (j-64)]);
  __syncthreads();
  if (t < 192){
    float a = b1[t];
    for (int k=0;k<384;k++) a = fmaf(nf[k], W1[(size_t)k*192 + t], a);
    y1[t] = a > 0.f ? a : 0.f;
  }
  __syncthreads();
  if (t < 96){
    float a = b2[t];
    for (int k=0;k<192;k++) a = fmaf(y1[k], W2[(size_t)k*96 + t], a);
    y2[t] = a > 0.f ? a : 0.f;
  }
  __syncthreads();
  if (t < 2){
    float a = b3[t];
    for (int k=0;k<96;k++) a = fmaf(y2[k], W3[k*2 + t], a);
    z[t] = a;
  }
  __syncthreads();
  if (t == 0){
    float m = fmaxf(z[0], z[1]);
    float l = m + logf(__expf(z[0]-m) + __expf(z[1]-m));
    out[0] = z[0] - l;
    out[1] = z[1] - l;
  }
}

extern "C" void kernel_launch(void* const* d_in, const int* in_sizes, int n_in,
                              void* d_out, int out_size, void* d_ws, size_t ws_size,
                              hipStream_t stream) {
  const float* x_s  = (const float*)d_in[0];
  const float* x_g  = (const float*)d_in[1];
  const float* x_t  = (const float*)d_in[2];
  const float* Wc_s = (const float*)d_in[3];
  const float* bc_s = (const float*)d_in[4];
  const float* Wc_g = (const float*)d_in[5];
  const float* bc_g = (const float*)d_in[6];
  const float* Wc_t = (const float*)d_in[7];
  const float* bc_t = (const float*)d_in[8];
  const float* Wx   = (const float*)d_in[9];
  const float* bx   = (const float*)d_in[10];
  const float* Wgat = (const float*)d_in[11];
  const float* al   = (const float*)d_in[12];
  const float* ar   = (const float*)d_in[13];
  const float* bgat = (const float*)d_in[14];
  const float* W1   = (const float*)d_in[15];
  const float* b1   = (const float*)d_in[16];
  const float* W2   = (const float*)d_in[17];
  const float* b2   = (const float*)d_in[18];
  const float* W3   = (const float*)d_in[19];
  const float* b3   = (const float*)d_in[20];
  const int* src_s  = (const int*)d_in[21];
  const int* dst_s  = (const int*)d_in[22];
  const int* src_g  = (const int*)d_in[23];
  const int* dst_g  = (const int*)d_in[24];
  const int* src_t  = (const int*)d_in[25];
  const int* dst_t  = (const int*)d_in[26];

  float* fb = (float*)d_ws;
  int*   ib = (int*)(fb + 3*GF);
  uchar_t* hb = (uchar_t*)(ib + 3*GI);
  float* sm = (float*)(hb + 3*GH);
  int*   pt = (int*)(sm + 384);              // 3*SCB scan partials
  int*   parts_ct = pt + 3*SCB + 64;         // 3*BPR*N
  int*   parts_no = parts_ct + (size_t)3*BPR*N;
  int*   off      = parts_no + (size_t)3*BPR*N;
  float* out = (float*)d_out;

  dim3 b256(256);
  int mmb = (N+63)/64;

  // graph prep: LDS-histogram counting sort (no global atomics)
  k_hist      <<<dim3(BPR, RNG, 3),  dim3(1024), 0, stream>>>(parts_ct, parts_no, src_s,dst_s, src_g,dst_g, src_t,dst_t);
  k_scan_local<<<dim3(SCB, 3),       dim3(1024), 0, stream>>>(ib, pt, parts_ct);
  k_scan_part <<<dim3(3),              dim3(64), 0, stream>>>(pt);
  k_scan_apply<<<dim3(SCB, 3),       dim3(1024), 0, stream>>>(fb, ib, pt, parts_no);
  k_slice_off <<<dim3((N+255)/256, 3),     b256, 0, stream>>>(ib, parts_ct, off);
  k_scatter_r <<<dim3(BPR, RNG, 3),  dim3(1024), 0, stream>>>(ib, off, src_s,dst_s, src_g,dst_g, src_t,dst_t);
  k_copyx     <<<dim3((N*H/4+255)/256, 3), b256, 0, stream>>>(fb, x_s, x_g, x_t);

  for (int it = 0; it < 2; ++it) {
    k_mm_gcn  <<<dim3(mmb, 3),     b256, 0, stream>>>(fb, hb, Wc_s + it*4096, Wc_g + it*4096, Wc_t + it*4096, sm);
    k_gcn_agg <<<dim3(3*AGB),      b256, 0, stream>>>(fb, hb, ib, bc_s, bc_g, bc_t, it, sm, 1);
    k_exchange<<<dim3(3), dim3(64), 0, stream>>>(fb, hb, sm, Wx, bx, Wgat, al, it);
    k_mm_gat  <<<dim3(mmb, 3),     b256, 0, stream>>>(fb, hb, Wgat, al, ar);
    k_gat_prep<<<dim3(AGB, 3),     b256, 0, stream>>>(fb, ib);
    k_gat_agg <<<dim3(3*AGB),      b256, 0, stream>>>(fb, hb, ib, bgat);
  }

  // final layer readouts + MLP head (x write skipped — only readout consumed)
  k_mm_gcn  <<<dim3(mmb, 3),     b256, 0, stream>>>(fb, hb, Wc_s + 2*4096, Wc_g + 2*4096, Wc_t + 2*4096, sm);
  k_gcn_agg <<<dim3(3*AGB),      b256, 0, stream>>>(fb, hb, ib, bc_s, bc_g, bc_t, 2, sm, 0);
  k_mlp     <<<1, 384, 0, stream>>>(sm, W1, b1, W2, b2, W3, b3, out);
}

// Round 4
// 943.240 us; speedup vs baseline: 1.3954x; 1.0610x over previous
//
#include <hip/hip_runtime.h>
#include <math.h>

constexpr int N = 50000;
constexpr int E = 800000;
constexpr int H = 64;
constexpr int NWAVE = 12500;          // N/4 nodes-per-wave mapping (4 nodes per wave)
constexpr int AGB = 3125;             // agg blocks (tiles) per graph (NWAVE/4)
constexpr int SCB = 49;               // scan blocks per graph: 49*1024 >= N
constexpr int RNG = 8;                // histogram ranges per graph
constexpr int BPR = 8;                // edge slices per graph
constexpr int BINS = N / RNG;         // 6250 bins per range
constexpr int ES   = E / BPR;         // 100000 edges per slice

// XCD-affinity swizzle constants (stateless, replay-safe).
// Default dispatch round-robins blockIdx across 8 XCDs; rounds of 8 blocks:
// slots 0-2 -> g0, 3-5 -> g1, 6-7 -> g2 until g0/g1 exhaust, then tail.
constexpr int FULLR = AGB / 3;        // 1041 full rounds
constexpr int FULLB = FULLR * 8;      // 8328 bids in full rounds
constexpr int G2F   = FULLR * 2;      // 2082 g2 tiles from full rounds
constexpr int REM0  = AGB - 3*FULLR;  // 2 leftover g0 tiles
static_assert(3*FULLR + REM0 == AGB, "g0 cover");
static_assert(2*FULLR + (3*AGB - FULLB - 2*REM0) == AGB, "g2 cover");

typedef unsigned short ushort_t;
typedef unsigned int uint_t;
typedef unsigned char uchar_t;
typedef float fl2 __attribute__((ext_vector_type(2)));
typedef float fl4 __attribute__((ext_vector_type(4)));

// ---- workspace layout (element offsets) ----
constexpr size_t X_OFF    = 0;                          // N*H
constexpr size_t NO_OFF   = X_OFF + (size_t)N*H;        // N   deg_out^-1/2
constexpr size_t NI_OFF   = NO_OFF + N;                 // N   deg_in^-1/2
constexpr size_t EL_OFF   = NI_OFF + N;                 // N+1 GAT el (incl supernode)
constexpr size_t ER_OFF   = EL_OFF + (N+1);             // N   GAT er
constexpr size_t EE_OFF   = ER_OFF + N;                 // E   per-edge exp(e) (CSR order)
constexpr size_t IS_OFF   = EE_OFF + E;                 // N   1/softmax-denominator
constexpr size_t ASLF_OFF = IS_OFF + N;                 // N   self-loop numerator
constexpr size_t ASUP_OFF = ASLF_OFF + N;               // N   supernode numerator
constexpr size_t GF = ((ASUP_OFF + N + 255)/256)*256;

constexpr size_t RP_OFF = 0;                            // N+1 row_ptr (CSR by dst)
constexpr size_t CT_OFF = RP_OFF + (N+1);               // N   in-degree count
constexpr size_t SS_OFF = CT_OFF + N;                   // E   src sorted by dst
constexpr size_t GI = ((SS_OFF + E + 255)/256)*256;

// per-graph fp8 h block: 64 B per row (64 x e4m3 = 16 uints); row N = supernode
constexpr size_t GH = (size_t)(N+1)*64;                 // bytes

// fp8 helpers: HW RNE pack/unpack (OCP e4m3 on gfx950)
__device__ inline uint_t f8pack4(float a, float b, float c, float d){
  int r = __builtin_amdgcn_cvt_pk_fp8_f32(a, b, 0, false);
  r = __builtin_amdgcn_cvt_pk_fp8_f32(c, d, r, true);
  return (uint_t)r;
}
__device__ inline fl4 f8up4(uint_t v){
  fl2 lo = __builtin_amdgcn_cvt_pk_f32_fp8((int)v, false);
  fl2 hi = __builtin_amdgcn_cvt_pk_f32_fp8((int)v, true);
  fl4 r; r.x = lo.x; r.y = lo.y; r.z = hi.x; r.w = hi.y;
  return r;
}

// Deterministic bid -> (graph, tile) swizzle for XCD L2 affinity.
// bid%8 in {0,1,2} -> g0, {3,4,5} -> g1, {6,7} -> g2 for the first FULLB bids;
// exact closed-form tail covers the remainder. Bijective onto 3 x [0,AGB).
__device__ inline void swz_tile(int bid, int& g, int& b){
  if (bid < FULLB){
    int r = bid >> 3, s = bid & 7;
    if (s < 3){ g = 0; b = r*3 + s; }
    else if (s < 6){ g = 1; b = r*3 + (s-3); }
    else { g = 2; b = r*2 + (s-6); }
  } else {
    int t = bid - FULLB;
    if (t < REM0){ g = 0; b = 3*FULLR + t; }
    else if (t < 2*REM0){ g = 1; b = 3*FULLR + (t-REM0); }
    else { g = 2; b = G2F + (t-2*REM0); }
  }
}

// ---- prep: range-partitioned LDS histograms, zero global atomics ----
__global__ __launch_bounds__(1024) void k_hist(int* parts_ct, int* parts_no,
    const int* s0,const int* d0,const int* s1,const int* d1,const int* s2,const int* d2) {
  int sl = blockIdx.x, r = blockIdx.y, g = blockIdx.z;
  const int* s = g==0?s0:(g==1?s1:s2);
  const int* d = g==0?d0:(g==1?d1:d2);
  __shared__ int hc[BINS];
  __shared__ int hn[BINS];
  for (int i=threadIdx.x;i<BINS;i+=1024){ hc[i]=0; hn[i]=0; }
  __syncthreads();
  int lo = r*BINS, hi = lo+BINS;
  int e0 = sl*ES, e1 = e0+ES;
  for (int e=e0+threadIdx.x; e<e1; e+=1024){
    int ds = d[e], sr = s[e];
    if (ds>=lo && ds<hi) atomicAdd(&hc[ds-lo],1);
    if (sr>=lo && sr<hi) atomicAdd(&hn[sr-lo],1);
  }
  __syncthreads();
  size_t base = ((size_t)g*BPR + sl)*N + lo;
  for (int i=threadIdx.x;i<BINS;i+=1024){
    parts_ct[base+i]=hc[i];
    parts_no[base+i]=hn[i];
  }
}

// ---- hierarchical exclusive scan of cnt -> rp (all parallel) ----
__global__ __launch_bounds__(1024) void k_scan_local(int* ib, int* pt, const int* parts_ct) {
  int g = blockIdx.y;
  int* ig = ib + (size_t)g*GI;
  int i = blockIdx.x*1024 + threadIdx.x;
  int c = 0;
  if (i < N){
    #pragma unroll
    for (int s=0;s<BPR;s++) c += parts_ct[((size_t)g*BPR+s)*N + i];
    ig[CT_OFF + i] = c;
  }
  __shared__ int sh[1024];
  sh[threadIdx.x] = c; __syncthreads();
  #pragma unroll
  for (int off=1; off<1024; off<<=1){
    int t = (threadIdx.x>=off) ? sh[threadIdx.x-off] : 0;
    __syncthreads();
    sh[threadIdx.x] += t;
    __syncthreads();
  }
  if (i < N) ig[RP_OFF + i] = sh[threadIdx.x] - c;       // local exclusive
  if (threadIdx.x == 1023) pt[g*SCB + blockIdx.x] = sh[1023];
}

__global__ void k_scan_part(int* pt) {
  int g = blockIdx.x;
  __shared__ int sh[SCB];
  int t = threadIdx.x;
  if (t < SCB) sh[t] = pt[g*SCB + t];
  __syncthreads();
  if (t == 0){
    int run = 0;
    for (int b=0;b<SCB;b++){ int c = sh[b]; sh[b] = run; run += c; }
  }
  __syncthreads();
  if (t < SCB) pt[g*SCB + t] = sh[t];
}

__global__ __launch_bounds__(1024) void k_scan_apply(float* fb, int* ib, const int* pt,
                                                     const int* parts_no) {
  int g = blockIdx.y;
  float* fg = fb + (size_t)g*GF;
  int* ig = ib + (size_t)g*GI;
  int i = blockIdx.x*1024 + threadIdx.x;
  if (i >= N) return;
  int base = pt[g*SCB + blockIdx.x];
  int r = ig[RP_OFF + i] + base;
  ig[RP_OFF + i] = r;
  int c = ig[CT_OFF + i];
  int o = 0;
  #pragma unroll
  for (int s=0;s<BPR;s++) o += parts_no[((size_t)g*BPR+s)*N + i];
  fg[NI_OFF + i] = rsqrtf((float)(c+1));                 // +1 self loop
  fg[NO_OFF + i] = rsqrtf((float)(o+1));
  if (i == N-1) ig[RP_OFF + N] = r + c;
}

// per-(slice,bin) exclusive prefix over slices -> exact scatter offsets
__global__ __launch_bounds__(256) void k_slice_off(const int* ib, const int* parts_ct, int* off) {
  int g = blockIdx.y;
  int i = blockIdx.x*256 + threadIdx.x;
  if (i >= N) return;
  int base = ib[(size_t)g*GI + RP_OFF + i];
  #pragma unroll
  for (int s=0;s<BPR;s++){
    size_t idx = ((size_t)g*BPR+s)*N + i;
    off[idx] = base;
    base += parts_ct[idx];
  }
}

// scatter: LDS cursors per range, plain scattered store (no global atomics)
__global__ __launch_bounds__(1024) void k_scatter_r(int* ib, const int* off,
    const int* s0,const int* d0,const int* s1,const int* d1,const int* s2,const int* d2) {
  int sl = blockIdx.x, r = blockIdx.y, g = blockIdx.z;
  const int* s = g==0?s0:(g==1?s1:s2);
  const int* d = g==0?d0:(g==1?d1:d2);
  int* ss = ib + (size_t)g*GI + SS_OFF;
  __shared__ int cur[BINS];
  int lo = r*BINS;
  size_t ob = ((size_t)g*BPR + sl)*N + lo;
  for (int i=threadIdx.x;i<BINS;i+=1024) cur[i] = off[ob+i];
  __syncthreads();
  int e0 = sl*ES, e1 = e0+ES;
  for (int e=e0+threadIdx.x; e<e1; e+=1024){
    int ds = d[e];
    if (ds>=lo && ds<lo+BINS){
      int pos = atomicAdd(&cur[ds-lo],1);
      ss[pos] = s[e];
    }
  }
}

__global__ __launch_bounds__(256) void k_copyx(float* fb, const float* x0,const float* x1,const float* x2) {
  int i = blockIdx.x*256 + threadIdx.x;
  int g = blockIdx.y;
  const float* x = g==0?x0:(g==1?x1:x2);
  if (i < N*H/4) {
    ((float4*)(fb + (size_t)g*GF + X_OFF))[i] = ((const float4*)x)[i];
  }
}

// Tiled matmul: 64 rows/block, 4 threads/row (q = 16-col group), acc[16].
// h = fp8( (x @ W) * no[row] ) -> 64 B/row. Block (0,0) zeroes readout accs.
__global__ __launch_bounds__(256) void k_mm_gcn(float* fb, uchar_t* hb,
    const float* W0,const float* W1,const float* W2, float* sm) {
  if (blockIdx.x==0 && blockIdx.y==0){
    for (int i=threadIdx.x;i<384;i+=256) sm[i]=0.f;
  }
  int g = blockIdx.y;
  const float* W = g==0?W0:(g==1?W1:W2);
  __shared__ float Ws[64*64];
  __shared__ float Xs[64*65];
  float* fg = fb + (size_t)g*GF;
  int row0 = blockIdx.x*64;
  for (int i=threadIdx.x; i<4096; i+=256) Ws[i] = W[i];
  int r = threadIdx.x>>2, q = threadIdx.x&3;
  int row = row0 + r;
  int rowc = row < N ? row : N-1;
  {
    const float4* xr = (const float4*)(fg + X_OFF + (size_t)rowc*64) + q*4;
    float* xd = Xs + r*65 + q*16;
    #pragma unroll
    for (int c=0;c<4;c++){ float4 v = xr[c]; xd[4*c]=v.x; xd[4*c+1]=v.y; xd[4*c+2]=v.z; xd[4*c+3]=v.w; }
  }
  __syncthreads();
  float acc[16];
  #pragma unroll
  for (int j=0;j<16;j++) acc[j]=0.f;
  const float* xrow = Xs + r*65;
  #pragma unroll 8
  for (int k=0;k<64;k++){
    float xk = xrow[k];
    const float* wr = Ws + k*64 + q*16;
    #pragma unroll
    for (int j=0;j<16;j++) acc[j] = fmaf(xk, wr[j], acc[j]);
  }
  if (row >= N) return;
  float sc = fg[NO_OFF + row];
  uint_t pk[4];
  #pragma unroll
  for (int j=0;j<4;j++)
    pk[j] = f8pack4(acc[4*j]*sc, acc[4*j+1]*sc, acc[4*j+2]*sc, acc[4*j+3]*sc);
  *(uint4*)(hb + (size_t)g*GH + (size_t)row*64 + q*16) = *(const uint4*)pk;
}

// Same tiling; h = fp8(x @ Wgat[g]); el/er via quad shfl reduce.
__global__ __launch_bounds__(256) void k_mm_gat(float* fb, uchar_t* hb,
    const float* Wgat, const float* al, const float* ar) {
  int g = blockIdx.y;
  const float* W = Wgat + (size_t)g*4096;
  __shared__ float Ws[64*64];
  __shared__ float Xs[64*65];
  __shared__ float als[64], ars[64];
  float* fg = fb + (size_t)g*GF;
  int row0 = blockIdx.x*64;
  for (int i=threadIdx.x; i<4096; i+=256) Ws[i] = W[i];
  if (threadIdx.x < 64){ als[threadIdx.x] = al[g*64+threadIdx.x]; ars[threadIdx.x] = ar[g*64+threadIdx.x]; }
  int r = threadIdx.x>>2, q = threadIdx.x&3;
  int row = row0 + r;
  int rowc = row < N ? row : N-1;
  {
    const float4* xr = (const float4*)(fg + X_OFF + (size_t)rowc*64) + q*4;
    float* xd = Xs + r*65 + q*16;
    #pragma unroll
    for (int c=0;c<4;c++){ float4 v = xr[c]; xd[4*c]=v.x; xd[4*c+1]=v.y; xd[4*c+2]=v.z; xd[4*c+3]=v.w; }
  }
  __syncthreads();
  float acc[16];
  #pragma unroll
  for (int j=0;j<16;j++) acc[j]=0.f;
  const float* xrow = Xs + r*65;
  #pragma unroll 8
  for (int k=0;k<64;k++){
    float xk = xrow[k];
    const float* wr = Ws + k*64 + q*16;
    #pragma unroll
    for (int j=0;j<16;j++) acc[j] = fmaf(xk, wr[j], acc[j]);
  }
  float el = 0.f, er = 0.f;
  #pragma unroll
  for (int j=0;j<16;j++){ el = fmaf(acc[j], als[q*16+j], el); er = fmaf(acc[j], ars[q*16+j], er); }
  el += __shfl_xor(el,1); el += __shfl_xor(el,2);
  er += __shfl_xor(er,1); er += __shfl_xor(er,2);
  if (row >= N) return;
  uint_t pk[4];
  #pragma unroll
  for (int j=0;j<4;j++)
    pk[j] = f8pack4(acc[4*j], acc[4*j+1], acc[4*j+2], acc[4*j+3]);
  *(uint4*)(hb + (size_t)g*GH + (size_t)row*64 + q*16) = *(const uint4*)pk;
  if (q == 0){
    fg[EL_OFF + row] = el;
    fg[ER_OFF + row] = er;
  }
}

// GCN aggregate (XCD affinity + short-chain edge loop).
// Chain cuts vs R3: (1) single predicated 16-edge round replaces the 4-edge
// tail (wave-uniform branch, clamped idx, weight 0); (2) round-1 ss indices
// prefetched for all 4 nodes upfront; round k+1's ss issued before round k's
// gathers are consumed. ~24 -> ~10 chained latencies per wave.
__global__ __launch_bounds__(256) void k_gcn_agg(float* fb, const uchar_t* hb, const int* ib,
    const float* b0, const float* b1, const float* b2, int lay, float* sm, int writex) {
  int g, blk;
  swz_tile(blockIdx.x, g, blk);
  const float* b = (g==0?b0:(g==1?b1:b2)) + lay*64;
  float* fg = fb + (size_t)g*GF;
  const uint_t* hu = (const uint_t*)(hb + (size_t)g*GH);  // 16 uints per row
  const int* ig = ib + (size_t)g*GI;
  int wave = threadIdx.x >> 6, lane = threadIdx.x & 63;
  int q = lane >> 4, u = lane & 15, l15 = lane & 15;
  int w = blk*4 + wave;
  const int* rp = ig + RP_OFF;
  const int* ss = ig + SS_OFF;
  fl4 bl = ((const fl4*)b)[u];
  fl4 vs = {0.f,0.f,0.f,0.f}, vm = {0.f,0.f,0.f,0.f};
  __shared__ float ssum[4][64];
  __shared__ float smx[4][64];

  // upfront independent loads: rp, round-1 ss, ni for all 4 nodes
  int s0a[4], s1a[4];
  #pragma unroll
  for (int i=0;i<4;i++){ int nd = w + NWAVE*i; s0a[i] = rp[nd]; s1a[i] = rp[nd+1]; }
  int iv0[4]; float nia[4];
  #pragma unroll
  for (int i=0;i<4;i++){
    int ei = s0a[i] + l15;
    int ec = ei < s1a[i] ? ei : s0a[i];
    iv0[i] = __builtin_nontemporal_load(&ss[ec]);
    nia[i] = fg[NI_OFF + (w + NWAVE*i)];
  }

  #pragma unroll
  for (int i=0;i<4;i++){
    int node = w + NWAVE*i;
    int s0 = s0a[i], s1 = s1a[i];
    fl4 a = {0.f,0.f,0.f,0.f};
    if (q == 0) a = f8up4(hu[(size_t)node*16 + u]);   // self loop (pre-scaled)
    int idxv = iv0[i];
    for (int k = s0; k < s1; k += 16){
      int i0 = __shfl(idxv, q);
      int i1 = __shfl(idxv, q+4);
      int i2 = __shfl(idxv, q+8);
      int i3 = __shfl(idxv, q+12);
      uint_t v0 = hu[(size_t)i0*16 + u];
      uint_t v1 = hu[(size_t)i1*16 + u];
      uint_t v2 = hu[(size_t)i2*16 + u];
      uint_t v3 = hu[(size_t)i3*16 + u];
      int kn = k + 16;
      if (kn < s1){                        // prefetch next round (wave-uniform)
        int ei = kn + l15;
        int ec = ei < s1 ? ei : s0;
        idxv = __builtin_nontemporal_load(&ss[ec]);
      }
      if (kn <= s1){                       // full round
        a += (f8up4(v0) + f8up4(v1)) + (f8up4(v2) + f8up4(v3));
      } else {                             // partial round: predicated slots
        fl4 f0=f8up4(v0), f1=f8up4(v1), f2=f8up4(v2), f3=f8up4(v3);
        float w0 = (k+q   ) < s1 ? 1.f : 0.f;
        float w1 = (k+q+4 ) < s1 ? 1.f : 0.f;
        float w2 = (k+q+8 ) < s1 ? 1.f : 0.f;
        float w3 = (k+q+12) < s1 ? 1.f : 0.f;
        a.x += fmaf(w0,f0.x, w1*f1.x) + fmaf(w2,f2.x, w3*f3.x);
        a.y += fmaf(w0,f0.y, w1*f1.y) + fmaf(w2,f2.y, w3*f3.y);
        a.z += fmaf(w0,f0.z, w1*f1.z) + fmaf(w2,f2.z, w3*f3.z);
        a.w += fmaf(w0,f0.w, w1*f1.w) + fmaf(w2,f2.w, w3*f3.w);
      }
    }
    a.x += __shfl_xor(a.x,16); a.x += __shfl_xor(a.x,32);
    a.y += __shfl_xor(a.y,16); a.y += __shfl_xor(a.y,32);
    a.z += __shfl_xor(a.z,16); a.z += __shfl_xor(a.z,32);
    a.w += __shfl_xor(a.w,16); a.w += __shfl_xor(a.w,32);
    if (q == 0){
      float ni = nia[i];
      fl4 v;
      v.x = fmaf(a.x, ni, bl.x); v.x = v.x > 0.f ? v.x : 0.f;
      v.y = fmaf(a.y, ni, bl.y); v.y = v.y > 0.f ? v.y : 0.f;
      v.z = fmaf(a.z, ni, bl.z); v.z = v.z > 0.f ? v.z : 0.f;
      v.w = fmaf(a.w, ni, bl.w); v.w = v.w > 0.f ? v.w : 0.f;
      if (writex){
        fl4* xp = (fl4*)(fg + X_OFF + (size_t)node*64);
        __builtin_nontemporal_store(v, &xp[u]);
      }
      vs += v;
      vm.x = fmaxf(vm.x,v.x); vm.y = fmaxf(vm.y,v.y);
      vm.z = fmaxf(vm.z,v.z); vm.w = fmaxf(vm.w,v.w);
    }
  }
  if (q == 0){
    ((fl4*)ssum[wave])[u] = vs;
    ((fl4*)smx[wave])[u]  = vm;
  }
  __syncthreads();
  if (threadIdx.x < 64){
    int t = threadIdx.x;
    float s = ssum[0][t]+ssum[1][t]+ssum[2][t]+ssum[3][t];
    float mx = fmaxf(fmaxf(smx[0][t],smx[1][t]), fmaxf(smx[2][t],smx[3][t]));
    atomicAdd(&sm[g*64 + t], s);
    atomicMax((int*)sm + 192 + g*64 + t, __float_as_int(mx));  // v>=0: int order == float order
  }
}

// readout finalize + cross-graph feature exchange + supernode h row (fp8), el[N]
__global__ void k_exchange(float* fb, uchar_t* hb, float* sm, const float* Wx, const float* bx,
                           const float* Wgat, const float* al, int it) {
  int gt = blockIdx.x;     // target graph
  int t = threadIdx.x;     // 64 threads
  int src, widx;
  if ((it & 1) == 0){ src = (gt==0)?1:(gt==1)?2:0; widx = (gt==0)?1:(gt==1)?0:2; }
  else              { src = (gt==0)?2:(gt==1)?0:1; widx = (gt==0)?5:(gt==1)?3:4; }
  __shared__ float ro[128];
  __shared__ float f[64];
  __shared__ float red[64];
  __shared__ float hsb[64];
  ro[t]      = sm[src*64 + t] * (1.0f/(float)N);
  ro[64 + t] = __int_as_float(((int*)sm)[192 + src*64 + t]);
  __syncthreads();
  float a = bx[widx*64 + t];
  for (int k=0;k<128;k++) a = fmaf(ro[k], Wx[(size_t)widx*8192 + k*64 + t], a);
  a = a > 0.f ? a : 0.f;
  f[t] = a;
  __syncthreads();
  float* fg = fb + (size_t)gt*GF;
  float hs = 0.f;
  for (int k=0;k<64;k++) hs = fmaf(f[k], Wgat[(size_t)gt*4096 + k*64 + t], hs);
  hsb[t] = hs;
  red[t] = hs * al[gt*64 + t];
  __syncthreads();
  if (t < 16){
    uint_t r = f8pack4(hsb[4*t], hsb[4*t+1], hsb[4*t+2], hsb[4*t+3]);
    ((uint_t*)(hb + (size_t)gt*GH + (size_t)N*64))[t] = r;
  }
  if (t == 0){
    float e = 0.f;
    for (int k=0;k<64;k++) e += red[k];
    fg[EL_OFF + N] = e;                      // el for supernode
  }
}

// GAT softmax prep: wave per 4 nodes, interleaved phases (all ss loads ->
// all el gathers -> compute); el table is 200KB/graph so it L2-caches fine.
__global__ __launch_bounds__(256) void k_gat_prep(float* fb, const int* ib) {
  int g = blockIdx.y;
  float* fg = fb + (size_t)g*GF;
  const int* ig = ib + (size_t)g*GI;
  const int* rp = ig + RP_OFF;
  const int* ss = ig + SS_OFF;
  const float* el = fg + EL_OFF;
  float* ee = fg + EE_OFF;
  int wave = threadIdx.x>>6, lane = threadIdx.x&63;
  int w = blockIdx.x*4 + wave;
  float elsup = el[N];
  int node[4], s0[4], s1[4];
  #pragma unroll
  for (int i=0;i<4;i++){ node[i] = w + NWAVE*i; s0[i] = rp[node[i]]; s1[i] = rp[node[i]+1]; }
  float eri[4];
  #pragma unroll
  for (int i=0;i<4;i++) eri[i] = fg[ER_OFF + node[i]];
  int sv[4];
  #pragma unroll
  for (int i=0;i<4;i++){ int e = s0[i] + lane; sv[i] = __builtin_nontemporal_load(&ss[e < s1[i] ? e : 0]); }
  float ev[4];
  #pragma unroll
  for (int i=0;i<4;i++) ev[i] = el[sv[i]];
  #pragma unroll
  for (int i=0;i<4;i++){
    int e = s0[i] + lane;
    float x = ev[i] + eri[i];
    x = x >= 0.f ? x : 0.2f*x;
    float t = 0.f;
    if (e < s1[i]){ t = __expf(x); __builtin_nontemporal_store(t, &ee[e]); }
    float s = t;
    for (int k = s0[i]+64; k < s1[i]; k += 64){          // wave-uniform, ~never
      int e2 = k + lane;
      float t2 = 0.f;
      if (e2 < s1[i]){
        float x2 = el[ss[e2]] + eri[i];
        x2 = x2 >= 0.f ? x2 : 0.2f*x2;
        t2 = __expf(x2);
        __builtin_nontemporal_store(t2, &ee[e2]);
      }
      s += t2;
    }
    #pragma unroll
    for (int m=1;m<64;m<<=1) s += __shfl_xor(s,m);
    if (lane == 0){
      float eself = el[node[i]] + eri[i]; eself = eself >= 0.f ? eself : 0.2f*eself;
      float esup  = elsup + eri[i];       esup  = esup  >= 0.f ? esup  : 0.2f*esup;
      float ts = __expf(eself), tu = __expf(esup);
      s += ts + tu;
      fg[IS_OFF + node[i]]   = 1.0f / s;
      fg[ASLF_OFF + node[i]] = ts;
      fg[ASUP_OFF + node[i]] = tu;
    }
  }
}

// GAT aggregation (XCD affinity + short-chain edge loop, mirrors k_gcn_agg).
__global__ __launch_bounds__(256) void k_gat_agg(float* fb, const uchar_t* hb, const int* ib,
    const float* bgat) {
  int g, blk;
  swz_tile(blockIdx.x, g, blk);
  float* fg = fb + (size_t)g*GF;
  const uint_t* hu = (const uint_t*)(hb + (size_t)g*GH);
  const int* ig = ib + (size_t)g*GI;
  int wave = threadIdx.x >> 6, lane = threadIdx.x & 63;
  int q = lane >> 4, u = lane & 15, l15 = lane & 15;
  int w = blk*4 + wave;
  const int* rp = ig + RP_OFF;
  const int* ss = ig + SS_OFF;
  const float* ee = fg + EE_OFF;
  fl4 bg = ((const fl4*)(bgat + g*64))[u];
  fl4 supf = f8up4(hu[(size_t)N*16 + u]);

  // upfront independent loads: rp, round-1 ss/ee, is for all 4 nodes
  int s0a[4], s1a[4];
  #pragma unroll
  for (int i=0;i<4;i++){ int nd = w + NWAVE*i; s0a[i] = rp[nd]; s1a[i] = rp[nd+1]; }
  int iv0[4]; float wv0[4]; float isa[4];
  #pragma unroll
  for (int i=0;i<4;i++){
    int ei = s0a[i] + l15;
    int ec = ei < s1a[i] ? ei : s0a[i];
    iv0[i] = __builtin_nontemporal_load(&ss[ec]);
    wv0[i] = __builtin_nontemporal_load(&ee[ec]);
    isa[i] = fg[IS_OFF + (w + NWAVE*i)];
  }

  #pragma unroll
  for (int i=0;i<4;i++){
    int node = w + NWAVE*i;
    int s0 = s0a[i], s1 = s1a[i];
    fl4 a = {0.f,0.f,0.f,0.f};
    if (q == 0){
      float aslf = fg[ASLF_OFF + node];
      fl4 f = f8up4(hu[(size_t)node*16 + u]);
      a.x = aslf*f.x; a.y = aslf*f.y; a.z = aslf*f.z; a.w = aslf*f.w;
    } else if (q == 1){
      float asup = fg[ASUP_OFF + node];
      a.x = asup*supf.x; a.y = asup*supf.y; a.z = asup*supf.z; a.w = asup*supf.w;
    }
    int idxv = iv0[i];
    float wtv = wv0[i];
    for (int k = s0; k < s1; k += 16){
      int i0 = __shfl(idxv, q);
      int i1 = __shfl(idxv, q+4);
      int i2 = __shfl(idxv, q+8);
      int i3 = __shfl(idxv, q+12);
      float w0 = __shfl(wtv, q);
      float w1 = __shfl(wtv, q+4);
      float w2 = __shfl(wtv, q+8);
      float w3 = __shfl(wtv, q+12);
      uint_t v0 = hu[(size_t)i0*16 + u];
      uint_t v1 = hu[(size_t)i1*16 + u];
      uint_t v2 = hu[(size_t)i2*16 + u];
      uint_t v3 = hu[(size_t)i3*16 + u];
      int kn = k + 16;
      if (kn < s1){                        // prefetch next round (wave-uniform)
        int ei = kn + l15;
        int ec = ei < s1 ? ei : s0;
        idxv = __builtin_nontemporal_load(&ss[ec]);
        wtv  = __builtin_nontemporal_load(&ee[ec]);
      }
      if (kn > s1){                        // partial round: zero invalid weights
        w0 = (k+q   ) < s1 ? w0 : 0.f;
        w1 = (k+q+4 ) < s1 ? w1 : 0.f;
        w2 = (k+q+8 ) < s1 ? w2 : 0.f;
        w3 = (k+q+12) < s1 ? w3 : 0.f;
      }
      fl4 f0=f8up4(v0), f1=f8up4(v1), f2=f8up4(v2), f3=f8up4(v3);
      a.x += (fmaf(w0,f0.x, w1*f1.x)) + (fmaf(w2,f2.x, w3*f3.x));
      a.y += (fmaf(w0,f0.y, w1*f1.y)) + (fmaf(w2,f2.y, w3*f3.y));
      a.z += (fmaf(w0,f0.z, w1*f1.z)) + (fmaf(w2,f2.z, w3*f3.z));
      a.w += (fmaf(w0,f0.w, w1*f1.w)) + (fmaf(w2,f2.w, w3*f3.w));
    }
    a.x += __shfl_xor(a.x,16); a.x += __shfl_xor(a.x,32);
    a.y += __shfl_xor(a.y,16); a.y += __shfl_xor(a.y,32);
    a.z += __shfl_xor(a.z,16); a.z += __shfl_xor(a.z,32);
    a.w += __shfl_xor(a.w,16); a.w += __shfl_xor(a.w,32);
    if (q == 0){
      float is = isa[i];
      fl4 v;
      v.x = fmaf(a.x, is, bg.x); v.y = fmaf(a.y, is, bg.y);
      v.z = fmaf(a.z, is, bg.z); v.w = fmaf(a.w, is, bg.w);
      fl4* xp = (fl4*)(fg + X_OFF + (size_t)node*64);
      __builtin_nontemporal_store(v, &xp[u]);
    }
  }
}

__global__ __launch_bounds__(384) void k_mlp(const float* sm, const float* W1, const float* b1,
    const float* W2, const float* b2, const float* W3, const float* b3, float* out) {
  __shared__ float nf[384];
  __shared__ float y1[192];
  __shared__ float y2[96];
  __shared__ float z[2];
  int t = threadIdx.x;
  int g = t / 128, j = t % 128;
  nf[t] = (j < 64) ? sm[g*64 + j] * (1.0f/(float)N)
                   : __int_as_float(((const int*)sm)[192 + g*64 + (j-64)]);
  __syncthreads();
  if (t < 192){
    float a = b1[t];
    for (int k=0;k<384;k++) a = fmaf(nf[k], W1[(size_t)k*192 + t], a);
    y1[t] = a > 0.f ? a : 0.f;
  }
  __syncthreads();
  if (t < 96){
    float a = b2[t];
    for (int k=0;k<192;k++) a = fmaf(y1[k], W2[(size_t)k*96 + t], a);
    y2[t] = a > 0.f ? a : 0.f;
  }
  __syncthreads();
  if (t < 2){
    float a = b3[t];
    for (int k=0;k<96;k++) a = fmaf(y2[k], W3[k*2 + t], a);
    z[t] = a;
  }
  __syncthreads();
  if (t == 0){
    float m = fmaxf(z[0], z[1]);
    float l = m + logf(__expf(z[0]-m) + __expf(z[1]-m));
    out[0] = z[0] - l;
    out[1] = z[1] - l;
  }
}

extern "C" void kernel_launch(void* const* d_in, const int* in_sizes, int n_in,
                              void* d_out, int out_size, void* d_ws, size_t ws_size,
                              hipStream_t stream) {
  const float* x_s  = (const float*)d_in[0];
  const float* x_g  = (const float*)d_in[1];
  const float* x_t  = (const float*)d_in[2];
  const float* Wc_s = (const float*)d_in[3];
  const float* bc_s = (const float*)d_in[4];
  const float* Wc_g = (const float*)d_in[5];
  const float* bc_g = (const float*)d_in[6];
  const float* Wc_t = (const float*)d_in[7];
  const float* bc_t = (const float*)d_in[8];
  const float* Wx   = (const float*)d_in[9];
  const float* bx   = (const float*)d_in[10];
  const float* Wgat = (const float*)d_in[11];
  const float* al   = (const float*)d_in[12];
  const float* ar   = (const float*)d_in[13];
  const float* bgat = (const float*)d_in[14];
  const float* W1   = (const float*)d_in[15];
  const float* b1   = (const float*)d_in[16];
  const float* W2   = (const float*)d_in[17];
  const float* b2   = (const float*)d_in[18];
  const float* W3   = (const float*)d_in[19];
  const float* b3   = (const float*)d_in[20];
  const int* src_s  = (const int*)d_in[21];
  const int* dst_s  = (const int*)d_in[22];
  const int* src_g  = (const int*)d_in[23];
  const int* dst_g  = (const int*)d_in[24];
  const int* src_t  = (const int*)d_in[25];
  const int* dst_t  = (const int*)d_in[26];

  float* fb = (float*)d_ws;
  int*   ib = (int*)(fb + 3*GF);
  uchar_t* hb = (uchar_t*)(ib + 3*GI);
  float* sm = (float*)(hb + 3*GH);
  int*   pt = (int*)(sm + 384);              // 3*SCB scan partials
  int*   parts_ct = pt + 3*SCB + 64;         // 3*BPR*N
  int*   parts_no = parts_ct + (size_t)3*BPR*N;
  int*   off      = parts_no + (size_t)3*BPR*N;
  float* out = (float*)d_out;

  dim3 b256(256);
  int mmb = (N+63)/64;

  // graph prep: LDS-histogram counting sort (no global atomics)
  k_hist      <<<dim3(BPR, RNG, 3),  dim3(1024), 0, stream>>>(parts_ct, parts_no, src_s,dst_s, src_g,dst_g, src_t,dst_t);
  k_scan_local<<<dim3(SCB, 3),       dim3(1024), 0, stream>>>(ib, pt, parts_ct);
  k_scan_part <<<dim3(3),              dim3(64), 0, stream>>>(pt);
  k_scan_apply<<<dim3(SCB, 3),       dim3(1024), 0, stream>>>(fb, ib, pt, parts_no);
  k_slice_off <<<dim3((N+255)/256, 3),     b256, 0, stream>>>(ib, parts_ct, off);
  k_scatter_r <<<dim3(BPR, RNG, 3),  dim3(1024), 0, stream>>>(ib, off, src_s,dst_s, src_g,dst_g, src_t,dst_t);
  k_copyx     <<<dim3((N*H/4+255)/256, 3), b256, 0, stream>>>(fb, x_s, x_g, x_t);

  for (int it = 0; it < 2; ++it) {
    k_mm_gcn  <<<dim3(mmb, 3),     b256, 0, stream>>>(fb, hb, Wc_s + it*4096, Wc_g + it*4096, Wc_t + it*4096, sm);
    k_gcn_agg <<<dim3(3*AGB),      b256, 0, stream>>>(fb, hb, ib, bc_s, bc_g, bc_t, it, sm, 1);
    k_exchange<<<dim3(3), dim3(64), 0, stream>>>(fb, hb, sm, Wx, bx, Wgat, al, it);
    k_mm_gat  <<<dim3(mmb, 3),     b256, 0, stream>>>(fb, hb, Wgat, al, ar);
    k_gat_prep<<<dim3(AGB, 3),     b256, 0, stream>>>(fb, ib);
    k_gat_agg <<<dim3(3*AGB),      b256, 0, stream>>>(fb, hb, ib, bgat);
  }

  // final layer readouts + MLP head (x write skipped — only readout consumed)
  k_mm_gcn  <<<dim3(mmb, 3),     b256, 0, stream>>>(fb, hb, Wc_s + 2*4096, Wc_g + 2*4096, Wc_t + 2*4096, sm);
  k_gcn_agg <<<dim3(3*AGB),      b256, 0, stream>>>(fb, hb, ib, bc_s, bc_g, bc_t, 2, sm, 0);
  k_mlp     <<<1, 384, 0, stream>>>(sm, W1, b1, W2, b2, W3, b3, out);
}

// Round 5
// 920.293 us; speedup vs baseline: 1.4302x; 1.0249x over previous
//
#include <hip/hip_runtime.h>
#include <math.h>

constexpr int N = 50000;
constexpr int E = 800000;
constexpr int H = 64;
constexpr int NWAVE = 12500;          // N/4 nodes-per-wave mapping (4 nodes per wave)
constexpr int AGB = 3125;             // agg blocks (tiles) per graph (NWAVE/4)
constexpr int SCB = 49;               // scan blocks per graph: 49*1024 >= N
constexpr int RNG = 8;                // histogram ranges per graph
constexpr int BPR = 8;                // edge slices per graph
constexpr int BINS = N / RNG;         // 6250 bins per range
constexpr int ES   = E / BPR;         // 100000 edges per slice

// XCD-affinity swizzle constants (stateless, replay-safe).
constexpr int FULLR = AGB / 3;        // 1041 full rounds
constexpr int FULLB = FULLR * 8;      // 8328 bids in full rounds
constexpr int G2F   = FULLR * 2;      // 2082 g2 tiles from full rounds
constexpr int REM0  = AGB - 3*FULLR;  // 2 leftover g0 tiles
static_assert(3*FULLR + REM0 == AGB, "g0 cover");
static_assert(2*FULLR + (3*AGB - FULLB - 2*REM0) == AGB, "g2 cover");

typedef unsigned short ushort_t;
typedef unsigned int uint_t;
typedef unsigned char uchar_t;
typedef float fl2 __attribute__((ext_vector_type(2)));
typedef float fl4 __attribute__((ext_vector_type(4)));

// ---- workspace layout (element offsets) ----
constexpr size_t X_OFF    = 0;                          // N*H
constexpr size_t NO_OFF   = X_OFF + (size_t)N*H;        // N   deg_out^-1/2
constexpr size_t NI_OFF   = NO_OFF + N;                 // N   deg_in^-1/2
constexpr size_t EL_OFF   = NI_OFF + N;                 // N+1 GAT el (incl supernode)
constexpr size_t ER_OFF   = EL_OFF + (N+1);             // N   GAT er
constexpr size_t EE_OFF   = ER_OFF + N;                 // E   per-edge exp(e) (CSR order)
constexpr size_t IS_OFF   = EE_OFF + E;                 // N   1/softmax-denominator
constexpr size_t ASLF_OFF = IS_OFF + N;                 // N   self-loop numerator
constexpr size_t ASUP_OFF = ASLF_OFF + N;               // N   supernode numerator
constexpr size_t GF = ((ASUP_OFF + N + 255)/256)*256;

constexpr size_t RP_OFF = 0;                            // N+1 row_ptr (CSR by dst)
constexpr size_t CT_OFF = RP_OFF + (N+1);               // N   in-degree count
constexpr size_t SS_OFF = CT_OFF + N;                   // E   src sorted by dst
constexpr size_t GI = ((SS_OFF + E + 255)/256)*256;     // ss[E] (clamp slack) stays in-bounds

// per-graph fp8 h block: 64 B per row (64 x e4m3 = 16 uints); row N = supernode
constexpr size_t GH = (size_t)(N+1)*64;                 // bytes

// fp8 helpers: HW RNE pack/unpack (OCP e4m3 on gfx950)
__device__ inline uint_t f8pack4(float a, float b, float c, float d){
  int r = __builtin_amdgcn_cvt_pk_fp8_f32(a, b, 0, false);
  r = __builtin_amdgcn_cvt_pk_fp8_f32(c, d, r, true);
  return (uint_t)r;
}
__device__ inline fl4 f8up4(uint_t v){
  fl2 lo = __builtin_amdgcn_cvt_pk_f32_fp8((int)v, false);
  fl2 hi = __builtin_amdgcn_cvt_pk_f32_fp8((int)v, true);
  fl4 r; r.x = lo.x; r.y = lo.y; r.z = hi.x; r.w = hi.y;
  return r;
}

// Deterministic bid -> (graph, tile) swizzle for XCD L2 affinity.
__device__ inline void swz_tile(int bid, int& g, int& b){
  if (bid < FULLB){
    int r = bid >> 3, s = bid & 7;
    if (s < 3){ g = 0; b = r*3 + s; }
    else if (s < 6){ g = 1; b = r*3 + (s-3); }
    else { g = 2; b = r*2 + (s-6); }
  } else {
    int t = bid - FULLB;
    if (t < REM0){ g = 0; b = 3*FULLR + t; }
    else if (t < 2*REM0){ g = 1; b = 3*FULLR + (t-REM0); }
    else { g = 2; b = G2F + (t-2*REM0); }
  }
}

// ---- prep: range-partitioned LDS histograms, zero global atomics ----
__global__ __launch_bounds__(1024) void k_hist(int* parts_ct, int* parts_no,
    const int* s0,const int* d0,const int* s1,const int* d1,const int* s2,const int* d2) {
  int sl = blockIdx.x, r = blockIdx.y, g = blockIdx.z;
  const int* s = g==0?s0:(g==1?s1:s2);
  const int* d = g==0?d0:(g==1?d1:d2);
  __shared__ int hc[BINS];
  __shared__ int hn[BINS];
  for (int i=threadIdx.x;i<BINS;i+=1024){ hc[i]=0; hn[i]=0; }
  __syncthreads();
  int lo = r*BINS, hi = lo+BINS;
  int e0 = sl*ES, e1 = e0+ES;
  for (int e=e0+threadIdx.x; e<e1; e+=1024){
    int ds = d[e], sr = s[e];
    if (ds>=lo && ds<hi) atomicAdd(&hc[ds-lo],1);
    if (sr>=lo && sr<hi) atomicAdd(&hn[sr-lo],1);
  }
  __syncthreads();
  size_t base = ((size_t)g*BPR + sl)*N + lo;
  for (int i=threadIdx.x;i<BINS;i+=1024){
    parts_ct[base+i]=hc[i];
    parts_no[base+i]=hn[i];
  }
}

// ---- hierarchical exclusive scan of cnt -> rp (all parallel) ----
__global__ __launch_bounds__(1024) void k_scan_local(int* ib, int* pt, const int* parts_ct) {
  int g = blockIdx.y;
  int* ig = ib + (size_t)g*GI;
  int i = blockIdx.x*1024 + threadIdx.x;
  int c = 0;
  if (i < N){
    #pragma unroll
    for (int s=0;s<BPR;s++) c += parts_ct[((size_t)g*BPR+s)*N + i];
    ig[CT_OFF + i] = c;
  }
  __shared__ int sh[1024];
  sh[threadIdx.x] = c; __syncthreads();
  #pragma unroll
  for (int off=1; off<1024; off<<=1){
    int t = (threadIdx.x>=off) ? sh[threadIdx.x-off] : 0;
    __syncthreads();
    sh[threadIdx.x] += t;
    __syncthreads();
  }
  if (i < N) ig[RP_OFF + i] = sh[threadIdx.x] - c;       // local exclusive
  if (threadIdx.x == 1023) pt[g*SCB + blockIdx.x] = sh[1023];
}

__global__ void k_scan_part(int* pt) {
  int g = blockIdx.x;
  __shared__ int sh[SCB];
  int t = threadIdx.x;
  if (t < SCB) sh[t] = pt[g*SCB + t];
  __syncthreads();
  if (t == 0){
    int run = 0;
    for (int b=0;b<SCB;b++){ int c = sh[b]; sh[b] = run; run += c; }
  }
  __syncthreads();
  if (t < SCB) pt[g*SCB + t] = sh[t];
}

__global__ __launch_bounds__(1024) void k_scan_apply(float* fb, int* ib, const int* pt,
                                                     const int* parts_no) {
  int g = blockIdx.y;
  float* fg = fb + (size_t)g*GF;
  int* ig = ib + (size_t)g*GI;
  int i = blockIdx.x*1024 + threadIdx.x;
  if (i >= N) return;
  int base = pt[g*SCB + blockIdx.x];
  int r = ig[RP_OFF + i] + base;
  ig[RP_OFF + i] = r;
  int c = ig[CT_OFF + i];
  int o = 0;
  #pragma unroll
  for (int s=0;s<BPR;s++) o += parts_no[((size_t)g*BPR+s)*N + i];
  fg[NI_OFF + i] = rsqrtf((float)(c+1));                 // +1 self loop
  fg[NO_OFF + i] = rsqrtf((float)(o+1));
  if (i == N-1) ig[RP_OFF + N] = r + c;
}

// per-(slice,bin) exclusive prefix over slices -> exact scatter offsets
__global__ __launch_bounds__(256) void k_slice_off(const int* ib, const int* parts_ct, int* off) {
  int g = blockIdx.y;
  int i = blockIdx.x*256 + threadIdx.x;
  if (i >= N) return;
  int base = ib[(size_t)g*GI + RP_OFF + i];
  #pragma unroll
  for (int s=0;s<BPR;s++){
    size_t idx = ((size_t)g*BPR+s)*N + i;
    off[idx] = base;
    base += parts_ct[idx];
  }
}

// scatter: LDS cursors per range, plain scattered store (no global atomics)
__global__ __launch_bounds__(1024) void k_scatter_r(int* ib, const int* off,
    const int* s0,const int* d0,const int* s1,const int* d1,const int* s2,const int* d2) {
  int sl = blockIdx.x, r = blockIdx.y, g = blockIdx.z;
  const int* s = g==0?s0:(g==1?s1:s2);
  const int* d = g==0?d0:(g==1?d1:d2);
  int* ss = ib + (size_t)g*GI + SS_OFF;
  __shared__ int cur[BINS];
  int lo = r*BINS;
  size_t ob = ((size_t)g*BPR + sl)*N + lo;
  for (int i=threadIdx.x;i<BINS;i+=1024) cur[i] = off[ob+i];
  __syncthreads();
  int e0 = sl*ES, e1 = e0+ES;
  for (int e=e0+threadIdx.x; e<e1; e+=1024){
    int ds = d[e];
    if (ds>=lo && ds<lo+BINS){
      int pos = atomicAdd(&cur[ds-lo],1);
      ss[pos] = s[e];
    }
  }
}

__global__ __launch_bounds__(256) void k_copyx(float* fb, const float* x0,const float* x1,const float* x2) {
  int i = blockIdx.x*256 + threadIdx.x;
  int g = blockIdx.y;
  const float* x = g==0?x0:(g==1?x1:x2);
  if (i < N*H/4) {
    ((float4*)(fb + (size_t)g*GF + X_OFF))[i] = ((const float4*)x)[i];
  }
}

// Tiled matmul: 64 rows/block, 4 threads/row (q = 16-col group), acc[16].
__global__ __launch_bounds__(256) void k_mm_gcn(float* fb, uchar_t* hb,
    const float* W0,const float* W1,const float* W2, float* sm) {
  if (blockIdx.x==0 && blockIdx.y==0){
    for (int i=threadIdx.x;i<384;i+=256) sm[i]=0.f;
  }
  int g = blockIdx.y;
  const float* W = g==0?W0:(g==1?W1:W2);
  __shared__ float Ws[64*64];
  __shared__ float Xs[64*65];
  float* fg = fb + (size_t)g*GF;
  int row0 = blockIdx.x*64;
  for (int i=threadIdx.x; i<4096; i+=256) Ws[i] = W[i];
  int r = threadIdx.x>>2, q = threadIdx.x&3;
  int row = row0 + r;
  int rowc = row < N ? row : N-1;
  {
    const float4* xr = (const float4*)(fg + X_OFF + (size_t)rowc*64) + q*4;
    float* xd = Xs + r*65 + q*16;
    #pragma unroll
    for (int c=0;c<4;c++){ float4 v = xr[c]; xd[4*c]=v.x; xd[4*c+1]=v.y; xd[4*c+2]=v.z; xd[4*c+3]=v.w; }
  }
  __syncthreads();
  float acc[16];
  #pragma unroll
  for (int j=0;j<16;j++) acc[j]=0.f;
  const float* xrow = Xs + r*65;
  #pragma unroll 8
  for (int k=0;k<64;k++){
    float xk = xrow[k];
    const float* wr = Ws + k*64 + q*16;
    #pragma unroll
    for (int j=0;j<16;j++) acc[j] = fmaf(xk, wr[j], acc[j]);
  }
  if (row >= N) return;
  float sc = fg[NO_OFF + row];
  uint_t pk[4];
  #pragma unroll
  for (int j=0;j<4;j++)
    pk[j] = f8pack4(acc[4*j]*sc, acc[4*j+1]*sc, acc[4*j+2]*sc, acc[4*j+3]*sc);
  *(uint4*)(hb + (size_t)g*GH + (size_t)row*64 + q*16) = *(const uint4*)pk;
}

// Same tiling; h = fp8(x @ Wgat[g]); el/er via quad shfl reduce.
__global__ __launch_bounds__(256) void k_mm_gat(float* fb, uchar_t* hb,
    const float* Wgat, const float* al, const float* ar) {
  int g = blockIdx.y;
  const float* W = Wgat + (size_t)g*4096;
  __shared__ float Ws[64*64];
  __shared__ float Xs[64*65];
  __shared__ float als[64], ars[64];
  float* fg = fb + (size_t)g*GF;
  int row0 = blockIdx.x*64;
  for (int i=threadIdx.x; i<4096; i+=256) Ws[i] = W[i];
  if (threadIdx.x < 64){ als[threadIdx.x] = al[g*64+threadIdx.x]; ars[threadIdx.x] = ar[g*64+threadIdx.x]; }
  int r = threadIdx.x>>2, q = threadIdx.x&3;
  int row = row0 + r;
  int rowc = row < N ? row : N-1;
  {
    const float4* xr = (const float4*)(fg + X_OFF + (size_t)rowc*64) + q*4;
    float* xd = Xs + r*65 + q*16;
    #pragma unroll
    for (int c=0;c<4;c++){ float4 v = xr[c]; xd[4*c]=v.x; xd[4*c+1]=v.y; xd[4*c+2]=v.z; xd[4*c+3]=v.w; }
  }
  __syncthreads();
  float acc[16];
  #pragma unroll
  for (int j=0;j<16;j++) acc[j]=0.f;
  const float* xrow = Xs + r*65;
  #pragma unroll 8
  for (int k=0;k<64;k++){
    float xk = xrow[k];
    const float* wr = Ws + k*64 + q*16;
    #pragma unroll
    for (int j=0;j<16;j++) acc[j] = fmaf(xk, wr[j], acc[j]);
  }
  float el = 0.f, er = 0.f;
  #pragma unroll
  for (int j=0;j<16;j++){ el = fmaf(acc[j], als[q*16+j], el); er = fmaf(acc[j], ars[q*16+j], er); }
  el += __shfl_xor(el,1); el += __shfl_xor(el,2);
  er += __shfl_xor(er,1); er += __shfl_xor(er,2);
  if (row >= N) return;
  uint_t pk[4];
  #pragma unroll
  for (int j=0;j<4;j++)
    pk[j] = f8pack4(acc[4*j], acc[4*j+1], acc[4*j+2], acc[4*j+3]);
  *(uint4*)(hb + (size_t)g*GH + (size_t)row*64 + q*16) = *(const uint4*)pk;
  if (q == 0){
    fg[EL_OFF + row] = el;
    fg[ER_OFF + row] = er;
  }
}

// GCN aggregate (XCD affinity + 2-deep node-pipelined gathers).
// vbuf[2][4]: node i+1's round-1 row-gathers issue BEFORE node i's accumulate
// consumes vbuf[i&1] (hw vmcnt lets the accumulate wait only on its own 4).
// iv1 prefetches round-2 ss (43% of nodes, Poisson-16); vself prefetched.
// All vbuf indices compile-time (unrolled) -> registers, no scratch.
__global__ __launch_bounds__(256) void k_gcn_agg(float* fb, const uchar_t* hb, const int* ib,
    const float* b0, const float* b1, const float* b2, int lay, float* sm, int writex) {
  int g, blk;
  swz_tile(blockIdx.x, g, blk);
  const float* b = (g==0?b0:(g==1?b1:b2)) + lay*64;
  float* fg = fb + (size_t)g*GF;
  const uint_t* hu = (const uint_t*)(hb + (size_t)g*GH);  // 16 uints per row
  const int* ig = ib + (size_t)g*GI;
  int wave = threadIdx.x >> 6, lane = threadIdx.x & 63;
  int q = lane >> 4, u = lane & 15, l15 = lane & 15;
  int w = blk*4 + wave;
  const int* rp = ig + RP_OFF;
  const int* ss = ig + SS_OFF;
  fl4 bl = ((const fl4*)b)[u];
  fl4 vs = {0.f,0.f,0.f,0.f}, vm = {0.f,0.f,0.f,0.f};
  __shared__ float ssum[4][64];
  __shared__ float smx[4][64];

  // upfront independent loads: rp, round-1/2 ss, self rows, ni
  int s0a[4], s1a[4];
  #pragma unroll
  for (int i=0;i<4;i++){ int nd = w + NWAVE*i; s0a[i] = rp[nd]; s1a[i] = rp[nd+1]; }
  int iv0[4], iv1[4]; float nia[4]; uint_t vself[4];
  #pragma unroll
  for (int i=0;i<4;i++){
    int e0 = s0a[i] + l15;
    int c0 = e0 < s1a[i] ? e0 : s0a[i];
    iv0[i] = __builtin_nontemporal_load(&ss[c0]);
    int e1 = s0a[i] + 16 + l15;
    int c1 = e1 < s1a[i] ? e1 : s0a[i];
    iv1[i] = __builtin_nontemporal_load(&ss[c1]);
    nia[i] = fg[NI_OFF + (w + NWAVE*i)];
    vself[i] = hu[(size_t)(w + NWAVE*i)*16 + u];
  }

  // prologue: node 0 round-1 gathers
  uint_t vbuf[2][4];
  #pragma unroll
  for (int j=0;j<4;j++){
    int ii = __shfl(iv0[0], q + j*4);
    vbuf[0][j] = hu[(size_t)ii*16 + u];
  }

  #pragma unroll
  for (int i=0;i<4;i++){
    // issue node i+1's round-1 gathers before consuming node i's
    if (i < 3){
      #pragma unroll
      for (int j=0;j<4;j++){
        int ii = __shfl(iv0[i+1], q + j*4);
        vbuf[(i+1)&1][j] = hu[(size_t)ii*16 + u];
      }
    }
    int node = w + NWAVE*i;
    int s0 = s0a[i], s1 = s1a[i];
    fl4 a = {0.f,0.f,0.f,0.f};
    if (q == 0) a = f8up4(vself[i]);                  // self loop (pre-scaled)
    // round 1 (predication covers deg<16 incl deg 0: all weights -> 0)
    {
      int kn = s0 + 16;
      if (kn <= s1){
        a += (f8up4(vbuf[i&1][0]) + f8up4(vbuf[i&1][1]))
           + (f8up4(vbuf[i&1][2]) + f8up4(vbuf[i&1][3]));
      } else {
        fl4 f0=f8up4(vbuf[i&1][0]), f1=f8up4(vbuf[i&1][1]);
        fl4 f2=f8up4(vbuf[i&1][2]), f3=f8up4(vbuf[i&1][3]);
        float w0 = (s0+q   ) < s1 ? 1.f : 0.f;
        float w1 = (s0+q+4 ) < s1 ? 1.f : 0.f;
        float w2 = (s0+q+8 ) < s1 ? 1.f : 0.f;
        float w3 = (s0+q+12) < s1 ? 1.f : 0.f;
        a.x += fmaf(w0,f0.x, w1*f1.x) + fmaf(w2,f2.x, w3*f3.x);
        a.y += fmaf(w0,f0.y, w1*f1.y) + fmaf(w2,f2.y, w3*f3.y);
        a.z += fmaf(w0,f0.z, w1*f1.z) + fmaf(w2,f2.z, w3*f3.z);
        a.w += fmaf(w0,f0.w, w1*f1.w) + fmaf(w2,f2.w, w3*f3.w);
      }
    }
    // extra rounds: first uses prefetched iv1; later rounds load ss inline
    int idxv = iv1[i];
    for (int k = s0+16; k < s1; k += 16){
      int i0 = __shfl(idxv, q);
      int i1 = __shfl(idxv, q+4);
      int i2 = __shfl(idxv, q+8);
      int i3 = __shfl(idxv, q+12);
      uint_t v0 = hu[(size_t)i0*16 + u];
      uint_t v1 = hu[(size_t)i1*16 + u];
      uint_t v2 = hu[(size_t)i2*16 + u];
      uint_t v3 = hu[(size_t)i3*16 + u];
      int kn = k + 16;
      if (kn < s1){
        int ei = kn + l15;
        int ec = ei < s1 ? ei : s0;
        idxv = __builtin_nontemporal_load(&ss[ec]);
      }
      if (kn <= s1){
        a += (f8up4(v0) + f8up4(v1)) + (f8up4(v2) + f8up4(v3));
      } else {
        fl4 f0=f8up4(v0), f1=f8up4(v1), f2=f8up4(v2), f3=f8up4(v3);
        float w0 = (k+q   ) < s1 ? 1.f : 0.f;
        float w1 = (k+q+4 ) < s1 ? 1.f : 0.f;
        float w2 = (k+q+8 ) < s1 ? 1.f : 0.f;
        float w3 = (k+q+12) < s1 ? 1.f : 0.f;
        a.x += fmaf(w0,f0.x, w1*f1.x) + fmaf(w2,f2.x, w3*f3.x);
        a.y += fmaf(w0,f0.y, w1*f1.y) + fmaf(w2,f2.y, w3*f3.y);
        a.z += fmaf(w0,f0.z, w1*f1.z) + fmaf(w2,f2.z, w3*f3.z);
        a.w += fmaf(w0,f0.w, w1*f1.w) + fmaf(w2,f2.w, w3*f3.w);
      }
    }
    a.x += __shfl_xor(a.x,16); a.x += __shfl_xor(a.x,32);
    a.y += __shfl_xor(a.y,16); a.y += __shfl_xor(a.y,32);
    a.z += __shfl_xor(a.z,16); a.z += __shfl_xor(a.z,32);
    a.w += __shfl_xor(a.w,16); a.w += __shfl_xor(a.w,32);
    if (q == 0){
      float ni = nia[i];
      fl4 v;
      v.x = fmaf(a.x, ni, bl.x); v.x = v.x > 0.f ? v.x : 0.f;
      v.y = fmaf(a.y, ni, bl.y); v.y = v.y > 0.f ? v.y : 0.f;
      v.z = fmaf(a.z, ni, bl.z); v.z = v.z > 0.f ? v.z : 0.f;
      v.w = fmaf(a.w, ni, bl.w); v.w = v.w > 0.f ? v.w : 0.f;
      if (writex){
        fl4* xp = (fl4*)(fg + X_OFF + (size_t)node*64);
        __builtin_nontemporal_store(v, &xp[u]);
      }
      vs += v;
      vm.x = fmaxf(vm.x,v.x); vm.y = fmaxf(vm.y,v.y);
      vm.z = fmaxf(vm.z,v.z); vm.w = fmaxf(vm.w,v.w);
    }
  }
  if (q == 0){
    ((fl4*)ssum[wave])[u] = vs;
    ((fl4*)smx[wave])[u]  = vm;
  }
  __syncthreads();
  if (threadIdx.x < 64){
    int t = threadIdx.x;
    float s = ssum[0][t]+ssum[1][t]+ssum[2][t]+ssum[3][t];
    float mx = fmaxf(fmaxf(smx[0][t],smx[1][t]), fmaxf(smx[2][t],smx[3][t]));
    atomicAdd(&sm[g*64 + t], s);
    atomicMax((int*)sm + 192 + g*64 + t, __float_as_int(mx));  // v>=0: int order == float order
  }
}

// readout finalize + cross-graph feature exchange + supernode h row (fp8), el[N]
__global__ void k_exchange(float* fb, uchar_t* hb, float* sm, const float* Wx, const float* bx,
                           const float* Wgat, const float* al, int it) {
  int gt = blockIdx.x;     // target graph
  int t = threadIdx.x;     // 64 threads
  int src, widx;
  if ((it & 1) == 0){ src = (gt==0)?1:(gt==1)?2:0; widx = (gt==0)?1:(gt==1)?0:2; }
  else              { src = (gt==0)?2:(gt==1)?0:1; widx = (gt==0)?5:(gt==1)?3:4; }
  __shared__ float ro[128];
  __shared__ float f[64];
  __shared__ float red[64];
  __shared__ float hsb[64];
  ro[t]      = sm[src*64 + t] * (1.0f/(float)N);
  ro[64 + t] = __int_as_float(((int*)sm)[192 + src*64 + t]);
  __syncthreads();
  float a = bx[widx*64 + t];
  for (int k=0;k<128;k++) a = fmaf(ro[k], Wx[(size_t)widx*8192 + k*64 + t], a);
  a = a > 0.f ? a : 0.f;
  f[t] = a;
  __syncthreads();
  float* fg = fb + (size_t)gt*GF;
  float hs = 0.f;
  for (int k=0;k<64;k++) hs = fmaf(f[k], Wgat[(size_t)gt*4096 + k*64 + t], hs);
  hsb[t] = hs;
  red[t] = hs * al[gt*64 + t];
  __syncthreads();
  if (t < 16){
    uint_t r = f8pack4(hsb[4*t], hsb[4*t+1], hsb[4*t+2], hsb[4*t+3]);
    ((uint_t*)(hb + (size_t)gt*GH + (size_t)N*64))[t] = r;
  }
  if (t == 0){
    float e = 0.f;
    for (int k=0;k<64;k++) e += red[k];
    fg[EL_OFF + N] = e;                      // el for supernode
  }
}

// GAT softmax prep: wave per 4 nodes, interleaved phases (all ss loads ->
// all el gathers -> compute); el table is 200KB/graph so it L2-caches fine.
__global__ __launch_bounds__(256) void k_gat_prep(float* fb, const int* ib) {
  int g = blockIdx.y;
  float* fg = fb + (size_t)g*GF;
  const int* ig = ib + (size_t)g*GI;
  const int* rp = ig + RP_OFF;
  const int* ss = ig + SS_OFF;
  const float* el = fg + EL_OFF;
  float* ee = fg + EE_OFF;
  int wave = threadIdx.x>>6, lane = threadIdx.x&63;
  int w = blockIdx.x*4 + wave;
  float elsup = el[N];
  int node[4], s0[4], s1[4];
  #pragma unroll
  for (int i=0;i<4;i++){ node[i] = w + NWAVE*i; s0[i] = rp[node[i]]; s1[i] = rp[node[i]+1]; }
  float eri[4];
  #pragma unroll
  for (int i=0;i<4;i++) eri[i] = fg[ER_OFF + node[i]];
  int sv[4];
  #pragma unroll
  for (int i=0;i<4;i++){ int e = s0[i] + lane; sv[i] = __builtin_nontemporal_load(&ss[e < s1[i] ? e : 0]); }
  float ev[4];
  #pragma unroll
  for (int i=0;i<4;i++) ev[i] = el[sv[i]];
  #pragma unroll
  for (int i=0;i<4;i++){
    int e = s0[i] + lane;
    float x = ev[i] + eri[i];
    x = x >= 0.f ? x : 0.2f*x;
    float t = 0.f;
    if (e < s1[i]){ t = __expf(x); __builtin_nontemporal_store(t, &ee[e]); }
    float s = t;
    for (int k = s0[i]+64; k < s1[i]; k += 64){          // wave-uniform, ~never
      int e2 = k + lane;
      float t2 = 0.f;
      if (e2 < s1[i]){
        float x2 = el[ss[e2]] + eri[i];
        x2 = x2 >= 0.f ? x2 : 0.2f*x2;
        t2 = __expf(x2);
        __builtin_nontemporal_store(t2, &ee[e2]);
      }
      s += t2;
    }
    #pragma unroll
    for (int m=1;m<64;m<<=1) s += __shfl_xor(s,m);
    if (lane == 0){
      float eself = el[node[i]] + eri[i]; eself = eself >= 0.f ? eself : 0.2f*eself;
      float esup  = elsup + eri[i];       esup  = esup  >= 0.f ? esup  : 0.2f*esup;
      float ts = __expf(eself), tu = __expf(esup);
      s += ts + tu;
      fg[IS_OFF + node[i]]   = 1.0f / s;
      fg[ASLF_OFF + node[i]] = ts;
      fg[ASUP_OFF + node[i]] = tu;
    }
  }
}

// GAT aggregation (XCD affinity + 2-deep node-pipelined gathers, mirrors gcn).
__global__ __launch_bounds__(256) void k_gat_agg(float* fb, const uchar_t* hb, const int* ib,
    const float* bgat) {
  int g, blk;
  swz_tile(blockIdx.x, g, blk);
  float* fg = fb + (size_t)g*GF;
  const uint_t* hu = (const uint_t*)(hb + (size_t)g*GH);
  const int* ig = ib + (size_t)g*GI;
  int wave = threadIdx.x >> 6, lane = threadIdx.x & 63;
  int q = lane >> 4, u = lane & 15, l15 = lane & 15;
  int w = blk*4 + wave;
  const int* rp = ig + RP_OFF;
  const int* ss = ig + SS_OFF;
  const float* ee = fg + EE_OFF;
  fl4 bg = ((const fl4*)(bgat + g*64))[u];
  fl4 supf = f8up4(hu[(size_t)N*16 + u]);

  // upfront independent loads
  int s0a[4], s1a[4];
  #pragma unroll
  for (int i=0;i<4;i++){ int nd = w + NWAVE*i; s0a[i] = rp[nd]; s1a[i] = rp[nd+1]; }
  int iv0[4], iv1[4]; float ev0[4], ev1[4]; float isa[4]; uint_t vself[4];
  #pragma unroll
  for (int i=0;i<4;i++){
    int e0 = s0a[i] + l15;
    int c0 = e0 < s1a[i] ? e0 : s0a[i];
    iv0[i] = __builtin_nontemporal_load(&ss[c0]);
    ev0[i] = __builtin_nontemporal_load(&ee[c0]);
    int e1 = s0a[i] + 16 + l15;
    int c1 = e1 < s1a[i] ? e1 : s0a[i];
    iv1[i] = __builtin_nontemporal_load(&ss[c1]);
    ev1[i] = __builtin_nontemporal_load(&ee[c1]);
    isa[i] = fg[IS_OFF + (w + NWAVE*i)];
    vself[i] = hu[(size_t)(w + NWAVE*i)*16 + u];
  }

  // prologue: node 0 round-1 gathers
  uint_t vbuf[2][4];
  #pragma unroll
  for (int j=0;j<4;j++){
    int ii = __shfl(iv0[0], q + j*4);
    vbuf[0][j] = hu[(size_t)ii*16 + u];
  }

  #pragma unroll
  for (int i=0;i<4;i++){
    if (i < 3){
      #pragma unroll
      for (int j=0;j<4;j++){
        int ii = __shfl(iv0[i+1], q + j*4);
        vbuf[(i+1)&1][j] = hu[(size_t)ii*16 + u];
      }
    }
    int node = w + NWAVE*i;
    int s0 = s0a[i], s1 = s1a[i];
    fl4 a = {0.f,0.f,0.f,0.f};
    if (q == 0){
      float aslf = fg[ASLF_OFF + node];
      fl4 f = f8up4(vself[i]);
      a.x = aslf*f.x; a.y = aslf*f.y; a.z = aslf*f.z; a.w = aslf*f.w;
    } else if (q == 1){
      float asup = fg[ASUP_OFF + node];
      a.x = asup*supf.x; a.y = asup*supf.y; a.z = asup*supf.z; a.w = asup*supf.w;
    }
    // round 1 with ee weights (predication covers deg<16 incl 0)
    {
      float w0 = __shfl(ev0[i], q);
      float w1 = __shfl(ev0[i], q+4);
      float w2 = __shfl(ev0[i], q+8);
      float w3 = __shfl(ev0[i], q+12);
      int kn = s0 + 16;
      if (kn > s1){
        w0 = (s0+q   ) < s1 ? w0 : 0.f;
        w1 = (s0+q+4 ) < s1 ? w1 : 0.f;
        w2 = (s0+q+8 ) < s1 ? w2 : 0.f;
        w3 = (s0+q+12) < s1 ? w3 : 0.f;
      }
      fl4 f0=f8up4(vbuf[i&1][0]), f1=f8up4(vbuf[i&1][1]);
      fl4 f2=f8up4(vbuf[i&1][2]), f3=f8up4(vbuf[i&1][3]);
      a.x += (fmaf(w0,f0.x, w1*f1.x)) + (fmaf(w2,f2.x, w3*f3.x));
      a.y += (fmaf(w0,f0.y, w1*f1.y)) + (fmaf(w2,f2.y, w3*f3.y));
      a.z += (fmaf(w0,f0.z, w1*f1.z)) + (fmaf(w2,f2.z, w3*f3.z));
      a.w += (fmaf(w0,f0.w, w1*f1.w)) + (fmaf(w2,f2.w, w3*f3.w));
    }
    // extra rounds
    int idxv = iv1[i];
    float wtv = ev1[i];
    for (int k = s0+16; k < s1; k += 16){
      int i0 = __shfl(idxv, q);
      int i1 = __shfl(idxv, q+4);
      int i2 = __shfl(idxv, q+8);
      int i3 = __shfl(idxv, q+12);
      float w0 = __shfl(wtv, q);
      float w1 = __shfl(wtv, q+4);
      float w2 = __shfl(wtv, q+8);
      float w3 = __shfl(wtv, q+12);
      uint_t v0 = hu[(size_t)i0*16 + u];
      uint_t v1 = hu[(size_t)i1*16 + u];
      uint_t v2 = hu[(size_t)i2*16 + u];
      uint_t v3 = hu[(size_t)i3*16 + u];
      int kn = k + 16;
      if (kn < s1){
        int ei = kn + l15;
        int ec = ei < s1 ? ei : s0;
        idxv = __builtin_nontemporal_load(&ss[ec]);
        wtv  = __builtin_nontemporal_load(&ee[ec]);
      }
      if (kn > s1){
        w0 = (k+q   ) < s1 ? w0 : 0.f;
        w1 = (k+q+4 ) < s1 ? w1 : 0.f;
        w2 = (k+q+8 ) < s1 ? w2 : 0.f;
        w3 = (k+q+12) < s1 ? w3 : 0.f;
      }
      fl4 f0=f8up4(v0), f1=f8up4(v1), f2=f8up4(v2), f3=f8up4(v3);
      a.x += (fmaf(w0,f0.x, w1*f1.x)) + (fmaf(w2,f2.x, w3*f3.x));
      a.y += (fmaf(w0,f0.y, w1*f1.y)) + (fmaf(w2,f2.y, w3*f3.y));
      a.z += (fmaf(w0,f0.z, w1*f1.z)) + (fmaf(w2,f2.z, w3*f3.z));
      a.w += (fmaf(w0,f0.w, w1*f1.w)) + (fmaf(w2,f2.w, w3*f3.w));
    }
    a.x += __shfl_xor(a.x,16); a.x += __shfl_xor(a.x,32);
    a.y += __shfl_xor(a.y,16); a.y += __shfl_xor(a.y,32);
    a.z += __shfl_xor(a.z,16); a.z += __shfl_xor(a.z,32);
    a.w += __shfl_xor(a.w,16); a.w += __shfl_xor(a.w,32);
    if (q == 0){
      float is = isa[i];
      fl4 v;
      v.x = fmaf(a.x, is, bg.x); v.y = fmaf(a.y, is, bg.y);
      v.z = fmaf(a.z, is, bg.z); v.w = fmaf(a.w, is, bg.w);
      fl4* xp = (fl4*)(fg + X_OFF + (size_t)node*64);
      __builtin_nontemporal_store(v, &xp[u]);
    }
  }
}

__global__ __launch_bounds__(384) void k_mlp(const float* sm, const float* W1, const float* b1,
    const float* W2, const float* b2, const float* W3, const float* b3, float* out) {
  __shared__ float nf[384];
  __shared__ float y1[192];
  __shared__ float y2[96];
  __shared__ float z[2];
  int t = threadIdx.x;
  int g = t / 128, j = t % 128;
  nf[t] = (j < 64) ? sm[g*64 + j] * (1.0f/(float)N)
                   : __int_as_float(((const int*)sm)[192 + g*64 + (j-64)]);
  __syncthreads();
  if (t < 192){
    float a = b1[t];
    for (int k=0;k<384;k++) a = fmaf(nf[k], W1[(size_t)k*192 + t], a);
    y1[t] = a > 0.f ? a : 0.f;
  }
  __syncthreads();
  if (t < 96){
    float a = b2[t];
    for (int k=0;k<192;k++) a = fmaf(y1[k], W2[(size_t)k*96 + t], a);
    y2[t] = a > 0.f ? a : 0.f;
  }
  __syncthreads();
  if (t < 2){
    float a = b3[t];
    for (int k=0;k<96;k++) a = fmaf(y2[k], W3[k*2 + t], a);
    z[t] = a;
  }
  __syncthreads();
  if (t == 0){
    float m = fmaxf(z[0], z[1]);
    float l = m + logf(__expf(z[0]-m) + __expf(z[1]-m));
    out[0] = z[0] - l;
    out[1] = z[1] - l;
  }
}

extern "C" void kernel_launch(void* const* d_in, const int* in_sizes, int n_in,
                              void* d_out, int out_size, void* d_ws, size_t ws_size,
                              hipStream_t stream) {
  const float* x_s  = (const float*)d_in[0];
  const float* x_g  = (const float*)d_in[1];
  const float* x_t  = (const float*)d_in[2];
  const float* Wc_s = (const float*)d_in[3];
  const float* bc_s = (const float*)d_in[4];
  const float* Wc_g = (const float*)d_in[5];
  const float* bc_g = (const float*)d_in[6];
  const float* Wc_t = (const float*)d_in[7];
  const float* bc_t = (const float*)d_in[8];
  const float* Wx   = (const float*)d_in[9];
  const float* bx   = (const float*)d_in[10];
  const float* Wgat = (const float*)d_in[11];
  const float* al   = (const float*)d_in[12];
  const float* ar   = (const float*)d_in[13];
  const float* bgat = (const float*)d_in[14];
  const float* W1   = (const float*)d_in[15];
  const float* b1   = (const float*)d_in[16];
  const float* W2   = (const float*)d_in[17];
  const float* b2   = (const float*)d_in[18];
  const float* W3   = (const float*)d_in[19];
  const float* b3   = (const float*)d_in[20];
  const int* src_s  = (const int*)d_in[21];
  const int* dst_s  = (const int*)d_in[22];
  const int* src_g  = (const int*)d_in[23];
  const int* dst_g  = (const int*)d_in[24];
  const int* src_t  = (const int*)d_in[25];
  const int* dst_t  = (const int*)d_in[26];

  float* fb = (float*)d_ws;
  int*   ib = (int*)(fb + 3*GF);
  uchar_t* hb = (uchar_t*)(ib + 3*GI);
  float* sm = (float*)(hb + 3*GH);
  int*   pt = (int*)(sm + 384);              // 3*SCB scan partials
  int*   parts_ct = pt + 3*SCB + 64;         // 3*BPR*N
  int*   parts_no = parts_ct + (size_t)3*BPR*N;
  int*   off      = parts_no + (size_t)3*BPR*N;
  float* out = (float*)d_out;

  dim3 b256(256);
  int mmb = (N+63)/64;

  // graph prep: LDS-histogram counting sort (no global atomics)
  k_hist      <<<dim3(BPR, RNG, 3),  dim3(1024), 0, stream>>>(parts_ct, parts_no, src_s,dst_s, src_g,dst_g, src_t,dst_t);
  k_scan_local<<<dim3(SCB, 3),       dim3(1024), 0, stream>>>(ib, pt, parts_ct);
  k_scan_part <<<dim3(3),              dim3(64), 0, stream>>>(pt);
  k_scan_apply<<<dim3(SCB, 3),       dim3(1024), 0, stream>>>(fb, ib, pt, parts_no);
  k_slice_off <<<dim3((N+255)/256, 3),     b256, 0, stream>>>(ib, parts_ct, off);
  k_scatter_r <<<dim3(BPR, RNG, 3),  dim3(1024), 0, stream>>>(ib, off, src_s,dst_s, src_g,dst_g, src_t,dst_t);
  k_copyx     <<<dim3((N*H/4+255)/256, 3), b256, 0, stream>>>(fb, x_s, x_g, x_t);

  for (int it = 0; it < 2; ++it) {
    k_mm_gcn  <<<dim3(mmb, 3),     b256, 0, stream>>>(fb, hb, Wc_s + it*4096, Wc_g + it*4096, Wc_t + it*4096, sm);
    k_gcn_agg <<<dim3(3*AGB),      b256, 0, stream>>>(fb, hb, ib, bc_s, bc_g, bc_t, it, sm, 1);
    k_exchange<<<dim3(3), dim3(64), 0, stream>>>(fb, hb, sm, Wx, bx, Wgat, al, it);
    k_mm_gat  <<<dim3(mmb, 3),     b256, 0, stream>>>(fb, hb, Wgat, al, ar);
    k_gat_prep<<<dim3(AGB, 3),     b256, 0, stream>>>(fb, ib);
    k_gat_agg <<<dim3(3*AGB),      b256, 0, stream>>>(fb, hb, ib, bgat);
  }

  // final layer readouts + MLP head (x write skipped — only readout consumed)
  k_mm_gcn  <<<dim3(mmb, 3),     b256, 0, stream>>>(fb, hb, Wc_s + 2*4096, Wc_g + 2*4096, Wc_t + 2*4096, sm);
  k_gcn_agg <<<dim3(3*AGB),      b256, 0, stream>>>(fb, hb, ib, bc_s, bc_g, bc_t, 2, sm, 0);
  k_mlp     <<<1, 384, 0, stream>>>(sm, W1, b1, W2, b2, W3, b3, out);
}

// Round 6
// 890.539 us; speedup vs baseline: 1.4779x; 1.0334x over previous
//
#include <hip/hip_runtime.h>
#include <math.h>

constexpr int N = 50000;
constexpr int E = 800000;
constexpr int H = 64;
constexpr int NWAVE = 12500;          // N/4 nodes-per-wave mapping (4 nodes per wave)
constexpr int AGB = 3125;             // agg blocks (tiles) per graph (NWAVE/4)
constexpr int SCB = 49;               // scan blocks per graph: 49*1024 >= N
constexpr int RNG = 8;                // histogram ranges per graph
constexpr int BPR = 8;                // edge slices per graph
constexpr int BINS = N / RNG;         // 6250 bins per range
constexpr int ES   = E / BPR;         // 100000 edges per slice

// XCD-affinity swizzle constants (stateless, replay-safe).
constexpr int FULLR = AGB / 3;        // 1041 full rounds
constexpr int FULLB = FULLR * 8;      // 8328 bids in full rounds
constexpr int G2F   = FULLR * 2;      // 2082 g2 tiles from full rounds
constexpr int REM0  = AGB - 3*FULLR;  // 2 leftover g0 tiles
static_assert(3*FULLR + REM0 == AGB, "g0 cover");
static_assert(2*FULLR + (3*AGB - FULLB - 2*REM0) == AGB, "g2 cover");

typedef unsigned short ushort_t;
typedef unsigned int uint_t;
typedef unsigned char uchar_t;
typedef float fl2 __attribute__((ext_vector_type(2)));
typedef float fl4 __attribute__((ext_vector_type(4)));

// ---- workspace layout (element offsets) ----
constexpr size_t X_OFF    = 0;                          // N*H
constexpr size_t NO_OFF   = X_OFF + (size_t)N*H;        // N   deg_out^-1/2
constexpr size_t NI_OFF   = NO_OFF + N;                 // N   deg_in^-1/2
constexpr size_t EL_OFF   = NI_OFF + N;                 // N+1 GAT el (incl supernode)
constexpr size_t ER_OFF   = EL_OFF + (N+1);             // N   GAT er
constexpr size_t EE_OFF   = ER_OFF + N;                 // E   per-edge exp(e) (CSR order)
constexpr size_t IS_OFF   = EE_OFF + E;                 // N   1/softmax-denominator
constexpr size_t ASLF_OFF = IS_OFF + N;                 // N   self-loop numerator
constexpr size_t ASUP_OFF = ASLF_OFF + N;               // N   supernode numerator
constexpr size_t GF = ((ASUP_OFF + N + 255)/256)*256;

constexpr size_t RP_OFF = 0;                            // N+1 row_ptr (CSR by dst)
constexpr size_t CT_OFF = RP_OFF + (N+1);               // N   in-degree count
constexpr size_t SS_OFF = CT_OFF + N;                   // E   src sorted by dst
constexpr size_t GI = ((SS_OFF + E + 255)/256)*256;     // ss[E] (clamp slack) stays in-bounds

// per-graph fp8 h block: 64 B per row (64 x e4m3 = 16 uints); row N = supernode
constexpr size_t GH = (size_t)(N+1)*64;                 // bytes

// fp8 helpers: HW RNE pack/unpack (OCP e4m3 on gfx950)
__device__ inline uint_t f8pack4(float a, float b, float c, float d){
  int r = __builtin_amdgcn_cvt_pk_fp8_f32(a, b, 0, false);
  r = __builtin_amdgcn_cvt_pk_fp8_f32(c, d, r, true);
  return (uint_t)r;
}
__device__ inline fl4 f8up4(uint_t v){
  fl2 lo = __builtin_amdgcn_cvt_pk_f32_fp8((int)v, false);
  fl2 hi = __builtin_amdgcn_cvt_pk_f32_fp8((int)v, true);
  fl4 r; r.x = lo.x; r.y = lo.y; r.z = hi.x; r.w = hi.y;
  return r;
}

// Deterministic bid -> (graph, tile) swizzle for XCD L2 affinity.
__device__ inline void swz_tile(int bid, int& g, int& b){
  if (bid < FULLB){
    int r = bid >> 3, s = bid & 7;
    if (s < 3){ g = 0; b = r*3 + s; }
    else if (s < 6){ g = 1; b = r*3 + (s-3); }
    else { g = 2; b = r*2 + (s-6); }
  } else {
    int t = bid - FULLB;
    if (t < REM0){ g = 0; b = 3*FULLR + t; }
    else if (t < 2*REM0){ g = 1; b = 3*FULLR + (t-REM0); }
    else { g = 2; b = G2F + (t-2*REM0); }
  }
}

// ---- prep: range-partitioned LDS histograms, zero global atomics ----
__global__ __launch_bounds__(1024) void k_hist(int* parts_ct, int* parts_no,
    const int* s0,const int* d0,const int* s1,const int* d1,const int* s2,const int* d2) {
  int sl = blockIdx.x, r = blockIdx.y, g = blockIdx.z;
  const int* s = g==0?s0:(g==1?s1:s2);
  const int* d = g==0?d0:(g==1?d1:d2);
  __shared__ int hc[BINS];
  __shared__ int hn[BINS];
  for (int i=threadIdx.x;i<BINS;i+=1024){ hc[i]=0; hn[i]=0; }
  __syncthreads();
  int lo = r*BINS, hi = lo+BINS;
  int e0 = sl*ES, e1 = e0+ES;
  for (int e=e0+threadIdx.x; e<e1; e+=1024){
    int ds = d[e], sr = s[e];
    if (ds>=lo && ds<hi) atomicAdd(&hc[ds-lo],1);
    if (sr>=lo && sr<hi) atomicAdd(&hn[sr-lo],1);
  }
  __syncthreads();
  size_t base = ((size_t)g*BPR + sl)*N + lo;
  for (int i=threadIdx.x;i<BINS;i+=1024){
    parts_ct[base+i]=hc[i];
    parts_no[base+i]=hn[i];
  }
}

// ---- hierarchical exclusive scan of cnt -> rp (all parallel) ----
__global__ __launch_bounds__(1024) void k_scan_local(int* ib, int* pt, const int* parts_ct) {
  int g = blockIdx.y;
  int* ig = ib + (size_t)g*GI;
  int i = blockIdx.x*1024 + threadIdx.x;
  int c = 0;
  if (i < N){
    #pragma unroll
    for (int s=0;s<BPR;s++) c += parts_ct[((size_t)g*BPR+s)*N + i];
    ig[CT_OFF + i] = c;
  }
  __shared__ int sh[1024];
  sh[threadIdx.x] = c; __syncthreads();
  #pragma unroll
  for (int off=1; off<1024; off<<=1){
    int t = (threadIdx.x>=off) ? sh[threadIdx.x-off] : 0;
    __syncthreads();
    sh[threadIdx.x] += t;
    __syncthreads();
  }
  if (i < N) ig[RP_OFF + i] = sh[threadIdx.x] - c;       // local exclusive
  if (threadIdx.x == 1023) pt[g*SCB + blockIdx.x] = sh[1023];
}

__global__ void k_scan_part(int* pt) {
  int g = blockIdx.x;
  __shared__ int sh[SCB];
  int t = threadIdx.x;
  if (t < SCB) sh[t] = pt[g*SCB + t];
  __syncthreads();
  if (t == 0){
    int run = 0;
    for (int b=0;b<SCB;b++){ int c = sh[b]; sh[b] = run; run += c; }
  }
  __syncthreads();
  if (t < SCB) pt[g*SCB + t] = sh[t];
}

__global__ __launch_bounds__(1024) void k_scan_apply(float* fb, int* ib, const int* pt,
                                                     const int* parts_no) {
  int g = blockIdx.y;
  float* fg = fb + (size_t)g*GF;
  int* ig = ib + (size_t)g*GI;
  int i = blockIdx.x*1024 + threadIdx.x;
  if (i >= N) return;
  int base = pt[g*SCB + blockIdx.x];
  int r = ig[RP_OFF + i] + base;
  ig[RP_OFF + i] = r;
  int c = ig[CT_OFF + i];
  int o = 0;
  #pragma unroll
  for (int s=0;s<BPR;s++) o += parts_no[((size_t)g*BPR+s)*N + i];
  fg[NI_OFF + i] = rsqrtf((float)(c+1));                 // +1 self loop
  fg[NO_OFF + i] = rsqrtf((float)(o+1));
  if (i == N-1) ig[RP_OFF + N] = r + c;
}

// per-(slice,bin) exclusive prefix over slices -> exact scatter offsets
__global__ __launch_bounds__(256) void k_slice_off(const int* ib, const int* parts_ct, int* off) {
  int g = blockIdx.y;
  int i = blockIdx.x*256 + threadIdx.x;
  if (i >= N) return;
  int base = ib[(size_t)g*GI + RP_OFF + i];
  #pragma unroll
  for (int s=0;s<BPR;s++){
    size_t idx = ((size_t)g*BPR+s)*N + i;
    off[idx] = base;
    base += parts_ct[idx];
  }
}

// scatter: LDS cursors per range, plain scattered store (no global atomics)
__global__ __launch_bounds__(1024) void k_scatter_r(int* ib, const int* off,
    const int* s0,const int* d0,const int* s1,const int* d1,const int* s2,const int* d2) {
  int sl = blockIdx.x, r = blockIdx.y, g = blockIdx.z;
  const int* s = g==0?s0:(g==1?s1:s2);
  const int* d = g==0?d0:(g==1?d1:d2);
  int* ss = ib + (size_t)g*GI + SS_OFF;
  __shared__ int cur[BINS];
  int lo = r*BINS;
  size_t ob = ((size_t)g*BPR + sl)*N + lo;
  for (int i=threadIdx.x;i<BINS;i+=1024) cur[i] = off[ob+i];
  __syncthreads();
  int e0 = sl*ES, e1 = e0+ES;
  for (int e=e0+threadIdx.x; e<e1; e+=1024){
    int ds = d[e];
    if (ds>=lo && ds<lo+BINS){
      int pos = atomicAdd(&cur[ds-lo],1);
      ss[pos] = s[e];
    }
  }
}

__global__ __launch_bounds__(256) void k_copyx(float* fb, const float* x0,const float* x1,const float* x2) {
  int i = blockIdx.x*256 + threadIdx.x;
  int g = blockIdx.y;
  const float* x = g==0?x0:(g==1?x1:x2);
  if (i < N*H/4) {
    ((float4*)(fb + (size_t)g*GF + X_OFF))[i] = ((const float4*)x)[i];
  }
}

// Tiled matmul: 64 rows/block, 4 threads/row (q = 16-col group), acc[16].
__global__ __launch_bounds__(256) void k_mm_gcn(float* fb, uchar_t* hb,
    const float* W0,const float* W1,const float* W2, float* sm) {
  if (blockIdx.x==0 && blockIdx.y==0){
    for (int i=threadIdx.x;i<384;i+=256) sm[i]=0.f;
  }
  int g = blockIdx.y;
  const float* W = g==0?W0:(g==1?W1:W2);
  __shared__ float Ws[64*64];
  __shared__ float Xs[64*65];
  float* fg = fb + (size_t)g*GF;
  int row0 = blockIdx.x*64;
  for (int i=threadIdx.x; i<4096; i+=256) Ws[i] = W[i];
  int r = threadIdx.x>>2, q = threadIdx.x&3;
  int row = row0 + r;
  int rowc = row < N ? row : N-1;
  {
    const float4* xr = (const float4*)(fg + X_OFF + (size_t)rowc*64) + q*4;
    float* xd = Xs + r*65 + q*16;
    #pragma unroll
    for (int c=0;c<4;c++){ float4 v = xr[c]; xd[4*c]=v.x; xd[4*c+1]=v.y; xd[4*c+2]=v.z; xd[4*c+3]=v.w; }
  }
  __syncthreads();
  float acc[16];
  #pragma unroll
  for (int j=0;j<16;j++) acc[j]=0.f;
  const float* xrow = Xs + r*65;
  #pragma unroll 8
  for (int k=0;k<64;k++){
    float xk = xrow[k];
    const float* wr = Ws + k*64 + q*16;
    #pragma unroll
    for (int j=0;j<16;j++) acc[j] = fmaf(xk, wr[j], acc[j]);
  }
  if (row >= N) return;
  float sc = fg[NO_OFF + row];
  uint_t pk[4];
  #pragma unroll
  for (int j=0;j<4;j++)
    pk[j] = f8pack4(acc[4*j]*sc, acc[4*j+1]*sc, acc[4*j+2]*sc, acc[4*j+3]*sc);
  *(uint4*)(hb + (size_t)g*GH + (size_t)row*64 + q*16) = *(const uint4*)pk;
}

// Same tiling; h = fp8(x @ Wgat[g]); el/er via quad shfl reduce.
__global__ __launch_bounds__(256) void k_mm_gat(float* fb, uchar_t* hb,
    const float* Wgat, const float* al, const float* ar) {
  int g = blockIdx.y;
  const float* W = Wgat + (size_t)g*4096;
  __shared__ float Ws[64*64];
  __shared__ float Xs[64*65];
  __shared__ float als[64], ars[64];
  float* fg = fb + (size_t)g*GF;
  int row0 = blockIdx.x*64;
  for (int i=threadIdx.x; i<4096; i+=256) Ws[i] = W[i];
  if (threadIdx.x < 64){ als[threadIdx.x] = al[g*64+threadIdx.x]; ars[threadIdx.x] = ar[g*64+threadIdx.x]; }
  int r = threadIdx.x>>2, q = threadIdx.x&3;
  int row = row0 + r;
  int rowc = row < N ? row : N-1;
  {
    const float4* xr = (const float4*)(fg + X_OFF + (size_t)rowc*64) + q*4;
    float* xd = Xs + r*65 + q*16;
    #pragma unroll
    for (int c=0;c<4;c++){ float4 v = xr[c]; xd[4*c]=v.x; xd[4*c+1]=v.y; xd[4*c+2]=v.z; xd[4*c+3]=v.w; }
  }
  __syncthreads();
  float acc[16];
  #pragma unroll
  for (int j=0;j<16;j++) acc[j]=0.f;
  const float* xrow = Xs + r*65;
  #pragma unroll 8
  for (int k=0;k<64;k++){
    float xk = xrow[k];
    const float* wr = Ws + k*64 + q*16;
    #pragma unroll
    for (int j=0;j<16;j++) acc[j] = fmaf(xk, wr[j], acc[j]);
  }
  float el = 0.f, er = 0.f;
  #pragma unroll
  for (int j=0;j<16;j++){ el = fmaf(acc[j], als[q*16+j], el); er = fmaf(acc[j], ars[q*16+j], er); }
  el += __shfl_xor(el,1); el += __shfl_xor(el,2);
  er += __shfl_xor(er,1); er += __shfl_xor(er,2);
  if (row >= N) return;
  uint_t pk[4];
  #pragma unroll
  for (int j=0;j<4;j++)
    pk[j] = f8pack4(acc[4*j], acc[4*j+1], acc[4*j+2], acc[4*j+3]);
  *(uint4*)(hb + (size_t)g*GH + (size_t)row*64 + q*16) = *(const uint4*)pk;
  if (q == 0){
    fg[EL_OFF + row] = el;
    fg[ER_OFF + row] = er;
  }
}

// GCN aggregate — group-per-node layout (XCD affinity kept).
// lane = (v = node group 0-3, u = dword 0-15). Group v owns node w+NWAVE*v:
// each of its 16 lanes owns dword u of the output row. Per 16-edge round:
// 16 full-row gathers in flight (lane (v,u) loads row idx_j dword u; idx_j
// broadcast via __shfl within the group). No per-node cross-lane reduction,
// no idle lanes; degree divergence across groups via exec mask. Readout
// sum/max across groups once per wave via shfl_xor(16/32).
__global__ __launch_bounds__(256) void k_gcn_agg(float* fb, const uchar_t* hb, const int* ib,
    const float* b0, const float* b1, const float* b2, int lay, float* sm, int writex) {
  int g, blk;
  swz_tile(blockIdx.x, g, blk);
  const float* b = (g==0?b0:(g==1?b1:b2)) + lay*64;
  float* fg = fb + (size_t)g*GF;
  const uint_t* hu = (const uint_t*)(hb + (size_t)g*GH);  // 16 uints per row
  const int* ig = ib + (size_t)g*GI;
  int wave = threadIdx.x >> 6, lane = threadIdx.x & 63;
  int v = lane >> 4, u = lane & 15;
  int base = lane & 48;                                   // group's lane base
  int w = blk*4 + wave;
  int node = w + NWAVE*v;
  const int* rp = ig + RP_OFF;
  const int* ss = ig + SS_OFF;
  fl4 bl = ((const fl4*)b)[u];
  __shared__ float ssum[4][64];
  __shared__ float smx[4][64];

  int s0 = rp[node], s1 = rp[node+1];
  float ni = fg[NI_OFF + node];
  fl4 a = f8up4(hu[(size_t)node*16 + u]);                 // self loop (pre-scaled)
  int idxv;
  { int ei = s0 + u; int ec = ei < s1 ? ei : s0;
    idxv = __builtin_nontemporal_load(&ss[ec]); }

  for (int kb = s0; kb < s1; kb += 16){                   // group-divergent loop
    uint_t vv[16];
    #pragma unroll
    for (int j=0;j<16;j++){
      int ij = __shfl(idxv, base + j);
      vv[j] = hu[(size_t)ij*16 + u];
    }
    int kn = kb + 16;
    if (kn < s1){                                         // prefetch next round
      int ei = kn + u; int ec = ei < s1 ? ei : s0;
      idxv = __builtin_nontemporal_load(&ss[ec]);
    }
    #pragma unroll
    for (int j=0;j<16;j++){
      float wj = (kb + j) < s1 ? 1.f : 0.f;
      fl4 f = f8up4(vv[j]);
      a.x = fmaf(wj, f.x, a.x); a.y = fmaf(wj, f.y, a.y);
      a.z = fmaf(wj, f.z, a.z); a.w = fmaf(wj, f.w, a.w);
    }
  }

  fl4 vo;
  vo.x = fmaf(a.x, ni, bl.x); vo.x = vo.x > 0.f ? vo.x : 0.f;
  vo.y = fmaf(a.y, ni, bl.y); vo.y = vo.y > 0.f ? vo.y : 0.f;
  vo.z = fmaf(a.z, ni, bl.z); vo.z = vo.z > 0.f ? vo.z : 0.f;
  vo.w = fmaf(a.w, ni, bl.w); vo.w = vo.w > 0.f ? vo.w : 0.f;
  if (writex){
    fl4* xp = (fl4*)(fg + X_OFF + (size_t)node*64);
    __builtin_nontemporal_store(vo, &xp[u]);
  }
  // readout: sum/max across the wave's 4 nodes (groups) once
  fl4 vs = vo, vm = vo;
  vs.x += __shfl_xor(vs.x,16); vs.x += __shfl_xor(vs.x,32);
  vs.y += __shfl_xor(vs.y,16); vs.y += __shfl_xor(vs.y,32);
  vs.z += __shfl_xor(vs.z,16); vs.z += __shfl_xor(vs.z,32);
  vs.w += __shfl_xor(vs.w,16); vs.w += __shfl_xor(vs.w,32);
  vm.x = fmaxf(vm.x, __shfl_xor(vm.x,16)); vm.x = fmaxf(vm.x, __shfl_xor(vm.x,32));
  vm.y = fmaxf(vm.y, __shfl_xor(vm.y,16)); vm.y = fmaxf(vm.y, __shfl_xor(vm.y,32));
  vm.z = fmaxf(vm.z, __shfl_xor(vm.z,16)); vm.z = fmaxf(vm.z, __shfl_xor(vm.z,32));
  vm.w = fmaxf(vm.w, __shfl_xor(vm.w,16)); vm.w = fmaxf(vm.w, __shfl_xor(vm.w,32));
  if (lane < 16){
    ((fl4*)ssum[wave])[u] = vs;
    ((fl4*)smx[wave])[u]  = vm;
  }
  __syncthreads();
  if (threadIdx.x < 64){
    int t = threadIdx.x;
    float s = ssum[0][t]+ssum[1][t]+ssum[2][t]+ssum[3][t];
    float mx = fmaxf(fmaxf(smx[0][t],smx[1][t]), fmaxf(smx[2][t],smx[3][t]));
    atomicAdd(&sm[g*64 + t], s);
    atomicMax((int*)sm + 192 + g*64 + t, __float_as_int(mx));  // v>=0: int order == float order
  }
}

// readout finalize + cross-graph feature exchange + supernode h row (fp8), el[N]
__global__ void k_exchange(float* fb, uchar_t* hb, float* sm, const float* Wx, const float* bx,
                           const float* Wgat, const float* al, int it) {
  int gt = blockIdx.x;     // target graph
  int t = threadIdx.x;     // 64 threads
  int src, widx;
  if ((it & 1) == 0){ src = (gt==0)?1:(gt==1)?2:0; widx = (gt==0)?1:(gt==1)?0:2; }
  else              { src = (gt==0)?2:(gt==1)?0:1; widx = (gt==0)?5:(gt==1)?3:4; }
  __shared__ float ro[128];
  __shared__ float f[64];
  __shared__ float red[64];
  __shared__ float hsb[64];
  ro[t]      = sm[src*64 + t] * (1.0f/(float)N);
  ro[64 + t] = __int_as_float(((int*)sm)[192 + src*64 + t]);
  __syncthreads();
  float a = bx[widx*64 + t];
  for (int k=0;k<128;k++) a = fmaf(ro[k], Wx[(size_t)widx*8192 + k*64 + t], a);
  a = a > 0.f ? a : 0.f;
  f[t] = a;
  __syncthreads();
  float* fg = fb + (size_t)gt*GF;
  float hs = 0.f;
  for (int k=0;k<64;k++) hs = fmaf(f[k], Wgat[(size_t)gt*4096 + k*64 + t], hs);
  hsb[t] = hs;
  red[t] = hs * al[gt*64 + t];
  __syncthreads();
  if (t < 16){
    uint_t r = f8pack4(hsb[4*t], hsb[4*t+1], hsb[4*t+2], hsb[4*t+3]);
    ((uint_t*)(hb + (size_t)gt*GH + (size_t)N*64))[t] = r;
  }
  if (t == 0){
    float e = 0.f;
    for (int k=0;k<64;k++) e += red[k];
    fg[EL_OFF + N] = e;                      // el for supernode
  }
}

// GAT softmax prep: wave per 4 nodes, interleaved phases (all ss loads ->
// all el gathers -> compute); el table is 200KB/graph so it L2-caches fine.
__global__ __launch_bounds__(256) void k_gat_prep(float* fb, const int* ib) {
  int g = blockIdx.y;
  float* fg = fb + (size_t)g*GF;
  const int* ig = ib + (size_t)g*GI;
  const int* rp = ig + RP_OFF;
  const int* ss = ig + SS_OFF;
  const float* el = fg + EL_OFF;
  float* ee = fg + EE_OFF;
  int wave = threadIdx.x>>6, lane = threadIdx.x&63;
  int w = blockIdx.x*4 + wave;
  float elsup = el[N];
  int node[4], s0[4], s1[4];
  #pragma unroll
  for (int i=0;i<4;i++){ node[i] = w + NWAVE*i; s0[i] = rp[node[i]]; s1[i] = rp[node[i]+1]; }
  float eri[4];
  #pragma unroll
  for (int i=0;i<4;i++) eri[i] = fg[ER_OFF + node[i]];
  int sv[4];
  #pragma unroll
  for (int i=0;i<4;i++){ int e = s0[i] + lane; sv[i] = __builtin_nontemporal_load(&ss[e < s1[i] ? e : 0]); }
  float ev[4];
  #pragma unroll
  for (int i=0;i<4;i++) ev[i] = el[sv[i]];
  #pragma unroll
  for (int i=0;i<4;i++){
    int e = s0[i] + lane;
    float x = ev[i] + eri[i];
    x = x >= 0.f ? x : 0.2f*x;
    float t = 0.f;
    if (e < s1[i]){ t = __expf(x); __builtin_nontemporal_store(t, &ee[e]); }
    float s = t;
    for (int k = s0[i]+64; k < s1[i]; k += 64){          // wave-uniform, ~never
      int e2 = k + lane;
      float t2 = 0.f;
      if (e2 < s1[i]){
        float x2 = el[ss[e2]] + eri[i];
        x2 = x2 >= 0.f ? x2 : 0.2f*x2;
        t2 = __expf(x2);
        __builtin_nontemporal_store(t2, &ee[e2]);
      }
      s += t2;
    }
    #pragma unroll
    for (int m=1;m<64;m<<=1) s += __shfl_xor(s,m);
    if (lane == 0){
      float eself = el[node[i]] + eri[i]; eself = eself >= 0.f ? eself : 0.2f*eself;
      float esup  = elsup + eri[i];       esup  = esup  >= 0.f ? esup  : 0.2f*esup;
      float ts = __expf(eself), tu = __expf(esup);
      s += ts + tu;
      fg[IS_OFF + node[i]]   = 1.0f / s;
      fg[ASLF_OFF + node[i]] = ts;
      fg[ASUP_OFF + node[i]] = tu;
    }
  }
}

// GAT aggregation — group-per-node layout, mirrors k_gcn_agg; per-edge ee
// weights broadcast from the saved round-register wold.
__global__ __launch_bounds__(256) void k_gat_agg(float* fb, const uchar_t* hb, const int* ib,
    const float* bgat) {
  int g, blk;
  swz_tile(blockIdx.x, g, blk);
  float* fg = fb + (size_t)g*GF;
  const uint_t* hu = (const uint_t*)(hb + (size_t)g*GH);
  const int* ig = ib + (size_t)g*GI;
  int wave = threadIdx.x >> 6, lane = threadIdx.x & 63;
  int v = lane >> 4, u = lane & 15;
  int base = lane & 48;
  int w = blk*4 + wave;
  int node = w + NWAVE*v;
  const int* rp = ig + RP_OFF;
  const int* ss = ig + SS_OFF;
  const float* ee = fg + EE_OFF;
  fl4 bg = ((const fl4*)(bgat + g*64))[u];
  fl4 supf = f8up4(hu[(size_t)N*16 + u]);

  int s0 = rp[node], s1 = rp[node+1];
  float isv  = fg[IS_OFF + node];
  float aslf = fg[ASLF_OFF + node];
  float asup = fg[ASUP_OFF + node];
  fl4 fs = f8up4(hu[(size_t)node*16 + u]);
  fl4 a;
  a.x = fmaf(asup, supf.x, aslf*fs.x);
  a.y = fmaf(asup, supf.y, aslf*fs.y);
  a.z = fmaf(asup, supf.z, aslf*fs.z);
  a.w = fmaf(asup, supf.w, aslf*fs.w);

  int idxv; float wtv;
  { int ei = s0 + u; int ec = ei < s1 ? ei : s0;
    idxv = __builtin_nontemporal_load(&ss[ec]);
    wtv  = __builtin_nontemporal_load(&ee[ec]); }

  for (int kb = s0; kb < s1; kb += 16){                   // group-divergent loop
    uint_t vv[16];
    #pragma unroll
    for (int j=0;j<16;j++){
      int ij = __shfl(idxv, base + j);
      vv[j] = hu[(size_t)ij*16 + u];
    }
    float wold = wtv;
    int kn = kb + 16;
    if (kn < s1){                                         // prefetch next round
      int ei = kn + u; int ec = ei < s1 ? ei : s0;
      idxv = __builtin_nontemporal_load(&ss[ec]);
      wtv  = __builtin_nontemporal_load(&ee[ec]);
    }
    #pragma unroll
    for (int j=0;j<16;j++){
      float wj = __shfl(wold, base + j);
      wj = (kb + j) < s1 ? wj : 0.f;
      fl4 f = f8up4(vv[j]);
      a.x = fmaf(wj, f.x, a.x); a.y = fmaf(wj, f.y, a.y);
      a.z = fmaf(wj, f.z, a.z); a.w = fmaf(wj, f.w, a.w);
    }
  }

  fl4 vo;
  vo.x = fmaf(a.x, isv, bg.x); vo.y = fmaf(a.y, isv, bg.y);
  vo.z = fmaf(a.z, isv, bg.z); vo.w = fmaf(a.w, isv, bg.w);
  fl4* xp = (fl4*)(fg + X_OFF + (size_t)node*64);
  __builtin_nontemporal_store(vo, &xp[u]);
}

__global__ __launch_bounds__(384) void k_mlp(const float* sm, const float* W1, const float* b1,
    const float* W2, const float* b2, const float* W3, const float* b3, float* out) {
  __shared__ float nf[384];
  __shared__ float y1[192];
  __shared__ float y2[96];
  __shared__ float z[2];
  int t = threadIdx.x;
  int g = t / 128, j = t % 128;
  nf[t] = (j < 64) ? sm[g*64 + j] * (1.0f/(float)N)
                   : __int_as_float(((const int*)sm)[192 + g*64 + (j-64)]);
  __syncthreads();
  if (t < 192){
    float a = b1[t];
    for (int k=0;k<384;k++) a = fmaf(nf[k], W1[(size_t)k*192 + t], a);
    y1[t] = a > 0.f ? a : 0.f;
  }
  __syncthreads();
  if (t < 96){
    float a = b2[t];
    for (int k=0;k<192;k++) a = fmaf(y1[k], W2[(size_t)k*96 + t], a);
    y2[t] = a > 0.f ? a : 0.f;
  }
  __syncthreads();
  if (t < 2){
    float a = b3[t];
    for (int k=0;k<96;k++) a = fmaf(y2[k], W3[k*2 + t], a);
    z[t] = a;
  }
  __syncthreads();
  if (t == 0){
    float m = fmaxf(z[0], z[1]);
    float l = m + logf(__expf(z[0]-m) + __expf(z[1]-m));
    out[0] = z[0] - l;
    out[1] = z[1] - l;
  }
}

extern "C" void kernel_launch(void* const* d_in, const int* in_sizes, int n_in,
                              void* d_out, int out_size, void* d_ws, size_t ws_size,
                              hipStream_t stream) {
  const float* x_s  = (const float*)d_in[0];
  const float* x_g  = (const float*)d_in[1];
  const float* x_t  = (const float*)d_in[2];
  const float* Wc_s = (const float*)d_in[3];
  const float* bc_s = (const float*)d_in[4];
  const float* Wc_g = (const float*)d_in[5];
  const float* bc_g = (const float*)d_in[6];
  const float* Wc_t = (const float*)d_in[7];
  const float* bc_t = (const float*)d_in[8];
  const float* Wx   = (const float*)d_in[9];
  const float* bx   = (const float*)d_in[10];
  const float* Wgat = (const float*)d_in[11];
  const float* al   = (const float*)d_in[12];
  const float* ar   = (const float*)d_in[13];
  const float* bgat = (const float*)d_in[14];
  const float* W1   = (const float*)d_in[15];
  const float* b1   = (const float*)d_in[16];
  const float* W2   = (const float*)d_in[17];
  const float* b2   = (const float*)d_in[18];
  const float* W3   = (const float*)d_in[19];
  const float* b3   = (const float*)d_in[20];
  const int* src_s  = (const int*)d_in[21];
  const int* dst_s  = (const int*)d_in[22];
  const int* src_g  = (const int*)d_in[23];
  const int* dst_g  = (const int*)d_in[24];
  const int* src_t  = (const int*)d_in[25];
  const int* dst_t  = (const int*)d_in[26];

  float* fb = (float*)d_ws;
  int*   ib = (int*)(fb + 3*GF);
  uchar_t* hb = (uchar_t*)(ib + 3*GI);
  float* sm = (float*)(hb + 3*GH);
  int*   pt = (int*)(sm + 384);              // 3*SCB scan partials
  int*   parts_ct = pt + 3*SCB + 64;         // 3*BPR*N
  int*   parts_no = parts_ct + (size_t)3*BPR*N;
  int*   off      = parts_no + (size_t)3*BPR*N;
  float* out = (float*)d_out;

  dim3 b256(256);
  int mmb = (N+63)/64;

  // graph prep: LDS-histogram counting sort (no global atomics)
  k_hist      <<<dim3(BPR, RNG, 3),  dim3(1024), 0, stream>>>(parts_ct, parts_no, src_s,dst_s, src_g,dst_g, src_t,dst_t);
  k_scan_local<<<dim3(SCB, 3),       dim3(1024), 0, stream>>>(ib, pt, parts_ct);
  k_scan_part <<<dim3(3),              dim3(64), 0, stream>>>(pt);
  k_scan_apply<<<dim3(SCB, 3),       dim3(1024), 0, stream>>>(fb, ib, pt, parts_no);
  k_slice_off <<<dim3((N+255)/256, 3),     b256, 0, stream>>>(ib, parts_ct, off);
  k_scatter_r <<<dim3(BPR, RNG, 3),  dim3(1024), 0, stream>>>(ib, off, src_s,dst_s, src_g,dst_g, src_t,dst_t);
  k_copyx     <<<dim3((N*H/4+255)/256, 3), b256, 0, stream>>>(fb, x_s, x_g, x_t);

  for (int it = 0; it < 2; ++it) {
    k_mm_gcn  <<<dim3(mmb, 3),     b256, 0, stream>>>(fb, hb, Wc_s + it*4096, Wc_g + it*4096, Wc_t + it*4096, sm);
    k_gcn_agg <<<dim3(3*AGB),      b256, 0, stream>>>(fb, hb, ib, bc_s, bc_g, bc_t, it, sm, 1);
    k_exchange<<<dim3(3), dim3(64), 0, stream>>>(fb, hb, sm, Wx, bx, Wgat, al, it);
    k_mm_gat  <<<dim3(mmb, 3),     b256, 0, stream>>>(fb, hb, Wgat, al, ar);
    k_gat_prep<<<dim3(AGB, 3),     b256, 0, stream>>>(fb, ib);
    k_gat_agg <<<dim3(3*AGB),      b256, 0, stream>>>(fb, hb, ib, bgat);
  }

  // final layer readouts + MLP head (x write skipped — only readout consumed)
  k_mm_gcn  <<<dim3(mmb, 3),     b256, 0, stream>>>(fb, hb, Wc_s + 2*4096, Wc_g + 2*4096, Wc_t + 2*4096, sm);
  k_gcn_agg <<<dim3(3*AGB),      b256, 0, stream>>>(fb, hb, ib, bc_s, bc_g, bc_t, 2, sm, 0);
  k_mlp     <<<1, 384, 0, stream>>>(sm, W1, b1, W2, b2, W3, b3, out);
}

// Round 7
// 809.455 us; speedup vs baseline: 1.6260x; 1.1002x over previous
//
#include <hip/hip_runtime.h>
#include <math.h>

constexpr int N = 50000;
constexpr int E = 800000;
constexpr int H = 64;
constexpr int NWAVE = 12500;          // N/4 nodes-per-wave mapping (4 nodes per wave)
constexpr int AGB = 3125;             // agg blocks (tiles) per graph (NWAVE/4)
constexpr int SCB = 49;               // scan blocks per graph: 49*1024 >= N
constexpr int RNG = 8;                // histogram ranges per graph
constexpr int BPR = 8;                // edge slices per graph
constexpr int BINS = N / RNG;         // 6250 bins per range
constexpr int ES   = E / BPR;         // 100000 edges per slice

// XCD-affinity swizzle constants (stateless, replay-safe).
constexpr int FULLR = AGB / 3;        // 1041 full rounds
constexpr int FULLB = FULLR * 8;      // 8328 bids in full rounds
constexpr int G2F   = FULLR * 2;      // 2082 g2 tiles from full rounds
constexpr int REM0  = AGB - 3*FULLR;  // 2 leftover g0 tiles
static_assert(3*FULLR + REM0 == AGB, "g0 cover");
static_assert(2*FULLR + (3*AGB - FULLB - 2*REM0) == AGB, "g2 cover");

typedef unsigned short ushort_t;
typedef unsigned int uint_t;
typedef unsigned char uchar_t;
typedef float fl2 __attribute__((ext_vector_type(2)));
typedef float fl4 __attribute__((ext_vector_type(4)));

// ---- workspace layout (element offsets) ----
constexpr size_t X_OFF    = 0;                          // N*H
constexpr size_t NO_OFF   = X_OFF + (size_t)N*H;        // N   deg_out^-1/2
constexpr size_t NI_OFF   = NO_OFF + N;                 // N   deg_in^-1/2
constexpr size_t EL_OFF   = NI_OFF + N;                 // N+1 GAT el (incl supernode)
constexpr size_t ER_OFF   = EL_OFF + (N+1);             // N   GAT er
constexpr size_t EE_OFF   = ER_OFF + N;                 // E   (unused after fusion; layout kept)
constexpr size_t IS_OFF   = EE_OFF + E;                 // N   (unused after fusion)
constexpr size_t ASLF_OFF = IS_OFF + N;                 // N   (unused after fusion)
constexpr size_t ASUP_OFF = ASLF_OFF + N;               // N   (unused after fusion)
constexpr size_t GF = ((ASUP_OFF + N + 255)/256)*256;

constexpr size_t RP_OFF = 0;                            // N+1 row_ptr (CSR by dst)
constexpr size_t CT_OFF = RP_OFF + (N+1);               // N   in-degree count
constexpr size_t SS_OFF = CT_OFF + N;                   // E   src sorted by dst
constexpr size_t GI = ((SS_OFF + E + 255)/256)*256;     // ss[E] (clamp slack) stays in-bounds

// per-graph fp8 h block: 64 B per row (64 x e4m3 = 16 uints); row N = supernode
constexpr size_t GH = (size_t)(N+1)*64;                 // bytes

// fp8 helpers: HW RNE pack/unpack (OCP e4m3 on gfx950)
__device__ inline uint_t f8pack4(float a, float b, float c, float d){
  int r = __builtin_amdgcn_cvt_pk_fp8_f32(a, b, 0, false);
  r = __builtin_amdgcn_cvt_pk_fp8_f32(c, d, r, true);
  return (uint_t)r;
}
__device__ inline fl4 f8up4(uint_t v){
  fl2 lo = __builtin_amdgcn_cvt_pk_f32_fp8((int)v, false);
  fl2 hi = __builtin_amdgcn_cvt_pk_f32_fp8((int)v, true);
  fl4 r; r.x = lo.x; r.y = lo.y; r.z = hi.x; r.w = hi.y;
  return r;
}

// Deterministic bid -> (graph, tile) swizzle for XCD L2 affinity.
__device__ inline void swz_tile(int bid, int& g, int& b){
  if (bid < FULLB){
    int r = bid >> 3, s = bid & 7;
    if (s < 3){ g = 0; b = r*3 + s; }
    else if (s < 6){ g = 1; b = r*3 + (s-3); }
    else { g = 2; b = r*2 + (s-6); }
  } else {
    int t = bid - FULLB;
    if (t < REM0){ g = 0; b = 3*FULLR + t; }
    else if (t < 2*REM0){ g = 1; b = 3*FULLR + (t-REM0); }
    else { g = 2; b = G2F + (t-2*REM0); }
  }
}

// ---- prep: range-partitioned LDS histograms, zero global atomics ----
__global__ __launch_bounds__(1024) void k_hist(int* parts_ct, int* parts_no,
    const int* s0,const int* d0,const int* s1,const int* d1,const int* s2,const int* d2) {
  int sl = blockIdx.x, r = blockIdx.y, g = blockIdx.z;
  const int* s = g==0?s0:(g==1?s1:s2);
  const int* d = g==0?d0:(g==1?d1:d2);
  __shared__ int hc[BINS];
  __shared__ int hn[BINS];
  for (int i=threadIdx.x;i<BINS;i+=1024){ hc[i]=0; hn[i]=0; }
  __syncthreads();
  int lo = r*BINS, hi = lo+BINS;
  int e0 = sl*ES, e1 = e0+ES;
  for (int e=e0+threadIdx.x; e<e1; e+=1024){
    int ds = d[e], sr = s[e];
    if (ds>=lo && ds<hi) atomicAdd(&hc[ds-lo],1);
    if (sr>=lo && sr<hi) atomicAdd(&hn[sr-lo],1);
  }
  __syncthreads();
  size_t base = ((size_t)g*BPR + sl)*N + lo;
  for (int i=threadIdx.x;i<BINS;i+=1024){
    parts_ct[base+i]=hc[i];
    parts_no[base+i]=hn[i];
  }
}

// ---- hierarchical exclusive scan of cnt -> rp (all parallel) ----
__global__ __launch_bounds__(1024) void k_scan_local(int* ib, int* pt, const int* parts_ct) {
  int g = blockIdx.y;
  int* ig = ib + (size_t)g*GI;
  int i = blockIdx.x*1024 + threadIdx.x;
  int c = 0;
  if (i < N){
    #pragma unroll
    for (int s=0;s<BPR;s++) c += parts_ct[((size_t)g*BPR+s)*N + i];
    ig[CT_OFF + i] = c;
  }
  __shared__ int sh[1024];
  sh[threadIdx.x] = c; __syncthreads();
  #pragma unroll
  for (int off=1; off<1024; off<<=1){
    int t = (threadIdx.x>=off) ? sh[threadIdx.x-off] : 0;
    __syncthreads();
    sh[threadIdx.x] += t;
    __syncthreads();
  }
  if (i < N) ig[RP_OFF + i] = sh[threadIdx.x] - c;       // local exclusive
  if (threadIdx.x == 1023) pt[g*SCB + blockIdx.x] = sh[1023];
}

__global__ void k_scan_part(int* pt) {
  int g = blockIdx.x;
  __shared__ int sh[SCB];
  int t = threadIdx.x;
  if (t < SCB) sh[t] = pt[g*SCB + t];
  __syncthreads();
  if (t == 0){
    int run = 0;
    for (int b=0;b<SCB;b++){ int c = sh[b]; sh[b] = run; run += c; }
  }
  __syncthreads();
  if (t < SCB) pt[g*SCB + t] = sh[t];
}

__global__ __launch_bounds__(1024) void k_scan_apply(float* fb, int* ib, const int* pt,
                                                     const int* parts_no) {
  int g = blockIdx.y;
  float* fg = fb + (size_t)g*GF;
  int* ig = ib + (size_t)g*GI;
  int i = blockIdx.x*1024 + threadIdx.x;
  if (i >= N) return;
  int base = pt[g*SCB + blockIdx.x];
  int r = ig[RP_OFF + i] + base;
  ig[RP_OFF + i] = r;
  int c = ig[CT_OFF + i];
  int o = 0;
  #pragma unroll
  for (int s=0;s<BPR;s++) o += parts_no[((size_t)g*BPR+s)*N + i];
  fg[NI_OFF + i] = rsqrtf((float)(c+1));                 // +1 self loop
  fg[NO_OFF + i] = rsqrtf((float)(o+1));
  if (i == N-1) ig[RP_OFF + N] = r + c;
}

// per-(slice,bin) exclusive prefix over slices -> exact scatter offsets
__global__ __launch_bounds__(256) void k_slice_off(const int* ib, const int* parts_ct, int* off) {
  int g = blockIdx.y;
  int i = blockIdx.x*256 + threadIdx.x;
  if (i >= N) return;
  int base = ib[(size_t)g*GI + RP_OFF + i];
  #pragma unroll
  for (int s=0;s<BPR;s++){
    size_t idx = ((size_t)g*BPR+s)*N + i;
    off[idx] = base;
    base += parts_ct[idx];
  }
}

// scatter: LDS cursors per range, plain scattered store (no global atomics)
__global__ __launch_bounds__(1024) void k_scatter_r(int* ib, const int* off,
    const int* s0,const int* d0,const int* s1,const int* d1,const int* s2,const int* d2) {
  int sl = blockIdx.x, r = blockIdx.y, g = blockIdx.z;
  const int* s = g==0?s0:(g==1?s1:s2);
  const int* d = g==0?d0:(g==1?d1:d2);
  int* ss = ib + (size_t)g*GI + SS_OFF;
  __shared__ int cur[BINS];
  int lo = r*BINS;
  size_t ob = ((size_t)g*BPR + sl)*N + lo;
  for (int i=threadIdx.x;i<BINS;i+=1024) cur[i] = off[ob+i];
  __syncthreads();
  int e0 = sl*ES, e1 = e0+ES;
  for (int e=e0+threadIdx.x; e<e1; e+=1024){
    int ds = d[e];
    if (ds>=lo && ds<lo+BINS){
      int pos = atomicAdd(&cur[ds-lo],1);
      ss[pos] = s[e];
    }
  }
}

__global__ __launch_bounds__(256) void k_copyx(float* fb, const float* x0,const float* x1,const float* x2) {
  int i = blockIdx.x*256 + threadIdx.x;
  int g = blockIdx.y;
  const float* x = g==0?x0:(g==1?x1:x2);
  if (i < N*H/4) {
    ((float4*)(fb + (size_t)g*GF + X_OFF))[i] = ((const float4*)x)[i];
  }
}

// Tiled matmul: 64 rows/block, 4 threads/row (q = 16-col group), acc[16].
__global__ __launch_bounds__(256) void k_mm_gcn(float* fb, uchar_t* hb,
    const float* W0,const float* W1,const float* W2, float* sm) {
  if (blockIdx.x==0 && blockIdx.y==0){
    for (int i=threadIdx.x;i<384;i+=256) sm[i]=0.f;
  }
  int g = blockIdx.y;
  const float* W = g==0?W0:(g==1?W1:W2);
  __shared__ float Ws[64*64];
  __shared__ float Xs[64*65];
  float* fg = fb + (size_t)g*GF;
  int row0 = blockIdx.x*64;
  for (int i=threadIdx.x; i<4096; i+=256) Ws[i] = W[i];
  int r = threadIdx.x>>2, q = threadIdx.x&3;
  int row = row0 + r;
  int rowc = row < N ? row : N-1;
  {
    const float4* xr = (const float4*)(fg + X_OFF + (size_t)rowc*64) + q*4;
    float* xd = Xs + r*65 + q*16;
    #pragma unroll
    for (int c=0;c<4;c++){ float4 v = xr[c]; xd[4*c]=v.x; xd[4*c+1]=v.y; xd[4*c+2]=v.z; xd[4*c+3]=v.w; }
  }
  __syncthreads();
  float acc[16];
  #pragma unroll
  for (int j=0;j<16;j++) acc[j]=0.f;
  const float* xrow = Xs + r*65;
  #pragma unroll 8
  for (int k=0;k<64;k++){
    float xk = xrow[k];
    const float* wr = Ws + k*64 + q*16;
    #pragma unroll
    for (int j=0;j<16;j++) acc[j] = fmaf(xk, wr[j], acc[j]);
  }
  if (row >= N) return;
  float sc = fg[NO_OFF + row];
  uint_t pk[4];
  #pragma unroll
  for (int j=0;j<4;j++)
    pk[j] = f8pack4(acc[4*j]*sc, acc[4*j+1]*sc, acc[4*j+2]*sc, acc[4*j+3]*sc);
  *(uint4*)(hb + (size_t)g*GH + (size_t)row*64 + q*16) = *(const uint4*)pk;
}

// Same tiling; h = fp8(x @ Wgat[g]); el/er via quad shfl reduce.
__global__ __launch_bounds__(256) void k_mm_gat(float* fb, uchar_t* hb,
    const float* Wgat, const float* al, const float* ar) {
  int g = blockIdx.y;
  const float* W = Wgat + (size_t)g*4096;
  __shared__ float Ws[64*64];
  __shared__ float Xs[64*65];
  __shared__ float als[64], ars[64];
  float* fg = fb + (size_t)g*GF;
  int row0 = blockIdx.x*64;
  for (int i=threadIdx.x; i<4096; i+=256) Ws[i] = W[i];
  if (threadIdx.x < 64){ als[threadIdx.x] = al[g*64+threadIdx.x]; ars[threadIdx.x] = ar[g*64+threadIdx.x]; }
  int r = threadIdx.x>>2, q = threadIdx.x&3;
  int row = row0 + r;
  int rowc = row < N ? row : N-1;
  {
    const float4* xr = (const float4*)(fg + X_OFF + (size_t)rowc*64) + q*4;
    float* xd = Xs + r*65 + q*16;
    #pragma unroll
    for (int c=0;c<4;c++){ float4 v = xr[c]; xd[4*c]=v.x; xd[4*c+1]=v.y; xd[4*c+2]=v.z; xd[4*c+3]=v.w; }
  }
  __syncthreads();
  float acc[16];
  #pragma unroll
  for (int j=0;j<16;j++) acc[j]=0.f;
  const float* xrow = Xs + r*65;
  #pragma unroll 8
  for (int k=0;k<64;k++){
    float xk = xrow[k];
    const float* wr = Ws + k*64 + q*16;
    #pragma unroll
    for (int j=0;j<16;j++) acc[j] = fmaf(xk, wr[j], acc[j]);
  }
  float el = 0.f, er = 0.f;
  #pragma unroll
  for (int j=0;j<16;j++){ el = fmaf(acc[j], als[q*16+j], el); er = fmaf(acc[j], ars[q*16+j], er); }
  el += __shfl_xor(el,1); el += __shfl_xor(el,2);
  er += __shfl_xor(er,1); er += __shfl_xor(er,2);
  if (row >= N) return;
  uint_t pk[4];
  #pragma unroll
  for (int j=0;j<4;j++)
    pk[j] = f8pack4(acc[4*j], acc[4*j+1], acc[4*j+2], acc[4*j+3]);
  *(uint4*)(hb + (size_t)g*GH + (size_t)row*64 + q*16) = *(const uint4*)pk;
  if (q == 0){
    fg[EL_OFF + row] = el;
    fg[ER_OFF + row] = er;
  }
}

// GCN aggregate — group-per-node layout (XCD affinity kept). UNCHANGED (control).
__global__ __launch_bounds__(256) void k_gcn_agg(float* fb, const uchar_t* hb, const int* ib,
    const float* b0, const float* b1, const float* b2, int lay, float* sm, int writex) {
  int g, blk;
  swz_tile(blockIdx.x, g, blk);
  const float* b = (g==0?b0:(g==1?b1:b2)) + lay*64;
  float* fg = fb + (size_t)g*GF;
  const uint_t* hu = (const uint_t*)(hb + (size_t)g*GH);  // 16 uints per row
  const int* ig = ib + (size_t)g*GI;
  int wave = threadIdx.x >> 6, lane = threadIdx.x & 63;
  int v = lane >> 4, u = lane & 15;
  int base = lane & 48;                                   // group's lane base
  int w = blk*4 + wave;
  int node = w + NWAVE*v;
  const int* rp = ig + RP_OFF;
  const int* ss = ig + SS_OFF;
  fl4 bl = ((const fl4*)b)[u];
  __shared__ float ssum[4][64];
  __shared__ float smx[4][64];

  int s0 = rp[node], s1 = rp[node+1];
  float ni = fg[NI_OFF + node];
  fl4 a = f8up4(hu[(size_t)node*16 + u]);                 // self loop (pre-scaled)
  int idxv;
  { int ei = s0 + u; int ec = ei < s1 ? ei : s0;
    idxv = __builtin_nontemporal_load(&ss[ec]); }

  for (int kb = s0; kb < s1; kb += 16){                   // group-divergent loop
    uint_t vv[16];
    #pragma unroll
    for (int j=0;j<16;j++){
      int ij = __shfl(idxv, base + j);
      vv[j] = hu[(size_t)ij*16 + u];
    }
    int kn = kb + 16;
    if (kn < s1){                                         // prefetch next round
      int ei = kn + u; int ec = ei < s1 ? ei : s0;
      idxv = __builtin_nontemporal_load(&ss[ec]);
    }
    #pragma unroll
    for (int j=0;j<16;j++){
      float wj = (kb + j) < s1 ? 1.f : 0.f;
      fl4 f = f8up4(vv[j]);
      a.x = fmaf(wj, f.x, a.x); a.y = fmaf(wj, f.y, a.y);
      a.z = fmaf(wj, f.z, a.z); a.w = fmaf(wj, f.w, a.w);
    }
  }

  fl4 vo;
  vo.x = fmaf(a.x, ni, bl.x); vo.x = vo.x > 0.f ? vo.x : 0.f;
  vo.y = fmaf(a.y, ni, bl.y); vo.y = vo.y > 0.f ? vo.y : 0.f;
  vo.z = fmaf(a.z, ni, bl.z); vo.z = vo.z > 0.f ? vo.z : 0.f;
  vo.w = fmaf(a.w, ni, bl.w); vo.w = vo.w > 0.f ? vo.w : 0.f;
  if (writex){
    fl4* xp = (fl4*)(fg + X_OFF + (size_t)node*64);
    __builtin_nontemporal_store(vo, &xp[u]);
  }
  // readout: sum/max across the wave's 4 nodes (groups) once
  fl4 vs = vo, vm = vo;
  vs.x += __shfl_xor(vs.x,16); vs.x += __shfl_xor(vs.x,32);
  vs.y += __shfl_xor(vs.y,16); vs.y += __shfl_xor(vs.y,32);
  vs.z += __shfl_xor(vs.z,16); vs.z += __shfl_xor(vs.z,32);
  vs.w += __shfl_xor(vs.w,16); vs.w += __shfl_xor(vs.w,32);
  vm.x = fmaxf(vm.x, __shfl_xor(vm.x,16)); vm.x = fmaxf(vm.x, __shfl_xor(vm.x,32));
  vm.y = fmaxf(vm.y, __shfl_xor(vm.y,16)); vm.y = fmaxf(vm.y, __shfl_xor(vm.y,32));
  vm.z = fmaxf(vm.z, __shfl_xor(vm.z,16)); vm.z = fmaxf(vm.z, __shfl_xor(vm.z,32));
  vm.w = fmaxf(vm.w, __shfl_xor(vm.w,16)); vm.w = fmaxf(vm.w, __shfl_xor(vm.w,32));
  if (lane < 16){
    ((fl4*)ssum[wave])[u] = vs;
    ((fl4*)smx[wave])[u]  = vm;
  }
  __syncthreads();
  if (threadIdx.x < 64){
    int t = threadIdx.x;
    float s = ssum[0][t]+ssum[1][t]+ssum[2][t]+ssum[3][t];
    float mx = fmaxf(fmaxf(smx[0][t],smx[1][t]), fmaxf(smx[2][t],smx[3][t]));
    atomicAdd(&sm[g*64 + t], s);
    atomicMax((int*)sm + 192 + g*64 + t, __float_as_int(mx));  // v>=0: int order == float order
  }
}

// readout finalize + cross-graph feature exchange + supernode h row (fp8), el[N]
__global__ void k_exchange(float* fb, uchar_t* hb, float* sm, const float* Wx, const float* bx,
                           const float* Wgat, const float* al, int it) {
  int gt = blockIdx.x;     // target graph
  int t = threadIdx.x;     // 64 threads
  int src, widx;
  if ((it & 1) == 0){ src = (gt==0)?1:(gt==1)?2:0; widx = (gt==0)?1:(gt==1)?0:2; }
  else              { src = (gt==0)?2:(gt==1)?0:1; widx = (gt==0)?5:(gt==1)?3:4; }
  __shared__ float ro[128];
  __shared__ float f[64];
  __shared__ float red[64];
  __shared__ float hsb[64];
  ro[t]      = sm[src*64 + t] * (1.0f/(float)N);
  ro[64 + t] = __int_as_float(((int*)sm)[192 + src*64 + t]);
  __syncthreads();
  float a = bx[widx*64 + t];
  for (int k=0;k<128;k++) a = fmaf(ro[k], Wx[(size_t)widx*8192 + k*64 + t], a);
  a = a > 0.f ? a : 0.f;
  f[t] = a;
  __syncthreads();
  float* fg = fb + (size_t)gt*GF;
  float hs = 0.f;
  for (int k=0;k<64;k++) hs = fmaf(f[k], Wgat[(size_t)gt*4096 + k*64 + t], hs);
  hsb[t] = hs;
  red[t] = hs * al[gt*64 + t];
  __syncthreads();
  if (t < 16){
    uint_t r = f8pack4(hsb[4*t], hsb[4*t+1], hsb[4*t+2], hsb[4*t+3]);
    ((uint_t*)(hb + (size_t)gt*GH + (size_t)N*64))[t] = r;
  }
  if (t == 0){
    float e = 0.f;
    for (int k=0;k<64;k++) e += red[k];
    fg[EL_OFF + N] = e;                      // el for supernode
  }
}

// GAT aggregation with FUSED online softmax (gat_prep eliminated).
// Group-per-node layout. Per round: lane u's edge index idxv feeds both the
// 16 h-row gathers (via shfl) and an el[idxv] gather (200KB L2-hot table);
// weight wv = exp(leaky(el+er)) computed inline, invalid lanes zeroed, so
// broadcast needs no extra predication. Denominator = running per-lane sum
// of wv, group-reduced once at the end; self/supernode terms added post-
// reduce (once, uniform across lanes). Removes the ee buffer round-trip and
// both k_gat_prep dispatches. Prologue clamp falls back to ss[0] so deg-0
// nodes never gather el with a garbage index.
__global__ __launch_bounds__(256) void k_gat_agg(float* fb, const uchar_t* hb, const int* ib,
    const float* bgat) {
  int g, blk;
  swz_tile(blockIdx.x, g, blk);
  float* fg = fb + (size_t)g*GF;
  const uint_t* hu = (const uint_t*)(hb + (size_t)g*GH);
  const int* ig = ib + (size_t)g*GI;
  int wave = threadIdx.x >> 6, lane = threadIdx.x & 63;
  int v = lane >> 4, u = lane & 15;
  int base = lane & 48;
  int w = blk*4 + wave;
  int node = w + NWAVE*v;
  const int* rp = ig + RP_OFF;
  const int* ss = ig + SS_OFF;
  const float* el = fg + EL_OFF;
  fl4 bg = ((const fl4*)(bgat + g*64))[u];
  fl4 supf = f8up4(hu[(size_t)N*16 + u]);

  int s0 = rp[node], s1 = rp[node+1];
  float ern = fg[ER_OFF + node];
  float eln = el[node];
  float elsup = el[N];
  float es = eln + ern;   es = es >= 0.f ? es : 0.2f*es;  float ts = __expf(es);
  float eu = elsup + ern; eu = eu >= 0.f ? eu : 0.2f*eu;  float tu = __expf(eu);
  fl4 fs = f8up4(hu[(size_t)node*16 + u]);
  fl4 a;
  a.x = fmaf(tu, supf.x, ts*fs.x);
  a.y = fmaf(tu, supf.y, ts*fs.y);
  a.z = fmaf(tu, supf.z, ts*fs.z);
  a.w = fmaf(tu, supf.w, ts*fs.w);
  float ssum = 0.f;

  int idxv; float elv;
  { int ei = s0 + u;
    int ec = ei < s1 ? ei : (s0 < s1 ? s0 : 0);           // always a valid edge slot
    idxv = __builtin_nontemporal_load(&ss[ec]); }
  elv = el[idxv];                                         // safe: idxv in [0,N)

  for (int kb = s0; kb < s1; kb += 16){                   // group-divergent loop
    // this round's weight from prefetched elv (lane u owns edge kb+u)
    float xe = elv + ern; xe = xe >= 0.f ? xe : 0.2f*xe;
    float ex = __expf(xe);
    float wv = (kb + u) < s1 ? ex : 0.f;
    ssum += wv;
    uint_t vv[16];
    #pragma unroll
    for (int j=0;j<16;j++){
      int ij = __shfl(idxv, base + j);
      vv[j] = hu[(size_t)ij*16 + u];
    }
    int kn = kb + 16;
    if (kn < s1){                                         // prefetch next round
      int ei = kn + u; int ec = ei < s1 ? ei : s0;
      idxv = __builtin_nontemporal_load(&ss[ec]);
      elv = el[idxv];
    }
    #pragma unroll
    for (int j=0;j<16;j++){
      float wj = __shfl(wv, base + j);                    // already zero-masked
      fl4 f = f8up4(vv[j]);
      a.x = fmaf(wj, f.x, a.x); a.y = fmaf(wj, f.y, a.y);
      a.z = fmaf(wj, f.z, a.z); a.w = fmaf(wj, f.w, a.w);
    }
  }

  // denominator: reduce edge-exp over the 16-lane group, then + self + sup
  ssum += __shfl_xor(ssum,1); ssum += __shfl_xor(ssum,2);
  ssum += __shfl_xor(ssum,4); ssum += __shfl_xor(ssum,8);
  float is = 1.0f / (ssum + ts + tu);

  fl4 vo;
  vo.x = fmaf(a.x, is, bg.x); vo.y = fmaf(a.y, is, bg.y);
  vo.z = fmaf(a.z, is, bg.z); vo.w = fmaf(a.w, is, bg.w);
  fl4* xp = (fl4*)(fg + X_OFF + (size_t)node*64);
  __builtin_nontemporal_store(vo, &xp[u]);
}

__global__ __launch_bounds__(384) void k_mlp(const float* sm, const float* W1, const float* b1,
    const float* W2, const float* b2, const float* W3, const float* b3, float* out) {
  __shared__ float nf[384];
  __shared__ float y1[192];
  __shared__ float y2[96];
  __shared__ float z[2];
  int t = threadIdx.x;
  int g = t / 128, j = t % 128;
  nf[t] = (j < 64) ? sm[g*64 + j] * (1.0f/(float)N)
                   : __int_as_float(((const int*)sm)[192 + g*64 + (j-64)]);
  __syncthreads();
  if (t < 192){
    float a = b1[t];
    for (int k=0;k<384;k++) a = fmaf(nf[k], W1[(size_t)k*192 + t], a);
    y1[t] = a > 0.f ? a : 0.f;
  }
  __syncthreads();
  if (t < 96){
    float a = b2[t];
    for (int k=0;k<192;k++) a = fmaf(y1[k], W2[(size_t)k*96 + t], a);
    y2[t] = a > 0.f ? a : 0.f;
  }
  __syncthreads();
  if (t < 2){
    float a = b3[t];
    for (int k=0;k<96;k++) a = fmaf(y2[k], W3[k*2 + t], a);
    z[t] = a;
  }
  __syncthreads();
  if (t == 0){
    float m = fmaxf(z[0], z[1]);
    float l = m + logf(__expf(z[0]-m) + __expf(z[1]-m));
    out[0] = z[0] - l;
    out[1] = z[1] - l;
  }
}

extern "C" void kernel_launch(void* const* d_in, const int* in_sizes, int n_in,
                              void* d_out, int out_size, void* d_ws, size_t ws_size,
                              hipStream_t stream) {
  const float* x_s  = (const float*)d_in[0];
  const float* x_g  = (const float*)d_in[1];
  const float* x_t  = (const float*)d_in[2];
  const float* Wc_s = (const float*)d_in[3];
  const float* bc_s = (const float*)d_in[4];
  const float* Wc_g = (const float*)d_in[5];
  const float* bc_g = (const float*)d_in[6];
  const float* Wc_t = (const float*)d_in[7];
  const float* bc_t = (const float*)d_in[8];
  const float* Wx   = (const float*)d_in[9];
  const float* bx   = (const float*)d_in[10];
  const float* Wgat = (const float*)d_in[11];
  const float* al   = (const float*)d_in[12];
  const float* ar   = (const float*)d_in[13];
  const float* bgat = (const float*)d_in[14];
  const float* W1   = (const float*)d_in[15];
  const float* b1   = (const float*)d_in[16];
  const float* W2   = (const float*)d_in[17];
  const float* b2   = (const float*)d_in[18];
  const float* W3   = (const float*)d_in[19];
  const float* b3   = (const float*)d_in[20];
  const int* src_s  = (const int*)d_in[21];
  const int* dst_s  = (const int*)d_in[22];
  const int* src_g  = (const int*)d_in[23];
  const int* dst_g  = (const int*)d_in[24];
  const int* src_t  = (const int*)d_in[25];
  const int* dst_t  = (const int*)d_in[26];

  float* fb = (float*)d_ws;
  int*   ib = (int*)(fb + 3*GF);
  uchar_t* hb = (uchar_t*)(ib + 3*GI);
  float* sm = (float*)(hb + 3*GH);
  int*   pt = (int*)(sm + 384);              // 3*SCB scan partials
  int*   parts_ct = pt + 3*SCB + 64;         // 3*BPR*N
  int*   parts_no = parts_ct + (size_t)3*BPR*N;
  int*   off      = parts_no + (size_t)3*BPR*N;
  float* out = (float*)d_out;

  dim3 b256(256);
  int mmb = (N+63)/64;

  // graph prep: LDS-histogram counting sort (no global atomics)
  k_hist      <<<dim3(BPR, RNG, 3),  dim3(1024), 0, stream>>>(parts_ct, parts_no, src_s,dst_s, src_g,dst_g, src_t,dst_t);
  k_scan_local<<<dim3(SCB, 3),       dim3(1024), 0, stream>>>(ib, pt, parts_ct);
  k_scan_part <<<dim3(3),              dim3(64), 0, stream>>>(pt);
  k_scan_apply<<<dim3(SCB, 3),       dim3(1024), 0, stream>>>(fb, ib, pt, parts_no);
  k_slice_off <<<dim3((N+255)/256, 3),     b256, 0, stream>>>(ib, parts_ct, off);
  k_scatter_r <<<dim3(BPR, RNG, 3),  dim3(1024), 0, stream>>>(ib, off, src_s,dst_s, src_g,dst_g, src_t,dst_t);
  k_copyx     <<<dim3((N*H/4+255)/256, 3), b256, 0, stream>>>(fb, x_s, x_g, x_t);

  for (int it = 0; it < 2; ++it) {
    k_mm_gcn  <<<dim3(mmb, 3),     b256, 0, stream>>>(fb, hb, Wc_s + it*4096, Wc_g + it*4096, Wc_t + it*4096, sm);
    k_gcn_agg <<<dim3(3*AGB),      b256, 0, stream>>>(fb, hb, ib, bc_s, bc_g, bc_t, it, sm, 1);
    k_exchange<<<dim3(3), dim3(64), 0, stream>>>(fb, hb, sm, Wx, bx, Wgat, al, it);
    k_mm_gat  <<<dim3(mmb, 3),     b256, 0, stream>>>(fb, hb, Wgat, al, ar);
    k_gat_agg <<<dim3(3*AGB),      b256, 0, stream>>>(fb, hb, ib, bgat);
  }

  // final layer readouts + MLP head (x write skipped — only readout consumed)
  k_mm_gcn  <<<dim3(mmb, 3),     b256, 0, stream>>>(fb, hb, Wc_s + 2*4096, Wc_g + 2*4096, Wc_t + 2*4096, sm);
  k_gcn_agg <<<dim3(3*AGB),      b256, 0, stream>>>(fb, hb, ib, bc_s, bc_g, bc_t, 2, sm, 0);
  k_mlp     <<<1, 384, 0, stream>>>(sm, W1, b1, W2, b2, W3, b3, out);
}

// Round 8
// 723.466 us; speedup vs baseline: 1.8192x; 1.1189x over previous
//
#include <hip/hip_runtime.h>
#include <math.h>

constexpr int N = 50000;
constexpr int E = 800000;
constexpr int H = 64;
constexpr int NWAVE = 12500;          // node stride between a wave's 4 groups
constexpr int AGB = 3125;             // agg blocks (tiles) per graph
constexpr int SCB = 49;               // scan blocks per graph: 49*1024 >= N
constexpr int RNG = 8;                // histogram ranges per graph
constexpr int BPR = 8;                // edge slices per graph
constexpr int BINS = N / RNG;         // 6250 bins per range
constexpr int ES   = E / BPR;         // 100000 edges per slice

// XCD-affinity swizzle constants (stateless, replay-safe).
constexpr int FULLR = AGB / 3;        // 1041 full rounds
constexpr int FULLB = FULLR * 8;      // 8328 bids in full rounds
constexpr int G2F   = FULLR * 2;      // 2082 g2 tiles from full rounds
constexpr int REM0  = AGB - 3*FULLR;  // 2 leftover g0 tiles
static_assert(3*FULLR + REM0 == AGB, "g0 cover");
static_assert(2*FULLR + (3*AGB - FULLB - 2*REM0) == AGB, "g2 cover");

typedef unsigned short ushort_t;
typedef unsigned int uint_t;
typedef unsigned char uchar_t;
typedef float fl2 __attribute__((ext_vector_type(2)));
typedef float fl4 __attribute__((ext_vector_type(4)));

// ---- workspace layout (element offsets) ----
// X region repurposed: holds the per-graph fp8 h_gat table ((N+1)*64 B fits
// in N*H*4 B). x itself is never materialized after the mm fusion.
constexpr size_t X_OFF    = 0;                          // h_gat table (fp8)
constexpr size_t NO_OFF   = X_OFF + (size_t)N*H;        // N   deg_out^-1/2
constexpr size_t NI_OFF   = NO_OFF + N;                 // N   deg_in^-1/2
constexpr size_t EL_OFF   = NI_OFF + N;                 // N+1 GAT el (incl supernode)
constexpr size_t ER_OFF   = EL_OFF + (N+1);             // N   GAT er
constexpr size_t EE_OFF   = ER_OFF + N;                 // E   (unused; layout kept)
constexpr size_t IS_OFF   = EE_OFF + E;                 // N   (unused)
constexpr size_t ASLF_OFF = IS_OFF + N;                 // N   (unused)
constexpr size_t ASUP_OFF = ASLF_OFF + N;               // N   (unused)
constexpr size_t GF = ((ASUP_OFF + N + 255)/256)*256;

constexpr size_t RP_OFF = 0;                            // N+1 row_ptr (CSR by dst)
constexpr size_t CT_OFF = RP_OFF + (N+1);               // N   in-degree count
constexpr size_t SS_OFF = CT_OFF + N;                   // E   src sorted by dst
constexpr size_t GI = ((SS_OFF + E + 255)/256)*256;

// per-graph fp8 h_gcn block: 64 B per row; row N = supernode (unused for gcn)
constexpr size_t GH = (size_t)(N+1)*64;                 // bytes

// fp8 helpers: HW RNE pack/unpack (OCP e4m3 on gfx950)
__device__ inline uint_t f8pack4(float a, float b, float c, float d){
  int r = __builtin_amdgcn_cvt_pk_fp8_f32(a, b, 0, false);
  r = __builtin_amdgcn_cvt_pk_fp8_f32(c, d, r, true);
  return (uint_t)r;
}
__device__ inline fl4 f8up4(uint_t v){
  fl2 lo = __builtin_amdgcn_cvt_pk_f32_fp8((int)v, false);
  fl2 hi = __builtin_amdgcn_cvt_pk_f32_fp8((int)v, true);
  fl4 r; r.x = lo.x; r.y = lo.y; r.z = hi.x; r.w = hi.y;
  return r;
}

// Deterministic bid -> (graph, tile) swizzle for XCD L2 affinity.
__device__ inline void swz_tile(int bid, int& g, int& b){
  if (bid < FULLB){
    int r = bid >> 3, s = bid & 7;
    if (s < 3){ g = 0; b = r*3 + s; }
    else if (s < 6){ g = 1; b = r*3 + (s-3); }
    else { g = 2; b = r*2 + (s-6); }
  } else {
    int t = bid - FULLB;
    if (t < REM0){ g = 0; b = 3*FULLR + t; }
    else if (t < 2*REM0){ g = 1; b = 3*FULLR + (t-REM0); }
    else { g = 2; b = G2F + (t-2*REM0); }
  }
}

// ---- prep: range-partitioned LDS histograms, zero global atomics ----
__global__ __launch_bounds__(1024) void k_hist(int* parts_ct, int* parts_no,
    const int* s0,const int* d0,const int* s1,const int* d1,const int* s2,const int* d2) {
  int sl = blockIdx.x, r = blockIdx.y, g = blockIdx.z;
  const int* s = g==0?s0:(g==1?s1:s2);
  const int* d = g==0?d0:(g==1?d1:d2);
  __shared__ int hc[BINS];
  __shared__ int hn[BINS];
  for (int i=threadIdx.x;i<BINS;i+=1024){ hc[i]=0; hn[i]=0; }
  __syncthreads();
  int lo = r*BINS, hi = lo+BINS;
  int e0 = sl*ES, e1 = e0+ES;
  for (int e=e0+threadIdx.x; e<e1; e+=1024){
    int ds = d[e], sr = s[e];
    if (ds>=lo && ds<hi) atomicAdd(&hc[ds-lo],1);
    if (sr>=lo && sr<hi) atomicAdd(&hn[sr-lo],1);
  }
  __syncthreads();
  size_t base = ((size_t)g*BPR + sl)*N + lo;
  for (int i=threadIdx.x;i<BINS;i+=1024){
    parts_ct[base+i]=hc[i];
    parts_no[base+i]=hn[i];
  }
}

// ---- hierarchical exclusive scan of cnt -> rp (all parallel) ----
__global__ __launch_bounds__(1024) void k_scan_local(int* ib, int* pt, const int* parts_ct) {
  int g = blockIdx.y;
  int* ig = ib + (size_t)g*GI;
  int i = blockIdx.x*1024 + threadIdx.x;
  int c = 0;
  if (i < N){
    #pragma unroll
    for (int s=0;s<BPR;s++) c += parts_ct[((size_t)g*BPR+s)*N + i];
    ig[CT_OFF + i] = c;
  }
  __shared__ int sh[1024];
  sh[threadIdx.x] = c; __syncthreads();
  #pragma unroll
  for (int off=1; off<1024; off<<=1){
    int t = (threadIdx.x>=off) ? sh[threadIdx.x-off] : 0;
    __syncthreads();
    sh[threadIdx.x] += t;
    __syncthreads();
  }
  if (i < N) ig[RP_OFF + i] = sh[threadIdx.x] - c;       // local exclusive
  if (threadIdx.x == 1023) pt[g*SCB + blockIdx.x] = sh[1023];
}

__global__ void k_scan_part(int* pt) {
  int g = blockIdx.x;
  __shared__ int sh[SCB];
  int t = threadIdx.x;
  if (t < SCB) sh[t] = pt[g*SCB + t];
  __syncthreads();
  if (t == 0){
    int run = 0;
    for (int b=0;b<SCB;b++){ int c = sh[b]; sh[b] = run; run += c; }
  }
  __syncthreads();
  if (t < SCB) pt[g*SCB + t] = sh[t];
}

__global__ __launch_bounds__(1024) void k_scan_apply(float* fb, int* ib, const int* pt,
                                                     const int* parts_no) {
  int g = blockIdx.y;
  float* fg = fb + (size_t)g*GF;
  int* ig = ib + (size_t)g*GI;
  int i = blockIdx.x*1024 + threadIdx.x;
  if (i >= N) return;
  int base = pt[g*SCB + blockIdx.x];
  int r = ig[RP_OFF + i] + base;
  ig[RP_OFF + i] = r;
  int c = ig[CT_OFF + i];
  int o = 0;
  #pragma unroll
  for (int s=0;s<BPR;s++) o += parts_no[((size_t)g*BPR+s)*N + i];
  fg[NI_OFF + i] = rsqrtf((float)(c+1));                 // +1 self loop
  fg[NO_OFF + i] = rsqrtf((float)(o+1));
  if (i == N-1) ig[RP_OFF + N] = r + c;
}

// per-(slice,bin) exclusive prefix over slices -> exact scatter offsets
__global__ __launch_bounds__(256) void k_slice_off(const int* ib, const int* parts_ct, int* off) {
  int g = blockIdx.y;
  int i = blockIdx.x*256 + threadIdx.x;
  if (i >= N) return;
  int base = ib[(size_t)g*GI + RP_OFF + i];
  #pragma unroll
  for (int s=0;s<BPR;s++){
    size_t idx = ((size_t)g*BPR+s)*N + i;
    off[idx] = base;
    base += parts_ct[idx];
  }
}

// scatter: LDS cursors per range, plain scattered store (no global atomics)
__global__ __launch_bounds__(1024) void k_scatter_r(int* ib, const int* off,
    const int* s0,const int* d0,const int* s1,const int* d1,const int* s2,const int* d2) {
  int sl = blockIdx.x, r = blockIdx.y, g = blockIdx.z;
  const int* s = g==0?s0:(g==1?s1:s2);
  const int* d = g==0?d0:(g==1?d1:d2);
  int* ss = ib + (size_t)g*GI + SS_OFF;
  __shared__ int cur[BINS];
  int lo = r*BINS;
  size_t ob = ((size_t)g*BPR + sl)*N + lo;
  for (int i=threadIdx.x;i<BINS;i+=1024) cur[i] = off[ob+i];
  __syncthreads();
  int e0 = sl*ES, e1 = e0+ES;
  for (int e=e0+threadIdx.x; e<e1; e+=1024){
    int ds = d[e];
    if (ds>=lo && ds<lo+BINS){
      int pos = atomicAdd(&cur[ds-lo],1);
      ss[pos] = s[e];
    }
  }
}

// Initial GCN dense layer: reads INPUT x directly (x never staged to ws).
// Tiled matmul: 64 rows/block, 4 threads/row (q = 16-col group), acc[16].
// h = fp8( (x @ Wc0) * no[row] ). Block (0,0) zeroes readout accs.
__global__ __launch_bounds__(256) void k_mm_gcn0(float* fb, uchar_t* hb,
    const float* x0,const float* x1,const float* x2,
    const float* W0,const float* W1,const float* W2, float* sm) {
  if (blockIdx.x==0 && blockIdx.y==0){
    for (int i=threadIdx.x;i<384;i+=256) sm[i]=0.f;
  }
  int g = blockIdx.y;
  const float* W = g==0?W0:(g==1?W1:W2);
  const float* x = g==0?x0:(g==1?x1:x2);
  __shared__ float Ws[64*64];
  __shared__ float Xs[64*65];
  float* fg = fb + (size_t)g*GF;
  int row0 = blockIdx.x*64;
  for (int i=threadIdx.x; i<4096; i+=256) Ws[i] = W[i];
  int r = threadIdx.x>>2, q = threadIdx.x&3;
  int row = row0 + r;
  int rowc = row < N ? row : N-1;
  {
    const float4* xr = (const float4*)(x + (size_t)rowc*64) + q*4;
    float* xd = Xs + r*65 + q*16;
    #pragma unroll
    for (int c=0;c<4;c++){ float4 v = xr[c]; xd[4*c]=v.x; xd[4*c+1]=v.y; xd[4*c+2]=v.z; xd[4*c+3]=v.w; }
  }
  __syncthreads();
  float acc[16];
  #pragma unroll
  for (int j=0;j<16;j++) acc[j]=0.f;
  const float* xrow = Xs + r*65;
  #pragma unroll 8
  for (int k=0;k<64;k++){
    float xk = xrow[k];
    const float* wr = Ws + k*64 + q*16;
    #pragma unroll
    for (int j=0;j<16;j++) acc[j] = fmaf(xk, wr[j], acc[j]);
  }
  if (row >= N) return;
  float sc = fg[NO_OFF + row];
  uint_t pk[4];
  #pragma unroll
  for (int j=0;j<4;j++)
    pk[j] = f8pack4(acc[4*j]*sc, acc[4*j+1]*sc, acc[4*j+2]*sc, acc[4*j+3]*sc);
  *(uint4*)(hb + (size_t)g*GH + (size_t)row*64 + q*16) = *(const uint4*)pk;
}

// GCN aggregate, group-per-node, FUSED with the GAT dense layer.
// After computing the relu'd convpool output vo (held as fl4 per lane,
// 16 lanes per node), the epilogue computes h_gat = fp8(vo @ Wgat) and
// el/er inline: vo is staged to a padded LDS tile (same-wave write->read,
// no barrier), Wgat lives in LDS (16KB, cooperative load). The dense math
// (~256 fma/lane) hides under the gather latency (VALU was 74% idle).
// x is never written (h_gat replaces it in the X region); kills k_mm_gat
// and the 38MB x round-trip. fuse=0 for the final readout-only dispatch.
__global__ __launch_bounds__(256) void k_gcn_agg(float* fb, const uchar_t* hb, const int* ib,
    const float* b0, const float* b1, const float* b2, int lay, float* sm,
    const float* Wgat, const float* al, const float* ar, int fuse) {
  int g, blk;
  swz_tile(blockIdx.x, g, blk);
  const float* b = (g==0?b0:(g==1?b1:b2)) + lay*64;
  float* fg = fb + (size_t)g*GF;
  const uint_t* hu = (const uint_t*)(hb + (size_t)g*GH);  // h_gcn (read)
  uint_t* hgat = (uint_t*)(fg + X_OFF);                   // h_gat (write)
  const int* ig = ib + (size_t)g*GI;
  int wave = threadIdx.x >> 6, lane = threadIdx.x & 63;
  int v = lane >> 4, u = lane & 15;
  int base = lane & 48;
  int w = blk*4 + wave;
  int node = w + NWAVE*v;
  const int* rp = ig + RP_OFF;
  const int* ss = ig + SS_OFF;
  fl4 bl = ((const fl4*)b)[u];
  __shared__ float Wsl[4096];
  __shared__ float xsl[16*68];          // padded stride 68: bank-spread slots
  __shared__ float ssum[4][64];
  __shared__ float smx[4][64];
  if (fuse){
    const float* Wg = Wgat + (size_t)g*4096;
    for (int i=threadIdx.x;i<4096;i+=256) Wsl[i] = Wg[i];
  }
  __syncthreads();

  int s0 = rp[node], s1 = rp[node+1];
  float ni = fg[NI_OFF + node];
  fl4 a = f8up4(hu[(size_t)node*16 + u]);                 // self loop (pre-scaled)
  int idxv;
  { int ei = s0 + u; int ec = ei < s1 ? ei : s0;
    idxv = __builtin_nontemporal_load(&ss[ec]); }

  for (int kb = s0; kb < s1; kb += 16){                   // group-divergent loop
    uint_t vv[16];
    #pragma unroll
    for (int j=0;j<16;j++){
      int ij = __shfl(idxv, base + j);
      vv[j] = hu[(size_t)ij*16 + u];
    }
    int kn = kb + 16;
    if (kn < s1){                                         // prefetch next round
      int ei = kn + u; int ec = ei < s1 ? ei : s0;
      idxv = __builtin_nontemporal_load(&ss[ec]);
    }
    #pragma unroll
    for (int j=0;j<16;j++){
      float wj = (kb + j) < s1 ? 1.f : 0.f;
      fl4 f = f8up4(vv[j]);
      a.x = fmaf(wj, f.x, a.x); a.y = fmaf(wj, f.y, a.y);
      a.z = fmaf(wj, f.z, a.z); a.w = fmaf(wj, f.w, a.w);
    }
  }

  fl4 vo;
  vo.x = fmaf(a.x, ni, bl.x); vo.x = vo.x > 0.f ? vo.x : 0.f;
  vo.y = fmaf(a.y, ni, bl.y); vo.y = vo.y > 0.f ? vo.y : 0.f;
  vo.z = fmaf(a.z, ni, bl.z); vo.z = vo.z > 0.f ? vo.z : 0.f;
  vo.w = fmaf(a.w, ni, bl.w); vo.w = vo.w > 0.f ? vo.w : 0.f;

  if (fuse){
    int slot = wave*4 + v;
    *(fl4*)&xsl[slot*68 + 4*u] = vo;    // same-wave write->read: lgkm-ordered
    fl4 hacc = {0.f,0.f,0.f,0.f};
    #pragma unroll 4
    for (int k4=0;k4<16;k4++){
      fl4 xv = *(fl4*)&xsl[slot*68 + 4*k4];
      #pragma unroll
      for (int j=0;j<4;j++){
        float xk = j==0?xv.x:(j==1?xv.y:(j==2?xv.z:xv.w));
        fl4 wv = *(fl4*)&Wsl[(4*k4+j)*64 + 4*u];
        hacc.x = fmaf(xk, wv.x, hacc.x); hacc.y = fmaf(xk, wv.y, hacc.y);
        hacc.z = fmaf(xk, wv.z, hacc.z); hacc.w = fmaf(xk, wv.w, hacc.w);
      }
    }
    hgat[(size_t)node*16 + u] = f8pack4(hacc.x, hacc.y, hacc.z, hacc.w);
    fl4 a4 = *(const fl4*)&al[g*64 + 4*u];
    fl4 r4 = *(const fl4*)&ar[g*64 + 4*u];
    float elp = hacc.x*a4.x + hacc.y*a4.y + hacc.z*a4.z + hacc.w*a4.w;
    float erp = hacc.x*r4.x + hacc.y*r4.y + hacc.z*r4.z + hacc.w*r4.w;
    elp += __shfl_xor(elp,1); elp += __shfl_xor(elp,2);
    elp += __shfl_xor(elp,4); elp += __shfl_xor(elp,8);
    erp += __shfl_xor(erp,1); erp += __shfl_xor(erp,2);
    erp += __shfl_xor(erp,4); erp += __shfl_xor(erp,8);
    if (u == 0){
      fg[EL_OFF + node] = elp;
      fg[ER_OFF + node] = erp;
    }
  }

  // readout: sum/max across the wave's 4 nodes (groups) once
  fl4 vs = vo, vm = vo;
  vs.x += __shfl_xor(vs.x,16); vs.x += __shfl_xor(vs.x,32);
  vs.y += __shfl_xor(vs.y,16); vs.y += __shfl_xor(vs.y,32);
  vs.z += __shfl_xor(vs.z,16); vs.z += __shfl_xor(vs.z,32);
  vs.w += __shfl_xor(vs.w,16); vs.w += __shfl_xor(vs.w,32);
  vm.x = fmaxf(vm.x, __shfl_xor(vm.x,16)); vm.x = fmaxf(vm.x, __shfl_xor(vm.x,32));
  vm.y = fmaxf(vm.y, __shfl_xor(vm.y,16)); vm.y = fmaxf(vm.y, __shfl_xor(vm.y,32));
  vm.z = fmaxf(vm.z, __shfl_xor(vm.z,16)); vm.z = fmaxf(vm.z, __shfl_xor(vm.z,32));
  vm.w = fmaxf(vm.w, __shfl_xor(vm.w,16)); vm.w = fmaxf(vm.w, __shfl_xor(vm.w,32));
  if (lane < 16){
    ((fl4*)ssum[wave])[u] = vs;
    ((fl4*)smx[wave])[u]  = vm;
  }
  __syncthreads();
  if (threadIdx.x < 64){
    int t = threadIdx.x;
    float s = ssum[0][t]+ssum[1][t]+ssum[2][t]+ssum[3][t];
    float mx = fmaxf(fmaxf(smx[0][t],smx[1][t]), fmaxf(smx[2][t],smx[3][t]));
    atomicAdd(&sm[g*64 + t], s);
    atomicMax((int*)sm + 192 + g*64 + t, __float_as_int(mx));  // v>=0: int order == float order
  }
}

// readout finalize + cross-graph feature exchange + supernode h_gat row, el[N].
// Also RE-ZEROES its source graph's sm slots (read-then-zero, block-exclusive)
// so the next gcn_agg's atomics start clean (mm kernels used to do this).
__global__ void k_exchange(float* fb, float* sm, const float* Wx, const float* bx,
                           const float* Wgat, const float* al, int it) {
  int gt = blockIdx.x;     // target graph
  int t = threadIdx.x;     // 64 threads
  int src, widx;
  if ((it & 1) == 0){ src = (gt==0)?1:(gt==1)?2:0; widx = (gt==0)?1:(gt==1)?0:2; }
  else              { src = (gt==0)?2:(gt==1)?0:1; widx = (gt==0)?5:(gt==1)?3:4; }
  __shared__ float ro[128];
  __shared__ float f[64];
  __shared__ float red[64];
  __shared__ float hsb[64];
  ro[t]      = sm[src*64 + t] * (1.0f/(float)N);
  ro[64 + t] = __int_as_float(((int*)sm)[192 + src*64 + t]);
  sm[src*64 + t] = 0.f;                    // exclusive: only this block reads src
  ((int*)sm)[192 + src*64 + t] = 0;
  __syncthreads();
  float a = bx[widx*64 + t];
  for (int k=0;k<128;k++) a = fmaf(ro[k], Wx[(size_t)widx*8192 + k*64 + t], a);
  a = a > 0.f ? a : 0.f;
  f[t] = a;
  __syncthreads();
  float* fg = fb + (size_t)gt*GF;
  float hs = 0.f;
  for (int k=0;k<64;k++) hs = fmaf(f[k], Wgat[(size_t)gt*4096 + k*64 + t], hs);
  hsb[t] = hs;
  red[t] = hs * al[gt*64 + t];
  __syncthreads();
  if (t < 16){
    uint_t r = f8pack4(hsb[4*t], hsb[4*t+1], hsb[4*t+2], hsb[4*t+3]);
    ((uint_t*)(fg + X_OFF))[(size_t)N*16 + t] = r;       // supernode h_gat row
  }
  if (t == 0){
    float e = 0.f;
    for (int k=0;k<64;k++) e += red[k];
    fg[EL_OFF + N] = e;                      // el for supernode
  }
}

// GAT aggregation with fused online softmax AND the next GCN dense layer.
// Reads h_gat (X region), writes h_gcn = fp8((gat_out @ Wc[lay]) * no) into hb
// for the next gcn_agg. Kills k_mm_gcn (it>0) and the x round-trip.
__global__ __launch_bounds__(256) void k_gat_agg(float* fb, uchar_t* hb, const int* ib,
    const float* bgat, const float* Wc0, const float* Wc1, const float* Wc2, int lay) {
  int g, blk;
  swz_tile(blockIdx.x, g, blk);
  float* fg = fb + (size_t)g*GF;
  const uint_t* hu = (const uint_t*)(fg + X_OFF);         // h_gat (read)
  uint_t* hout = (uint_t*)(hb + (size_t)g*GH);            // h_gcn (write)
  const int* ig = ib + (size_t)g*GI;
  int wave = threadIdx.x >> 6, lane = threadIdx.x & 63;
  int v = lane >> 4, u = lane & 15;
  int base = lane & 48;
  int w = blk*4 + wave;
  int node = w + NWAVE*v;
  const int* rp = ig + RP_OFF;
  const int* ss = ig + SS_OFF;
  const float* el = fg + EL_OFF;
  fl4 bg = ((const fl4*)(bgat + g*64))[u];
  __shared__ float Wsl[4096];
  __shared__ float xsl[16*68];
  {
    const float* W = (g==0?Wc0:(g==1?Wc1:Wc2)) + (size_t)lay*4096;
    for (int i=threadIdx.x;i<4096;i+=256) Wsl[i] = W[i];
  }
  __syncthreads();
  fl4 supf = f8up4(hu[(size_t)N*16 + u]);

  int s0 = rp[node], s1 = rp[node+1];
  float ern = fg[ER_OFF + node];
  float eln = el[node];
  float elsup = el[N];
  float es = eln + ern;   es = es >= 0.f ? es : 0.2f*es;  float ts = __expf(es);
  float eu = elsup + ern; eu = eu >= 0.f ? eu : 0.2f*eu;  float tu = __expf(eu);
  fl4 fs = f8up4(hu[(size_t)node*16 + u]);
  fl4 a;
  a.x = fmaf(tu, supf.x, ts*fs.x);
  a.y = fmaf(tu, supf.y, ts*fs.y);
  a.z = fmaf(tu, supf.z, ts*fs.z);
  a.w = fmaf(tu, supf.w, ts*fs.w);
  float esum = 0.f;

  int idxv; float elv;
  { int ei = s0 + u;
    int ec = ei < s1 ? ei : (s0 < s1 ? s0 : 0);           // always a valid slot
    idxv = __builtin_nontemporal_load(&ss[ec]); }
  elv = el[idxv];                                         // safe: idxv in [0,N)

  for (int kb = s0; kb < s1; kb += 16){                   // group-divergent loop
    float xe = elv + ern; xe = xe >= 0.f ? xe : 0.2f*xe;
    float ex = __expf(xe);
    float wv = (kb + u) < s1 ? ex : 0.f;
    esum += wv;
    uint_t vv[16];
    #pragma unroll
    for (int j=0;j<16;j++){
      int ij = __shfl(idxv, base + j);
      vv[j] = hu[(size_t)ij*16 + u];
    }
    int kn = kb + 16;
    if (kn < s1){                                         // prefetch next round
      int ei = kn + u; int ec = ei < s1 ? ei : s0;
      idxv = __builtin_nontemporal_load(&ss[ec]);
      elv = el[idxv];
    }
    #pragma unroll
    for (int j=0;j<16;j++){
      float wj = __shfl(wv, base + j);                    // already zero-masked
      fl4 f = f8up4(vv[j]);
      a.x = fmaf(wj, f.x, a.x); a.y = fmaf(wj, f.y, a.y);
      a.z = fmaf(wj, f.z, a.z); a.w = fmaf(wj, f.w, a.w);
    }
  }

  esum += __shfl_xor(esum,1); esum += __shfl_xor(esum,2);
  esum += __shfl_xor(esum,4); esum += __shfl_xor(esum,8);
  float is = 1.0f / (esum + ts + tu);

  fl4 vo;                                                 // GAT output (no relu)
  vo.x = fmaf(a.x, is, bg.x); vo.y = fmaf(a.y, is, bg.y);
  vo.z = fmaf(a.z, is, bg.z); vo.w = fmaf(a.w, is, bg.w);

  // fused next-layer GCN dense: h_gcn = fp8((vo @ Wc[lay]) * no[node])
  int slot = wave*4 + v;
  *(fl4*)&xsl[slot*68 + 4*u] = vo;
  fl4 hacc = {0.f,0.f,0.f,0.f};
  #pragma unroll 4
  for (int k4=0;k4<16;k4++){
    fl4 xv = *(fl4*)&xsl[slot*68 + 4*k4];
    #pragma unroll
    for (int j=0;j<4;j++){
      float xk = j==0?xv.x:(j==1?xv.y:(j==2?xv.z:xv.w));
      fl4 wv = *(fl4*)&Wsl[(4*k4+j)*64 + 4*u];
      hacc.x = fmaf(xk, wv.x, hacc.x); hacc.y = fmaf(xk, wv.y, hacc.y);
      hacc.z = fmaf(xk, wv.z, hacc.z); hacc.w = fmaf(xk, wv.w, hacc.w);
    }
  }
  float no = fg[NO_OFF + node];
  hout[(size_t)node*16 + u] = f8pack4(hacc.x*no, hacc.y*no, hacc.z*no, hacc.w*no);
}

__global__ __launch_bounds__(384) void k_mlp(const float* sm, const float* W1, const float* b1,
    const float* W2, const float* b2, const float* W3, const float* b3, float* out) {
  __shared__ float nf[384];
  __shared__ float y1[192];
  __shared__ float y2[96];
  __shared__ float z[2];
  int t = threadIdx.x;
  int g = t / 128, j = t % 128;
  nf[t] = (j < 64) ? sm[g*64 + j] * (1.0f/(float)N)
                   : __int_as_float(((const int*)sm)[192 + g*64 + (j-64)]);
  __syncthreads();
  if (t < 192){
    float a = b1[t];
    for (int k=0;k<384;k++) a = fmaf(nf[k], W1[(size_t)k*192 + t], a);
    y1[t] = a > 0.f ? a : 0.f;
  }
  __syncthreads();
  if (t < 96){
    float a = b2[t];
    for (int k=0;k<192;k++) a = fmaf(y1[k], W2[(size_t)k*96 + t], a);
    y2[t] = a > 0.f ? a : 0.f;
  }
  __syncthreads();
  if (t < 2){
    float a = b3[t];
    for (int k=0;k<96;k++) a = fmaf(y2[k], W3[k*2 + t], a);
    z[t] = a;
  }
  __syncthreads();
  if (t == 0){
    float m = fmaxf(z[0], z[1]);
    float l = m + logf(__expf(z[0]-m) + __expf(z[1]-m));
    out[0] = z[0] - l;
    out[1] = z[1] - l;
  }
}

extern "C" void kernel_launch(void* const* d_in, const int* in_sizes, int n_in,
                              void* d_out, int out_size, void* d_ws, size_t ws_size,
                              hipStream_t stream) {
  const float* x_s  = (const float*)d_in[0];
  const float* x_g  = (const float*)d_in[1];
  const float* x_t  = (const float*)d_in[2];
  const float* Wc_s = (const float*)d_in[3];
  const float* bc_s = (const float*)d_in[4];
  const float* Wc_g = (const float*)d_in[5];
  const float* bc_g = (const float*)d_in[6];
  const float* Wc_t = (const float*)d_in[7];
  const float* bc_t = (const float*)d_in[8];
  const float* Wx   = (const float*)d_in[9];
  const float* bx   = (const float*)d_in[10];
  const float* Wgat = (const float*)d_in[11];
  const float* al   = (const float*)d_in[12];
  const float* ar   = (const float*)d_in[13];
  const float* bgat = (const float*)d_in[14];
  const float* W1   = (const float*)d_in[15];
  const float* b1   = (const float*)d_in[16];
  const float* W2   = (const float*)d_in[17];
  const float* b2   = (const float*)d_in[18];
  const float* W3   = (const float*)d_in[19];
  const float* b3   = (const float*)d_in[20];
  const int* src_s  = (const int*)d_in[21];
  const int* dst_s  = (const int*)d_in[22];
  const int* src_g  = (const int*)d_in[23];
  const int* dst_g  = (const int*)d_in[24];
  const int* src_t  = (const int*)d_in[25];
  const int* dst_t  = (const int*)d_in[26];

  float* fb = (float*)d_ws;
  int*   ib = (int*)(fb + 3*GF);
  uchar_t* hb = (uchar_t*)(ib + 3*GI);
  float* sm = (float*)(hb + 3*GH);
  int*   pt = (int*)(sm + 384);              // 3*SCB scan partials
  int*   parts_ct = pt + 3*SCB + 64;         // 3*BPR*N
  int*   parts_no = parts_ct + (size_t)3*BPR*N;
  int*   off      = parts_no + (size_t)3*BPR*N;
  float* out = (float*)d_out;

  dim3 b256(256);
  int mmb = (N+63)/64;

  // graph prep: LDS-histogram counting sort (no global atomics)
  k_hist      <<<dim3(BPR, RNG, 3),  dim3(1024), 0, stream>>>(parts_ct, parts_no, src_s,dst_s, src_g,dst_g, src_t,dst_t);
  k_scan_local<<<dim3(SCB, 3),       dim3(1024), 0, stream>>>(ib, pt, parts_ct);
  k_scan_part <<<dim3(3),              dim3(64), 0, stream>>>(pt);
  k_scan_apply<<<dim3(SCB, 3),       dim3(1024), 0, stream>>>(fb, ib, pt, parts_no);
  k_slice_off <<<dim3((N+255)/256, 3),     b256, 0, stream>>>(ib, parts_ct, off);
  k_scatter_r <<<dim3(BPR, RNG, 3),  dim3(1024), 0, stream>>>(ib, off, src_s,dst_s, src_g,dst_g, src_t,dst_t);

  // initial GCN dense from input x (no copyx; x never materialized in ws)
  k_mm_gcn0 <<<dim3(mmb, 3), b256, 0, stream>>>(fb, hb, x_s, x_g, x_t,
                                                Wc_s, Wc_g, Wc_t, sm);

  for (int it = 0; it < 2; ++it) {
    k_gcn_agg <<<dim3(3*AGB), b256, 0, stream>>>(fb, hb, ib, bc_s, bc_g, bc_t, it, sm,
                                                 Wgat, al, ar, 1);
    k_exchange<<<dim3(3), dim3(64), 0, stream>>>(fb, sm, Wx, bx, Wgat, al, it);
    k_gat_agg <<<dim3(3*AGB), b256, 0, stream>>>(fb, hb, ib, bgat,
                                                 Wc_s, Wc_g, Wc_t, it+1);
  }

  // final layer readout (no fusion) + MLP head
  k_gcn_agg <<<dim3(3*AGB), b256, 0, stream>>>(fb, hb, ib, bc_s, bc_g, bc_t, 2, sm,
                                               Wgat, al, ar, 0);
  k_mlp     <<<1, 384, 0, stream>>>(sm, W1, b1, W2, b2, W3, b3, out);
}